// Round 1
// baseline (1781.381 us; speedup 1.0000x reference)
//
#include <hip/hip_runtime.h>
#include <math.h>

#define B_    2
#define N_    2048
#define DIM_  1024
#define H_    16
#define HD_   64
#define TDIM  3072      // 3*DIM
#define ROWS  4096      // B*N
#define PI_F  3.14159265358979323846f

__device__ __forceinline__ float wave_sum(float v) {
#pragma unroll
  for (int off = 32; off > 0; off >>= 1) v += __shfl_xor(v, off, 64);
  return v;
}

// ---------------------------------------------------------------------------
// M = (I + 0.1*Wf)^10  (64x64). Flow z<-z+0.1*z@Wf ten times == z @ M.
// ---------------------------------------------------------------------------
__global__ __launch_bounds__(256) void compute_M(const float* __restrict__ Wf,
                                                 float* __restrict__ M) {
  __shared__ float A[4096], Mc[4096], Mn[4096];
  const int tid = threadIdx.x;
  for (int i = tid; i < 4096; i += 256) {
    float a = 0.1f * Wf[i] + (((i >> 6) == (i & 63)) ? 1.0f : 0.0f);
    A[i] = a; Mc[i] = a;
  }
  __syncthreads();
  for (int it = 0; it < 9; ++it) {
    for (int i = tid; i < 4096; i += 256) {
      const int r = i >> 6, c = i & 63;
      float s = 0.0f;
      for (int e = 0; e < 64; ++e) s = fmaf(Mc[r * 64 + e], A[e * 64 + c], s);
      Mn[i] = s;
    }
    __syncthreads();
    for (int i = tid; i < 4096; i += 256) Mc[i] = Mn[i];
    __syncthreads();
  }
  for (int i = tid; i < 4096; i += 256) M[i] = Mc[i];
}

// ---------------------------------------------------------------------------
// qkv = x @ Wqkv + bqkv   [4096 x 3072], K=1024. fp32 tiled GEMM 64x64x16.
// ---------------------------------------------------------------------------
__global__ __launch_bounds__(256) void gemm_qkv(const float* __restrict__ X,
                                                const float* __restrict__ W,
                                                const float* __restrict__ bias,
                                                float* __restrict__ C) {
  __shared__ float As[16][64];   // [k][m]
  __shared__ float Bs[16][64];   // [k][n]
  const int tid = threadIdx.x;
  const int tx = tid & 15, ty = tid >> 4;
  const int row0 = blockIdx.y * 64, col0 = blockIdx.x * 64;
  const int am = tid >> 2;            // 0..63
  const int ak = (tid & 3) * 4;       // 0,4,8,12
  const int bk = tid >> 4;            // 0..15
  const int bn = (tid & 15) * 4;
  float acc[4][4] = {{0.f}};
  for (int k0 = 0; k0 < 1024; k0 += 16) {
    float4 av = *(const float4*)&X[(size_t)(row0 + am) * DIM_ + k0 + ak];
    float4 bv = *(const float4*)&W[(size_t)(k0 + bk) * TDIM + col0 + bn];
    __syncthreads();
    As[ak + 0][am] = av.x; As[ak + 1][am] = av.y;
    As[ak + 2][am] = av.z; As[ak + 3][am] = av.w;
    *(float4*)&Bs[bk][bn] = bv;
    __syncthreads();
#pragma unroll
    for (int k = 0; k < 16; ++k) {
      float4 a = *(const float4*)&As[k][ty * 4];
      float4 b = *(const float4*)&Bs[k][tx * 4];
      float ar[4] = {a.x, a.y, a.z, a.w};
      float br[4] = {b.x, b.y, b.z, b.w};
#pragma unroll
      for (int i = 0; i < 4; ++i)
#pragma unroll
        for (int j = 0; j < 4; ++j) acc[i][j] = fmaf(ar[i], br[j], acc[i][j]);
    }
  }
#pragma unroll
  for (int i = 0; i < 4; ++i) {
    const int r = row0 + ty * 4 + i;
    float4 o;
    o.x = acc[i][0] + bias[col0 + tx * 4 + 0];
    o.y = acc[i][1] + bias[col0 + tx * 4 + 1];
    o.z = acc[i][2] + bias[col0 + tx * 4 + 2];
    o.w = acc[i][3] + bias[col0 + tx * 4 + 3];
    *(float4*)&C[(size_t)r * TDIM + col0 + tx * 4] = o;
  }
}

// ---------------------------------------------------------------------------
// inv row norm over 3072 (the l2norm of the concatenated qkv row)
// ---------------------------------------------------------------------------
__global__ __launch_bounds__(256) void rownorm(const float* __restrict__ qkv,
                                               float* __restrict__ invn) {
  const int row = blockIdx.x;
  const float4* rp = (const float4*)(qkv + (size_t)row * TDIM);
  float s = 0.f;
  for (int c = threadIdx.x; c < TDIM / 4; c += 256) {
    float4 v = rp[c];
    s += v.x * v.x + v.y * v.y + v.z * v.z + v.w * v.w;
  }
  s = wave_sum(s);
  __shared__ float red[4];
  if ((threadIdx.x & 63) == 0) red[threadIdx.x >> 6] = s;
  __syncthreads();
  if (threadIdx.x == 0) {
    float t = red[0] + red[1] + red[2] + red[3];
    invn[row] = 1.0f / fmaxf(sqrtf(t), 1e-12f);
  }
}

// ---------------------------------------------------------------------------
// prep: per (b,h,n) row -> Q (complex), Kt (complex), Vabs.
// One wave handles 4 rows; lane = head-dim index d.
// ---------------------------------------------------------------------------
__device__ __forceinline__ void qstate_flow(
    const float t[4], int wv, int lane,
    const float* __restrict__ Wp1, const float* __restrict__ bp1,
    const float* __restrict__ Wp2, const float* __restrict__ bp2,
    const float* __restrict__ M,
    float shT[4][4][64], float shH[4][4][128], float shZ[4][4][128],
    float outR[4], float outI[4]) {
#pragma unroll
  for (int r = 0; r < 4; ++r) shT[wv][r][lane] = t[r];
  __syncthreads();
  // layer 1: hidden = tanh(t @ Wp1 + bp1), 128 wide (lane owns j and j+64)
  float h1[4], h2[4];
  const float b1a = bp1[lane], b1b = bp1[lane + 64];
#pragma unroll
  for (int r = 0; r < 4; ++r) { h1[r] = b1a; h2[r] = b1b; }
  for (int e = 0; e < 64; ++e) {
    const float w1 = Wp1[e * 128 + lane];
    const float w2 = Wp1[e * 128 + 64 + lane];
#pragma unroll
    for (int r = 0; r < 4; ++r) {
      const float te = shT[wv][r][e];
      h1[r] = fmaf(te, w1, h1[r]);
      h2[r] = fmaf(te, w2, h2[r]);
    }
  }
#pragma unroll
  for (int r = 0; r < 4; ++r) {
    shH[wv][r][lane]      = tanhf(h1[r]);
    shH[wv][r][lane + 64] = tanhf(h2[r]);
  }
  __syncthreads();
  // layer 2: phase = hidden @ Wp2 + bp2
  float p[4];
  const float b2 = bp2[lane];
#pragma unroll
  for (int r = 0; r < 4; ++r) p[r] = b2;
  for (int e = 0; e < 128; ++e) {
    const float w = Wp2[e * 64 + lane];
#pragma unroll
    for (int r = 0; r < 4; ++r) p[r] = fmaf(shH[wv][r][e], w, p[r]);
  }
  // amplitude * exp(i * tanh(phase) * pi)
#pragma unroll
  for (int r = 0; r < 4; ++r) {
    const float s = wave_sum(t[r] * t[r]);
    const float inv = 1.0f / fmaxf(sqrtf(s), 1e-12f);
    const float amp = t[r] * inv;
    const float ph = tanhf(p[r]) * PI_F;
    shZ[wv][r][lane]      = amp * cosf(ph);
    shZ[wv][r][lane + 64] = amp * sinf(ph);
  }
  __syncthreads();
  // flow: z @ M (M = (I+0.1Wf)^10), then complex l2norm
  float fr[4] = {0, 0, 0, 0}, fi[4] = {0, 0, 0, 0};
  for (int e = 0; e < 64; ++e) {
    const float m = M[e * 64 + lane];
#pragma unroll
    for (int r = 0; r < 4; ++r) {
      fr[r] = fmaf(shZ[wv][r][e], m, fr[r]);
      fi[r] = fmaf(shZ[wv][r][64 + e], m, fi[r]);
    }
  }
#pragma unroll
  for (int r = 0; r < 4; ++r) {
    const float s = wave_sum(fmaf(fr[r], fr[r], fi[r] * fi[r]));
    const float inv = 1.0f / fmaxf(sqrtf(s), 1e-12f);
    outR[r] = fr[r] * inv;
    outI[r] = fi[r] * inv;
  }
  __syncthreads();
}

__global__ __launch_bounds__(256) void prep_kernel(
    const float* __restrict__ qkv, const float* __restrict__ invn,
    const float* __restrict__ Wp1, const float* __restrict__ bp1,
    const float* __restrict__ Wp2, const float* __restrict__ bp2,
    const float* __restrict__ M,
    float* __restrict__ Qr, float* __restrict__ Qi,
    float* __restrict__ Ktr, float* __restrict__ Kti,
    float* __restrict__ Vabs) {
  __shared__ float shT[4][4][64];
  __shared__ float shH[4][4][128];
  __shared__ float shZ[4][4][128];
  const int lane = threadIdx.x & 63;
  const int wv = threadIdx.x >> 6;
  const int g0 = blockIdx.x * 16 + wv * 4;
  float tq[4], tk[4], tv[4];
  int gidx[4];
#pragma unroll
  for (int r = 0; r < 4; ++r) {
    const int g = g0 + r;
    gidx[r] = g;
    const int b = g >> 15;
    const int h = (g >> 11) & 15;
    const int n = g & 2047;
    const size_t base = ((size_t)(b * N_ + n)) * TDIM + h * HD_;
    const float inv = invn[b * N_ + n];
    tq[r] = qkv[base + lane] * inv;
    tk[r] = qkv[base + 1024 + lane] * inv;
    tv[r] = qkv[base + 2048 + lane] * inv;
  }
  // v: |amp * e^{i phi}| = |t|/||t||  (phase net is dead code for v)
#pragma unroll
  for (int r = 0; r < 4; ++r) {
    const float s = wave_sum(tv[r] * tv[r]);
    const float inv = 1.0f / fmaxf(sqrtf(s), 1e-12f);
    Vabs[(size_t)gidx[r] * HD_ + lane] = fabsf(tv[r]) * inv;
  }
  float qr[4], qi[4], kr[4], ki[4];
  qstate_flow(tq, wv, lane, Wp1, bp1, Wp2, bp2, M, shT, shH, shZ, qr, qi);
  qstate_flow(tk, wv, lane, Wp1, bp1, Wp2, bp2, M, shT, shH, shZ, kr, ki);
#pragma unroll
  for (int r = 0; r < 4; ++r) {
    const size_t o = (size_t)gidx[r] * HD_ + lane;
    Qr[o] = qr[r]; Qi[o] = qi[r];
    // parallel transport: dist = csqrt(sum(diff*diff)), tf = 1/(1+cexp(10 dist))
    const float dr = kr[r] - qr[r], di = ki[r] - qi[r];
    const float sr = wave_sum(fmaf(dr, dr, -di * di));
    const float si = wave_sum(2.0f * dr * di);
    const float rad = sqrtf(fmaf(sr, sr, si * si));
    const float ur = sqrtf(fmaxf((rad + sr) * 0.5f, 0.0f));
    const float ui = copysignf(sqrtf(fmaxf((rad - sr) * 0.5f, 0.0f)), si);
    const float er = expf(10.0f * ur);
    const float exr = er * cosf(10.0f * ui);
    const float exi = er * sinf(10.0f * ui);
    const float dnr = 1.0f + exr, dni = exi;
    const float d2 = fmaf(dnr, dnr, dni * dni);
    const float tfr = dnr / d2, tfi = -dni / d2;
    const float omr = 1.0f - tfr, omi = -tfi;
    float ktr = kr[r] * tfr - ki[r] * tfi + qr[r] * omr - qi[r] * omi;
    float kti = kr[r] * tfi + ki[r] * tfr + qr[r] * omi + qi[r] * omr;
    const float s2 = wave_sum(fmaf(ktr, ktr, kti * kti));
    const float inv2 = 1.0f / fmaxf(sqrtf(s2), 1e-12f);
    Ktr[o] = ktr * inv2; Kti[o] = kti * inv2;
  }
}

// ---------------------------------------------------------------------------
// attention: flash-style, no running max (|logit| <= 0.125).
// Q-tile 64 (LDS, transposed), K-tile 32. P round-trips through LDS (aliased
// with Ksr) for the PV GEMM. den accumulated in registers of tid<64.
// LDS = 16K+16K+8K(alias)+8K+8K = 57344 B -> 2 blocks/CU.
// ---------------------------------------------------------------------------
__global__ __launch_bounds__(256) void attn_kernel(
    const float* __restrict__ Qr, const float* __restrict__ Qi,
    const float* __restrict__ Ktr, const float* __restrict__ Kti,
    const float* __restrict__ V, float* __restrict__ out) {
  __shared__ float Qsr[64][64];      // [d][r]
  __shared__ float Qsi[64][64];
  __shared__ float KP[2048];         // Ksr[d][c] during S; Ps[m][r] during PV
  __shared__ float Ksi[64][32];
  __shared__ float Vs[32][64];       // [m][vd]
  const int tid = threadIdx.x;
  const int bh = blockIdx.y;
  const int q0 = blockIdx.x * 64;
  const size_t base = (size_t)bh * (N_ * HD_);
  // stage Q tile transposed
  for (int l = tid; l < 1024; l += 256) {
    const int r = l >> 4, dq = (l & 15) * 4;
    float4 a = *(const float4*)&Qr[base + (size_t)(q0 + r) * HD_ + dq];
    float4 c = *(const float4*)&Qi[base + (size_t)(q0 + r) * HD_ + dq];
    Qsr[dq + 0][r] = a.x; Qsr[dq + 1][r] = a.y;
    Qsr[dq + 2][r] = a.z; Qsr[dq + 3][r] = a.w;
    Qsi[dq + 0][r] = c.x; Qsi[dq + 1][r] = c.y;
    Qsi[dq + 2][r] = c.z; Qsi[dq + 3][r] = c.w;
  }
  const int tc = tid & 15, tr = tid >> 4;   // S: rows tr*4..+4, cols tc*2..+2
  float acc[4][4] = {{0.f}};
  float den = 0.0f;                          // valid for tid < 64
  for (int kt = 0; kt < N_ / 32; ++kt) {
    const int k0 = kt * 32;
    __syncthreads();   // prev PV done (and Q staging on first iter)
    for (int l = tid; l < 512; l += 256) {
      const int c = l >> 4, dq = (l & 15) * 4;
      float4 a = *(const float4*)&Ktr[base + (size_t)(k0 + c) * HD_ + dq];
      float4 b = *(const float4*)&Kti[base + (size_t)(k0 + c) * HD_ + dq];
      KP[(dq + 0) * 32 + c] = a.x; KP[(dq + 1) * 32 + c] = a.y;
      KP[(dq + 2) * 32 + c] = a.z; KP[(dq + 3) * 32 + c] = a.w;
      Ksi[dq + 0][c] = b.x; Ksi[dq + 1][c] = b.y;
      Ksi[dq + 2][c] = b.z; Ksi[dq + 3][c] = b.w;
    }
    for (int l = tid; l < 512; l += 256) {
      const int m = l >> 4, dq = (l & 15) * 4;
      *(float4*)&Vs[m][dq] = *(const float4*)&V[base + (size_t)(k0 + m) * HD_ + dq];
    }
    __syncthreads();
    float s[4][2] = {{0.f}};
    for (int d = 0; d < 64; ++d) {
      float4 ar4 = *(const float4*)&Qsr[d][tr * 4];
      float4 ai4 = *(const float4*)&Qsi[d][tr * 4];
      float2 br2 = *(const float2*)&KP[d * 32 + tc * 2];
      float2 bi2 = *(const float2*)&Ksi[d][tc * 2];
      float ar[4] = {ar4.x, ar4.y, ar4.z, ar4.w};
      float ai[4] = {ai4.x, ai4.y, ai4.z, ai4.w};
      float br[2] = {br2.x, br2.y};
      float bi[2] = {bi2.x, bi2.y};
#pragma unroll
      for (int i = 0; i < 4; ++i)
#pragma unroll
        for (int j = 0; j < 2; ++j) {
          s[i][j] = fmaf(ar[i], br[j], s[i][j]);
          s[i][j] = fmaf(-ai[i], bi[j], s[i][j]);
        }
    }
    __syncthreads();   // everyone done reading KP as Ksr
#pragma unroll
    for (int i = 0; i < 4; ++i)
#pragma unroll
      for (int j = 0; j < 2; ++j)
        KP[(tc * 2 + j) * 64 + (tr * 4 + i)] = expf(s[i][j] * 0.125f);
    __syncthreads();   // Ps visible
    if (tid < 64) {
#pragma unroll 8
      for (int m = 0; m < 32; ++m) den += KP[m * 64 + tid];
    }
    for (int m = 0; m < 32; ++m) {
      float4 pa4 = *(const float4*)&KP[m * 64 + tr * 4];
      float4 vb4 = *(const float4*)&Vs[m][tc * 4];
      float pa[4] = {pa4.x, pa4.y, pa4.z, pa4.w};
      float vb[4] = {vb4.x, vb4.y, vb4.z, vb4.w};
#pragma unroll
      for (int i = 0; i < 4; ++i)
#pragma unroll
        for (int j = 0; j < 4; ++j) acc[i][j] = fmaf(pa[i], vb[j], acc[i][j]);
    }
  }
  __syncthreads();
  if (tid < 64) Qsr[0][tid] = den;
  __syncthreads();
  const int b = bh >> 4, h = bh & 15;
#pragma unroll
  for (int i = 0; i < 4; ++i) {
    const int n = q0 + tr * 4 + i;
    const float invd = 1.0f / Qsr[0][tr * 4 + i];
    float4 o;
    o.x = acc[i][0] * invd; o.y = acc[i][1] * invd;
    o.z = acc[i][2] * invd; o.w = acc[i][3] * invd;
    *(float4*)&out[(((size_t)b * N_ + n) * H_ + h) * HD_ + tc * 4] = o;
  }
}

// ---------------------------------------------------------------------------
extern "C" void kernel_launch(void* const* d_in, const int* in_sizes, int n_in,
                              void* d_out, int out_size, void* d_ws, size_t ws_size,
                              hipStream_t stream) {
  const float* x    = (const float*)d_in[0];
  const float* Wqkv = (const float*)d_in[1];
  const float* bqkv = (const float*)d_in[2];
  const float* Wp1  = (const float*)d_in[3];
  const float* bp1  = (const float*)d_in[4];
  const float* Wp2  = (const float*)d_in[5];
  const float* bp2  = (const float*)d_in[6];
  const float* Wf   = (const float*)d_in[7];
  float* out = (float*)d_out;

  const size_t SZ = (size_t)B_ * H_ * N_ * HD_;   // 4,194,304
  float* ws      = (float*)d_ws;
  float* qkv_raw = ws;                             // ROWS*TDIM = 12,582,912
  float* invn    = qkv_raw + (size_t)ROWS * TDIM;  // 4096
  float* gM      = invn + ROWS;                    // 4096
  float* Qr      = gM + 4096;
  float* Qi      = Qr + SZ;
  float* Ktr     = Qi + SZ;
  float* Kti     = Ktr + SZ;
  float* Vab     = Kti + SZ;
  // total ws use: ~134.3 MB (floats)

  hipLaunchKernelGGL(compute_M, dim3(1), dim3(256), 0, stream, Wf, gM);
  hipLaunchKernelGGL(gemm_qkv, dim3(48, 64), dim3(256), 0, stream, x, Wqkv, bqkv, qkv_raw);
  hipLaunchKernelGGL(rownorm, dim3(ROWS), dim3(256), 0, stream, qkv_raw, invn);
  hipLaunchKernelGGL(prep_kernel, dim3(4096), dim3(256), 0, stream,
                     qkv_raw, invn, Wp1, bp1, Wp2, bp2, gM, Qr, Qi, Ktr, Kti, Vab);
  hipLaunchKernelGGL(attn_kernel, dim3(N_ / 64, B_ * H_), dim3(256), 0, stream,
                     Qr, Qi, Ktr, Kti, Vab, out);
}

// Round 2
// 676.578 us; speedup vs baseline: 2.6329x; 2.6329x over previous
//
#include <hip/hip_runtime.h>
#include <math.h>

#define B_    2
#define N_    2048
#define DIM_  1024
#define H_    16
#define HD_   64
#define TDIM  3072      // 3*DIM
#define ROWS  4096      // B*N
#define PI_F  3.14159265358979323846f
#define SCALE_F 0.125f

typedef short short8 __attribute__((ext_vector_type(8)));
typedef float f32x4 __attribute__((ext_vector_type(4)));

__device__ __forceinline__ float wave_sum(float v) {
#pragma unroll
  for (int off = 32; off > 0; off >>= 1) v += __shfl_xor(v, off, 64);
  return v;
}

__device__ __forceinline__ unsigned short f2bf(float x) {
  unsigned u = __float_as_uint(x);
  u += 0x7fffu + ((u >> 16) & 1u);   // RNE
  return (unsigned short)(u >> 16);
}
__device__ __forceinline__ float bf2f(unsigned short h) {
  return __uint_as_float(((unsigned)h) << 16);
}

// ---------------------------------------------------------------------------
// M = (I + 0.1*Wf)^10  (64x64). Flow z<-z+0.1*z@Wf ten times == z @ M.
// ---------------------------------------------------------------------------
__global__ __launch_bounds__(256) void compute_M(const float* __restrict__ Wf,
                                                 float* __restrict__ M) {
  __shared__ float A[4096], Mc[4096], Mn[4096];
  const int tid = threadIdx.x;
  for (int i = tid; i < 4096; i += 256) {
    float a = 0.1f * Wf[i] + (((i >> 6) == (i & 63)) ? 1.0f : 0.0f);
    A[i] = a; Mc[i] = a;
  }
  __syncthreads();
  for (int it = 0; it < 9; ++it) {
    for (int i = tid; i < 4096; i += 256) {
      const int r = i >> 6, c = i & 63;
      float s = 0.0f;
      for (int e = 0; e < 64; ++e) s = fmaf(Mc[r * 64 + e], A[e * 64 + c], s);
      Mn[i] = s;
    }
    __syncthreads();
    for (int i = tid; i < 4096; i += 256) Mc[i] = Mn[i];
    __syncthreads();
  }
  for (int i = tid; i < 4096; i += 256) M[i] = Mc[i];
}

// ---------------------------------------------------------------------------
// split fp32 -> bf16 hi/lo.  Xs[m][0..1023]=hi, [1024..2047]=lo
// ---------------------------------------------------------------------------
__global__ __launch_bounds__(256) void split_X(const float* __restrict__ X,
                                               unsigned short* __restrict__ Xs) {
  const int gid = blockIdx.x * 256 + threadIdx.x;   // ROWS*1024/4 threads
  const int m = gid >> 8, c = (gid & 255) * 4;
  float4 v = *(const float4*)&X[(size_t)m * 1024 + c];
  ushort4 hi, lo;
  hi.x = f2bf(v.x); lo.x = f2bf(v.x - bf2f(hi.x));
  hi.y = f2bf(v.y); lo.y = f2bf(v.y - bf2f(hi.y));
  hi.z = f2bf(v.z); lo.z = f2bf(v.z - bf2f(hi.z));
  hi.w = f2bf(v.w); lo.w = f2bf(v.w - bf2f(hi.w));
  *(ushort4*)&Xs[(size_t)m * 2048 + c] = hi;
  *(ushort4*)&Xs[(size_t)m * 2048 + 1024 + c] = lo;
}

// W[1024][3072] -> Wt[3072][2048] (n-major; cols 0..1023 hi, 1024..2047 lo)
__global__ __launch_bounds__(256) void split_W(const float* __restrict__ W,
                                               unsigned short* __restrict__ Wt) {
  __shared__ float T[64][68];
  const int n0 = blockIdx.x * 64, k0 = blockIdx.y * 64;
  const int tid = threadIdx.x;
  for (int l = tid; l < 1024; l += 256) {
    const int r = l >> 4, c = (l & 15) * 4;
    *(float4*)&T[r][c] = *(const float4*)&W[(size_t)(k0 + r) * TDIM + n0 + c];
  }
  __syncthreads();
  const int n = tid >> 2, q = (tid & 3) * 16;
  alignas(16) unsigned short hi16[16];
  alignas(16) unsigned short lo16[16];
#pragma unroll
  for (int j = 0; j < 16; ++j) {
    const float v = T[q + j][n];
    const unsigned short h = f2bf(v);
    hi16[j] = h; lo16[j] = f2bf(v - bf2f(h));
  }
  unsigned short* dst = &Wt[(size_t)(n0 + n) * 2048];
  *(uint4*)&dst[k0 + q]          = *(uint4*)&hi16[0];
  *(uint4*)&dst[k0 + q + 8]      = *(uint4*)&hi16[8];
  *(uint4*)&dst[1024 + k0 + q]     = *(uint4*)&lo16[0];
  *(uint4*)&dst[1024 + k0 + q + 8] = *(uint4*)&lo16[8];
}

// ---------------------------------------------------------------------------
// qkv = x @ Wqkv + bqkv via split-bf16 MFMA, K'=3072 (hh + hl + lh)
// 128x128 tile, 4 waves of 64x64 (4x4 frags of 16x16x32)
// ---------------------------------------------------------------------------
__global__ __launch_bounds__(256) void gemm2(const unsigned short* __restrict__ Xs,
                                             const unsigned short* __restrict__ Wt,
                                             const float* __restrict__ bias,
                                             float* __restrict__ C) {
  __shared__ unsigned short As[128][40];   // +8B pad: 16B-aligned rows, 2-way max
  __shared__ unsigned short Bs[128][40];
  const int tid = threadIdx.x;
  const int wv = tid >> 6, ln = tid & 63;
  const int l16 = ln & 15, quad = ln >> 4;
  const int wrow = wv >> 1, wcol = wv & 1;
  const int row0 = blockIdx.y * 128, col0 = blockIdx.x * 128;
  const int sr = tid >> 1;            // 0..127
  const int sc = (tid & 1) * 2;       // chunk pair
  f32x4 acc[4][4];
#pragma unroll
  for (int i = 0; i < 4; ++i)
#pragma unroll
    for (int j = 0; j < 4; ++j) acc[i][j] = {0.f, 0.f, 0.f, 0.f};
  for (int k0 = 0; k0 < 3072; k0 += 32) {
    const int acol = (k0 < 1024) ? k0 : k0 - 1024;   // hi, hi, lo
    const int bcol = (k0 < 2048) ? k0 : k0 - 2048;   // hi, lo, hi
    uint4 a0 = *(const uint4*)&Xs[(size_t)(row0 + sr) * 2048 + acol + (sc + 0) * 8];
    uint4 a1 = *(const uint4*)&Xs[(size_t)(row0 + sr) * 2048 + acol + (sc + 1) * 8];
    uint4 b0 = *(const uint4*)&Wt[(size_t)(col0 + sr) * 2048 + bcol + (sc + 0) * 8];
    uint4 b1 = *(const uint4*)&Wt[(size_t)(col0 + sr) * 2048 + bcol + (sc + 1) * 8];
    __syncthreads();
    *(uint4*)&As[sr][(sc + 0) * 8] = a0;
    *(uint4*)&As[sr][(sc + 1) * 8] = a1;
    *(uint4*)&Bs[sr][(sc + 0) * 8] = b0;
    *(uint4*)&Bs[sr][(sc + 1) * 8] = b1;
    __syncthreads();
    short8 af[4], bfr[4];
#pragma unroll
    for (int mi = 0; mi < 4; ++mi)
      af[mi] = *(const short8*)&As[wrow * 64 + mi * 16 + l16][quad * 8];
#pragma unroll
    for (int ni = 0; ni < 4; ++ni)
      bfr[ni] = *(const short8*)&Bs[wcol * 64 + ni * 16 + l16][quad * 8];
#pragma unroll
    for (int mi = 0; mi < 4; ++mi)
#pragma unroll
      for (int ni = 0; ni < 4; ++ni)
        acc[mi][ni] = __builtin_amdgcn_mfma_f32_16x16x32_bf16(af[mi], bfr[ni], acc[mi][ni], 0, 0, 0);
  }
#pragma unroll
  for (int ni = 0; ni < 4; ++ni) {
    const int col = col0 + wcol * 64 + ni * 16 + l16;
    const float bb = bias[col];
#pragma unroll
    for (int mi = 0; mi < 4; ++mi) {
#pragma unroll
      for (int r = 0; r < 4; ++r) {
        const int row = row0 + wrow * 64 + mi * 16 + quad * 4 + r;
        C[(size_t)row * TDIM + col] = acc[mi][ni][r] + bb;
      }
    }
  }
}

// ---------------------------------------------------------------------------
// inv row norm over 3072
// ---------------------------------------------------------------------------
__global__ __launch_bounds__(256) void rownorm(const float* __restrict__ qkv,
                                               float* __restrict__ invn) {
  const int row = blockIdx.x;
  const float4* rp = (const float4*)(qkv + (size_t)row * TDIM);
  float s = 0.f;
  for (int c = threadIdx.x; c < TDIM / 4; c += 256) {
    float4 v = rp[c];
    s += v.x * v.x + v.y * v.y + v.z * v.z + v.w * v.w;
  }
  s = wave_sum(s);
  __shared__ float red[4];
  if ((threadIdx.x & 63) == 0) red[threadIdx.x >> 6] = s;
  __syncthreads();
  if (threadIdx.x == 0) {
    float t = red[0] + red[1] + red[2] + red[3];
    invn[row] = 1.0f / fmaxf(sqrtf(t), 1e-12f);
  }
}

// ---------------------------------------------------------------------------
// prep: per (b,h,n) row -> Qc [bh][n][128] bf16 (r|i), Kc same with -imag,
// Vt [bh][d][n] bf16. One wave = 4 rows; lane = head-dim d.
// ---------------------------------------------------------------------------
__device__ __forceinline__ void qstate_flow(
    const float t[4], int wv, int lane,
    const float* __restrict__ Wp1, const float* __restrict__ bp1,
    const float* __restrict__ Wp2, const float* __restrict__ bp2,
    const float* __restrict__ M,
    float shT[4][4][64], float shH[4][4][128], float shZ[4][4][128],
    float outR[4], float outI[4]) {
#pragma unroll
  for (int r = 0; r < 4; ++r) shT[wv][r][lane] = t[r];
  __syncthreads();
  float h1[4], h2[4];
  const float b1a = bp1[lane], b1b = bp1[lane + 64];
#pragma unroll
  for (int r = 0; r < 4; ++r) { h1[r] = b1a; h2[r] = b1b; }
  for (int e = 0; e < 64; ++e) {
    const float w1 = Wp1[e * 128 + lane];
    const float w2 = Wp1[e * 128 + 64 + lane];
#pragma unroll
    for (int r = 0; r < 4; ++r) {
      const float te = shT[wv][r][e];
      h1[r] = fmaf(te, w1, h1[r]);
      h2[r] = fmaf(te, w2, h2[r]);
    }
  }
#pragma unroll
  for (int r = 0; r < 4; ++r) {
    shH[wv][r][lane]      = tanhf(h1[r]);
    shH[wv][r][lane + 64] = tanhf(h2[r]);
  }
  __syncthreads();
  float p[4];
  const float b2 = bp2[lane];
#pragma unroll
  for (int r = 0; r < 4; ++r) p[r] = b2;
  for (int e = 0; e < 128; ++e) {
    const float w = Wp2[e * 64 + lane];
#pragma unroll
    for (int r = 0; r < 4; ++r) p[r] = fmaf(shH[wv][r][e], w, p[r]);
  }
#pragma unroll
  for (int r = 0; r < 4; ++r) {
    const float s = wave_sum(t[r] * t[r]);
    const float inv = 1.0f / fmaxf(sqrtf(s), 1e-12f);
    const float amp = t[r] * inv;
    const float ph = tanhf(p[r]) * PI_F;
    shZ[wv][r][lane]      = amp * cosf(ph);
    shZ[wv][r][lane + 64] = amp * sinf(ph);
  }
  __syncthreads();
  float fr[4] = {0, 0, 0, 0}, fi[4] = {0, 0, 0, 0};
  for (int e = 0; e < 64; ++e) {
    const float m = M[e * 64 + lane];
#pragma unroll
    for (int r = 0; r < 4; ++r) {
      fr[r] = fmaf(shZ[wv][r][e], m, fr[r]);
      fi[r] = fmaf(shZ[wv][r][64 + e], m, fi[r]);
    }
  }
#pragma unroll
  for (int r = 0; r < 4; ++r) {
    const float s = wave_sum(fmaf(fr[r], fr[r], fi[r] * fi[r]));
    const float inv = 1.0f / fmaxf(sqrtf(s), 1e-12f);
    outR[r] = fr[r] * inv;
    outI[r] = fi[r] * inv;
  }
  __syncthreads();
}

__global__ __launch_bounds__(256) void prep_kernel(
    const float* __restrict__ qkv, const float* __restrict__ invn,
    const float* __restrict__ Wp1, const float* __restrict__ bp1,
    const float* __restrict__ Wp2, const float* __restrict__ bp2,
    const float* __restrict__ M,
    unsigned short* __restrict__ Qc, unsigned short* __restrict__ Kc,
    unsigned short* __restrict__ Vt) {
  __shared__ float shT[4][4][64];
  __shared__ float shH[4][4][128];
  __shared__ float shZ[4][4][128];
  const int lane = threadIdx.x & 63;
  const int wv = threadIdx.x >> 6;
  const int g0 = blockIdx.x * 16 + wv * 4;
  const int bh = g0 >> 11;            // b*16+h
  const int n0 = g0 & 2047;
  const int b = g0 >> 15;
  const int h = (g0 >> 11) & 15;
  float tq[4], tk[4], tv[4];
#pragma unroll
  for (int r = 0; r < 4; ++r) {
    const int n = n0 + r;
    const size_t base = ((size_t)(b * N_ + n)) * TDIM + h * HD_;
    const float inv = invn[b * N_ + n];
    tq[r] = qkv[base + lane] * inv;
    tk[r] = qkv[base + 1024 + lane] * inv;
    tv[r] = qkv[base + 2048 + lane] * inv;
  }
  // v: |amp * e^{i phi}| = |t|/||t||  (phase net is dead code for v)
  ushort4 vpack;
  {
    float vv[4];
#pragma unroll
    for (int r = 0; r < 4; ++r) {
      const float s = wave_sum(tv[r] * tv[r]);
      const float inv = 1.0f / fmaxf(sqrtf(s), 1e-12f);
      vv[r] = fabsf(tv[r]) * inv;
    }
    vpack.x = f2bf(vv[0]); vpack.y = f2bf(vv[1]);
    vpack.z = f2bf(vv[2]); vpack.w = f2bf(vv[3]);
  }
  *(ushort4*)&Vt[((size_t)bh * 64 + lane) * N_ + n0] = vpack;

  float qr[4], qi[4], kr[4], ki[4];
  qstate_flow(tq, wv, lane, Wp1, bp1, Wp2, bp2, M, shT, shH, shZ, qr, qi);
  qstate_flow(tk, wv, lane, Wp1, bp1, Wp2, bp2, M, shT, shH, shZ, kr, ki);
#pragma unroll
  for (int r = 0; r < 4; ++r) {
    const size_t o = ((size_t)bh * N_ + n0 + r) * 128;
    Qc[o + lane]      = f2bf(qr[r]);
    Qc[o + 64 + lane] = f2bf(qi[r]);
    // parallel transport: dist = csqrt(sum(diff*diff)), tf = 1/(1+cexp(10 dist))
    const float dr = kr[r] - qr[r], di = ki[r] - qi[r];
    const float sr = wave_sum(fmaf(dr, dr, -di * di));
    const float si = wave_sum(2.0f * dr * di);
    const float rad = sqrtf(fmaf(sr, sr, si * si));
    const float ur = sqrtf(fmaxf((rad + sr) * 0.5f, 0.0f));
    const float ui = copysignf(sqrtf(fmaxf((rad - sr) * 0.5f, 0.0f)), si);
    const float er = expf(10.0f * ur);
    const float exr = er * cosf(10.0f * ui);
    const float exi = er * sinf(10.0f * ui);
    const float dnr = 1.0f + exr, dni = exi;
    const float d2 = fmaf(dnr, dnr, dni * dni);
    const float tfr = dnr / d2, tfi = -dni / d2;
    const float omr = 1.0f - tfr, omi = -tfi;
    float ktr = kr[r] * tfr - ki[r] * tfi + qr[r] * omr - qi[r] * omi;
    float kti = kr[r] * tfi + ki[r] * tfr + qr[r] * omi + qi[r] * omr;
    const float s2 = wave_sum(fmaf(ktr, ktr, kti * kti));
    const float inv2 = 1.0f / fmaxf(sqrtf(s2), 1e-12f);
    Kc[o + lane]      = f2bf(ktr * inv2);
    Kc[o + 64 + lane] = f2bf(-kti * inv2);   // negated: S = qr.kr + qi.(-ki)
  }
}

// ---------------------------------------------------------------------------
// attention: bf16 MFMA flash (no running max; |logit| <= 0.125)
// block = 64 q-rows x (iterate 64-key tiles); 4 waves, wave = 16q x 64k
// S: A=[qr|qi] (hoisted frags), B=[ktr|-kti], K=128.  P->LDS->PV MFMA.
// ---------------------------------------------------------------------------
__global__ __launch_bounds__(256) void attn2(
    const unsigned short* __restrict__ Qc,
    const unsigned short* __restrict__ Kc,
    const unsigned short* __restrict__ Vt,
    float* __restrict__ out) {
  __shared__ unsigned short Qs[64][136];   // pad 8 -> 16B-aligned rows, 2-way max
  __shared__ unsigned short Ks[64][136];
  __shared__ unsigned short Vs[64][72];    // [d][m]
  __shared__ unsigned short Ps[64][72];    // [q][m]
  const int tid = threadIdx.x;
  const int wv = tid >> 6, ln = tid & 63;
  const int l16 = ln & 15, quad = ln >> 4;
  const int bh = blockIdx.y;
  const int q0 = blockIdx.x * 64;
  const size_t qbase = ((size_t)bh * N_ + q0) * 128;
  for (int l = tid; l < 1024; l += 256) {
    const int r = l >> 4, c = l & 15;
    *(uint4*)&Qs[r][c * 8] = *(const uint4*)&Qc[qbase + (size_t)r * 128 + c * 8];
  }
  __syncthreads();
  short8 aq[4];
#pragma unroll
  for (int s = 0; s < 4; ++s)
    aq[s] = *(const short8*)&Qs[wv * 16 + l16][s * 32 + quad * 8];
  f32x4 acc_o[4];
#pragma unroll
  for (int d = 0; d < 4; ++d) acc_o[d] = {0.f, 0.f, 0.f, 0.f};
  float den[4] = {0.f, 0.f, 0.f, 0.f};

  for (int kt = 0; kt < N_ / 64; ++kt) {
    const int k0 = kt * 64;
    const size_t kbase = ((size_t)bh * N_ + k0) * 128;
    __syncthreads();   // prev iter's K/V reads done
    for (int l = tid; l < 1024; l += 256) {
      const int r = l >> 4, c = l & 15;
      *(uint4*)&Ks[r][c * 8] = *(const uint4*)&Kc[kbase + (size_t)r * 128 + c * 8];
    }
    for (int l = tid; l < 512; l += 256) {
      const int d = l >> 3, c = l & 7;
      *(uint4*)&Vs[d][c * 8] =
          *(const uint4*)&Vt[((size_t)bh * 64 + d) * N_ + k0 + c * 8];
    }
    __syncthreads();
#pragma unroll
    for (int t = 0; t < 4; ++t) {
      f32x4 acc = {0.f, 0.f, 0.f, 0.f};
#pragma unroll
      for (int s = 0; s < 4; ++s) {
        short8 bk = *(const short8*)&Ks[t * 16 + l16][s * 32 + quad * 8];
        acc = __builtin_amdgcn_mfma_f32_16x16x32_bf16(aq[s], bk, acc, 0, 0, 0);
      }
#pragma unroll
      for (int r = 0; r < 4; ++r) {
        const float p = __expf(acc[r] * SCALE_F);
        den[r] += p;
        Ps[wv * 16 + quad * 4 + r][t * 16 + l16] = f2bf(p);
      }
    }
    // PV: wave-local Ps rows (no cross-wave barrier needed)
#pragma unroll
    for (int s2 = 0; s2 < 2; ++s2) {
      short8 ap = *(const short8*)&Ps[wv * 16 + l16][s2 * 32 + quad * 8];
#pragma unroll
      for (int dt = 0; dt < 4; ++dt) {
        short8 bv = *(const short8*)&Vs[dt * 16 + l16][s2 * 32 + quad * 8];
        acc_o[dt] = __builtin_amdgcn_mfma_f32_16x16x32_bf16(ap, bv, acc_o[dt], 0, 0, 0);
      }
    }
  }
#pragma unroll
  for (int r = 0; r < 4; ++r) {
    float d = den[r];
    d += __shfl_xor(d, 1, 64);
    d += __shfl_xor(d, 2, 64);
    d += __shfl_xor(d, 4, 64);
    d += __shfl_xor(d, 8, 64);
    den[r] = 1.0f / d;
  }
  const int b = bh >> 4, h = bh & 15;
#pragma unroll
  for (int dt = 0; dt < 4; ++dt) {
#pragma unroll
    for (int r = 0; r < 4; ++r) {
      const int qg = q0 + wv * 16 + quad * 4 + r;
      out[(((size_t)b * N_ + qg) * H_ + h) * HD_ + dt * 16 + l16] = acc_o[dt][r] * den[r];
    }
  }
}

// ---------------------------------------------------------------------------
extern "C" void kernel_launch(void* const* d_in, const int* in_sizes, int n_in,
                              void* d_out, int out_size, void* d_ws, size_t ws_size,
                              hipStream_t stream) {
  const float* x    = (const float*)d_in[0];
  const float* Wqkv = (const float*)d_in[1];
  const float* bqkv = (const float*)d_in[2];
  const float* Wp1  = (const float*)d_in[3];
  const float* bp1  = (const float*)d_in[4];
  const float* Wp2  = (const float*)d_in[5];
  const float* bp2  = (const float*)d_in[6];
  const float* Wf   = (const float*)d_in[7];
  float* out = (float*)d_out;

  char* w = (char*)d_ws;
  float* qkv = (float*)w;               w += (size_t)ROWS * TDIM * 4;   // 50.3 MB
  float* invn = (float*)w;              w += (size_t)ROWS * 4;
  float* gM = (float*)w;                w += 4096 * 4;
  unsigned short* Xs = (unsigned short*)w; w += (size_t)ROWS * 2048 * 2;   // 16.8 MB
  unsigned short* Wt = (unsigned short*)w; w += (size_t)TDIM * 2048 * 2;   // 12.6 MB
  unsigned short* Qc = (unsigned short*)w; w += (size_t)32 * N_ * 128 * 2; // 16.8 MB
  unsigned short* Kc = (unsigned short*)w; w += (size_t)32 * N_ * 128 * 2; // 16.8 MB
  unsigned short* Vt = (unsigned short*)w; w += (size_t)32 * 64 * N_ * 2;  // 8.4 MB

  hipLaunchKernelGGL(split_X, dim3(ROWS * 1024 / 4 / 256), dim3(256), 0, stream, x, Xs);
  hipLaunchKernelGGL(split_W, dim3(48, 16), dim3(256), 0, stream, Wqkv, Wt);
  hipLaunchKernelGGL(compute_M, dim3(1), dim3(256), 0, stream, Wf, gM);
  hipLaunchKernelGGL(gemm2, dim3(24, 32), dim3(256), 0, stream, Xs, Wt, bqkv, qkv);
  hipLaunchKernelGGL(rownorm, dim3(ROWS), dim3(256), 0, stream, qkv, invn);
  hipLaunchKernelGGL(prep_kernel, dim3(4096), dim3(256), 0, stream,
                     qkv, invn, Wp1, bp1, Wp2, bp2, gM, Qc, Kc, Vt);
  hipLaunchKernelGGL(attn2, dim3(N_ / 64, B_ * H_), dim3(256), 0, stream,
                     Qc, Kc, Vt, out);
}

// Round 3
// 619.686 us; speedup vs baseline: 2.8746x; 1.0918x over previous
//
#include <hip/hip_runtime.h>
#include <math.h>

#define B_    2
#define N_    2048
#define DIM_  1024
#define H_    16
#define HD_   64
#define TDIM  3072      // 3*DIM
#define ROWS  4096      // B*N
#define PI_F  3.14159265358979323846f
#define SCALE_F 0.125f

typedef short short8 __attribute__((ext_vector_type(8)));
typedef float f32x4 __attribute__((ext_vector_type(4)));
typedef unsigned short ushort_t;

__device__ __forceinline__ float wave_sum(float v) {
#pragma unroll
  for (int off = 32; off > 0; off >>= 1) v += __shfl_xor(v, off, 64);
  return v;
}

__device__ __forceinline__ unsigned short f2bf(float x) {
  unsigned u = __float_as_uint(x);
  u += 0x7fffu + ((u >> 16) & 1u);   // RNE
  return (unsigned short)(u >> 16);
}
__device__ __forceinline__ float bf2f(unsigned short h) {
  return __uint_as_float(((unsigned)h) << 16);
}
// abs err ~1e-7 (cancellation at small x) -- below bf16-split representation err
__device__ __forceinline__ float fast_tanh(float x) {
  return 1.0f - 2.0f / (__expf(2.0f * x) + 1.0f);
}

// ---------------------------------------------------------------------------
// M = (I + 0.1*Wf)^10 (64x64); emit transposed split-bf16 Ms[2][64][64],
// Ms[h][n][k] = split(M[k][n]) for MFMA B-operand use.
// ---------------------------------------------------------------------------
__global__ __launch_bounds__(256) void compute_M(const float* __restrict__ Wf,
                                                 ushort_t* __restrict__ Ms) {
  __shared__ float A[4096], Mc[4096], Mn[4096];
  const int tid = threadIdx.x;
  for (int i = tid; i < 4096; i += 256) {
    float a = 0.1f * Wf[i] + (((i >> 6) == (i & 63)) ? 1.0f : 0.0f);
    A[i] = a; Mc[i] = a;
  }
  __syncthreads();
  for (int it = 0; it < 9; ++it) {
    for (int i = tid; i < 4096; i += 256) {
      const int r = i >> 6, c = i & 63;
      float s = 0.0f;
      for (int e = 0; e < 64; ++e) s = fmaf(Mc[r * 64 + e], A[e * 64 + c], s);
      Mn[i] = s;
    }
    __syncthreads();
    for (int i = tid; i < 4096; i += 256) Mc[i] = Mn[i];
    __syncthreads();
  }
  for (int i = tid; i < 4096; i += 256) {
    const int n = i >> 6, k = i & 63;
    const float v = Mc[k * 64 + n];
    const ushort_t hi = f2bf(v);
    Ms[i] = hi; Ms[4096 + i] = f2bf(v - bf2f(hi));
  }
}

// ---------------------------------------------------------------------------
// split/transpose the phase-MLP weights:
// W1s[2][128][64]: W1s[h][n][k] = split(Wp1[k][n])   (Wp1 is [64][128])
// W2s[2][64][128]: W2s[h][n][k] = split(Wp2[k][n])   (Wp2 is [128][64])
// ---------------------------------------------------------------------------
__global__ __launch_bounds__(256) void prep_w(const float* __restrict__ Wp1,
                                              const float* __restrict__ Wp2,
                                              ushort_t* __restrict__ W1s,
                                              ushort_t* __restrict__ W2s) {
  const int tid = threadIdx.x;
  for (int i = tid; i < 8192; i += 256) {
    const int n = i >> 6, k = i & 63;
    const float v = Wp1[k * 128 + n];
    const ushort_t hi = f2bf(v);
    W1s[i] = hi; W1s[8192 + i] = f2bf(v - bf2f(hi));
  }
  for (int i = tid; i < 8192; i += 256) {
    const int n = i >> 7, k = i & 127;
    const float v = Wp2[k * 64 + n];
    const ushort_t hi = f2bf(v);
    W2s[i] = hi; W2s[8192 + i] = f2bf(v - bf2f(hi));
  }
}

// ---------------------------------------------------------------------------
// split fp32 -> bf16 hi/lo.  Xs[m][0..1023]=hi, [1024..2047]=lo
// ---------------------------------------------------------------------------
__global__ __launch_bounds__(256) void split_X(const float* __restrict__ X,
                                               unsigned short* __restrict__ Xs) {
  const int gid = blockIdx.x * 256 + threadIdx.x;
  const int m = gid >> 8, c = (gid & 255) * 4;
  float4 v = *(const float4*)&X[(size_t)m * 1024 + c];
  ushort4 hi, lo;
  hi.x = f2bf(v.x); lo.x = f2bf(v.x - bf2f(hi.x));
  hi.y = f2bf(v.y); lo.y = f2bf(v.y - bf2f(hi.y));
  hi.z = f2bf(v.z); lo.z = f2bf(v.z - bf2f(hi.z));
  hi.w = f2bf(v.w); lo.w = f2bf(v.w - bf2f(hi.w));
  *(ushort4*)&Xs[(size_t)m * 2048 + c] = hi;
  *(ushort4*)&Xs[(size_t)m * 2048 + 1024 + c] = lo;
}

// W[1024][3072] -> Wt[3072][2048] (n-major; cols 0..1023 hi, 1024..2047 lo)
__global__ __launch_bounds__(256) void split_W(const float* __restrict__ W,
                                               unsigned short* __restrict__ Wt) {
  __shared__ float T[64][68];
  const int n0 = blockIdx.x * 64, k0 = blockIdx.y * 64;
  const int tid = threadIdx.x;
  for (int l = tid; l < 1024; l += 256) {
    const int r = l >> 4, c = (l & 15) * 4;
    *(float4*)&T[r][c] = *(const float4*)&W[(size_t)(k0 + r) * TDIM + n0 + c];
  }
  __syncthreads();
  const int n = tid >> 2, q = (tid & 3) * 16;
  alignas(16) unsigned short hi16[16];
  alignas(16) unsigned short lo16[16];
#pragma unroll
  for (int j = 0; j < 16; ++j) {
    const float v = T[q + j][n];
    const unsigned short h = f2bf(v);
    hi16[j] = h; lo16[j] = f2bf(v - bf2f(h));
  }
  unsigned short* dst = &Wt[(size_t)(n0 + n) * 2048];
  *(uint4*)&dst[k0 + q]          = *(uint4*)&hi16[0];
  *(uint4*)&dst[k0 + q + 8]      = *(uint4*)&hi16[8];
  *(uint4*)&dst[1024 + k0 + q]     = *(uint4*)&lo16[0];
  *(uint4*)&dst[1024 + k0 + q + 8] = *(uint4*)&lo16[8];
}

// ---------------------------------------------------------------------------
// qkv = x @ Wqkv + bqkv via split-bf16 MFMA, K'=3072 (hh + hl + lh)
// ---------------------------------------------------------------------------
__global__ __launch_bounds__(256) void gemm2(const unsigned short* __restrict__ Xs,
                                             const unsigned short* __restrict__ Wt,
                                             const float* __restrict__ bias,
                                             float* __restrict__ C) {
  __shared__ unsigned short As[128][40];
  __shared__ unsigned short Bs[128][40];
  const int tid = threadIdx.x;
  const int wv = tid >> 6, ln = tid & 63;
  const int l16 = ln & 15, quad = ln >> 4;
  const int wrow = wv >> 1, wcol = wv & 1;
  const int row0 = blockIdx.y * 128, col0 = blockIdx.x * 128;
  const int sr = tid >> 1;
  const int sc = (tid & 1) * 2;
  f32x4 acc[4][4];
#pragma unroll
  for (int i = 0; i < 4; ++i)
#pragma unroll
    for (int j = 0; j < 4; ++j) acc[i][j] = {0.f, 0.f, 0.f, 0.f};
  for (int k0 = 0; k0 < 3072; k0 += 32) {
    const int acol = (k0 < 1024) ? k0 : k0 - 1024;   // hi, hi, lo
    const int bcol = (k0 < 2048) ? k0 : k0 - 2048;   // hi, lo, hi
    uint4 a0 = *(const uint4*)&Xs[(size_t)(row0 + sr) * 2048 + acol + (sc + 0) * 8];
    uint4 a1 = *(const uint4*)&Xs[(size_t)(row0 + sr) * 2048 + acol + (sc + 1) * 8];
    uint4 b0 = *(const uint4*)&Wt[(size_t)(col0 + sr) * 2048 + bcol + (sc + 0) * 8];
    uint4 b1 = *(const uint4*)&Wt[(size_t)(col0 + sr) * 2048 + bcol + (sc + 1) * 8];
    __syncthreads();
    *(uint4*)&As[sr][(sc + 0) * 8] = a0;
    *(uint4*)&As[sr][(sc + 1) * 8] = a1;
    *(uint4*)&Bs[sr][(sc + 0) * 8] = b0;
    *(uint4*)&Bs[sr][(sc + 1) * 8] = b1;
    __syncthreads();
    short8 af[4], bfr[4];
#pragma unroll
    for (int mi = 0; mi < 4; ++mi)
      af[mi] = *(const short8*)&As[wrow * 64 + mi * 16 + l16][quad * 8];
#pragma unroll
    for (int ni = 0; ni < 4; ++ni)
      bfr[ni] = *(const short8*)&Bs[wcol * 64 + ni * 16 + l16][quad * 8];
#pragma unroll
    for (int mi = 0; mi < 4; ++mi)
#pragma unroll
      for (int ni = 0; ni < 4; ++ni)
        acc[mi][ni] = __builtin_amdgcn_mfma_f32_16x16x32_bf16(af[mi], bfr[ni], acc[mi][ni], 0, 0, 0);
  }
#pragma unroll
  for (int ni = 0; ni < 4; ++ni) {
    const int col = col0 + wcol * 64 + ni * 16 + l16;
    const float bb = bias[col];
#pragma unroll
    for (int mi = 0; mi < 4; ++mi) {
#pragma unroll
      for (int r = 0; r < 4; ++r) {
        const int row = row0 + wrow * 64 + mi * 16 + quad * 4 + r;
        C[(size_t)row * TDIM + col] = acc[mi][ni][r] + bb;
      }
    }
  }
}

// ---------------------------------------------------------------------------
// inv row norm over 3072
// ---------------------------------------------------------------------------
__global__ __launch_bounds__(256) void rownorm(const float* __restrict__ qkv,
                                               float* __restrict__ invn) {
  const int row = blockIdx.x;
  const float4* rp = (const float4*)(qkv + (size_t)row * TDIM);
  float s = 0.f;
  for (int c = threadIdx.x; c < TDIM / 4; c += 256) {
    float4 v = rp[c];
    s += v.x * v.x + v.y * v.y + v.z * v.z + v.w * v.w;
  }
  s = wave_sum(s);
  __shared__ float red[4];
  if ((threadIdx.x & 63) == 0) red[threadIdx.x >> 6] = s;
  __syncthreads();
  if (threadIdx.x == 0) {
    float t = red[0] + red[1] + red[2] + red[3];
    invn[row] = 1.0f / fmaxf(sqrtf(t), 1e-12f);
  }
}

// ---------------------------------------------------------------------------
// prep (MFMA version): 16 (b,h,n) rows per block; MLP rows = 32 (16 q + 16 k).
// Stages: A(load/norm/split) -> L1 MFMA -> tanh -> L2 MFMA -> z -> flow MFMA
//         -> transport. Split-bf16 (hh+hl+lh) keeps fp32-level accuracy.
// LDS 45.2 KB (F aliases dead T/H region) -> 3 blocks/CU.
// ---------------------------------------------------------------------------
__global__ __launch_bounds__(256) void prep_mfma(
    const float* __restrict__ qkv, const float* __restrict__ invn,
    const ushort_t* __restrict__ W1s, const float* __restrict__ bp1,
    const ushort_t* __restrict__ W2s, const float* __restrict__ bp2,
    const ushort_t* __restrict__ Ms,
    ushort_t* __restrict__ Qc, ushort_t* __restrict__ Kc,
    ushort_t* __restrict__ Vt) {
  __shared__ __align__(16) char smem[45184];
  ushort_t (*Th)[72]  = (ushort_t(*)[72])(smem + 0);       // 4608
  ushort_t (*Tl)[72]  = (ushort_t(*)[72])(smem + 4608);    // 4608
  ushort_t (*Hh)[136] = (ushort_t(*)[136])(smem + 9216);   // 8704
  ushort_t (*Hl)[136] = (ushort_t(*)[136])(smem + 17920);  // 8704
  ushort_t (*Zrh)[72] = (ushort_t(*)[72])(smem + 26624);
  ushort_t (*Zrl)[72] = (ushort_t(*)[72])(smem + 31232);
  ushort_t (*Zih)[72] = (ushort_t(*)[72])(smem + 35840);
  ushort_t (*Zil)[72] = (ushort_t(*)[72])(smem + 40448);   // -> 45056
  float (*Fr)[68] = (float(*)[68])(smem + 0);              // alias T/H (dead)
  float (*Fi)[68] = (float(*)[68])(smem + 8704);
  float* invt = (float*)(smem + 45056);                    // [32]

  const int tid = threadIdx.x;
  const int wv = tid >> 6, ln = tid & 63;
  const int l16 = ln & 15, quad = ln >> 4;
  const int g0 = blockIdx.x * 16;
  const int bh = g0 >> 11, n0 = g0 & 2047;
  const int b = bh >> 4, h = bh & 15;

  // ---- stage A: load t_q/t_k/t_v, row norms, V output, T split into LDS
  {
    const int row = tid >> 4;          // 0..15
    const int c4 = (tid & 15) * 4;
    const int n = n0 + row;
    const size_t base = ((size_t)(b * N_ + n)) * TDIM + h * HD_;
    const float inv = invn[b * N_ + n];
    float4 q4 = *(const float4*)&qkv[base + c4];
    float4 k4 = *(const float4*)&qkv[base + 1024 + c4];
    float4 v4 = *(const float4*)&qkv[base + 2048 + c4];
    q4.x *= inv; q4.y *= inv; q4.z *= inv; q4.w *= inv;
    k4.x *= inv; k4.y *= inv; k4.z *= inv; k4.w *= inv;
    v4.x *= inv; v4.y *= inv; v4.z *= inv; v4.w *= inv;
    float sq = q4.x * q4.x + q4.y * q4.y + q4.z * q4.z + q4.w * q4.w;
    float sk = k4.x * k4.x + k4.y * k4.y + k4.z * k4.z + k4.w * k4.w;
    float sv = v4.x * v4.x + v4.y * v4.y + v4.z * v4.z + v4.w * v4.w;
#pragma unroll
    for (int off = 1; off < 16; off <<= 1) {
      sq += __shfl_xor(sq, off, 64);
      sk += __shfl_xor(sk, off, 64);
      sv += __shfl_xor(sv, off, 64);
    }
    if ((tid & 15) == 0) {
      invt[row]      = 1.0f / fmaxf(sqrtf(sq), 1e-12f);
      invt[16 + row] = 1.0f / fmaxf(sqrtf(sk), 1e-12f);
    }
    const float vinv = 1.0f / fmaxf(sqrtf(sv), 1e-12f);
    const float va[4] = {v4.x, v4.y, v4.z, v4.w};
#pragma unroll
    for (int j = 0; j < 4; ++j)
      Vt[((size_t)(bh * 64 + c4 + j)) * N_ + n] = f2bf(fabsf(va[j]) * vinv);
    ushort4 qh, ql, kh, kl;
    qh.x = f2bf(q4.x); ql.x = f2bf(q4.x - bf2f(qh.x));
    qh.y = f2bf(q4.y); ql.y = f2bf(q4.y - bf2f(qh.y));
    qh.z = f2bf(q4.z); ql.z = f2bf(q4.z - bf2f(qh.z));
    qh.w = f2bf(q4.w); ql.w = f2bf(q4.w - bf2f(qh.w));
    kh.x = f2bf(k4.x); kl.x = f2bf(k4.x - bf2f(kh.x));
    kh.y = f2bf(k4.y); kl.y = f2bf(k4.y - bf2f(kh.y));
    kh.z = f2bf(k4.z); kl.z = f2bf(k4.z - bf2f(kh.z));
    kh.w = f2bf(k4.w); kl.w = f2bf(k4.w - bf2f(kh.w));
    *(ushort4*)&Th[row][c4] = qh;      *(ushort4*)&Tl[row][c4] = ql;
    *(ushort4*)&Th[16 + row][c4] = kh; *(ushort4*)&Tl[16 + row][c4] = kl;
  }
  __syncthreads();

  const int rt = wv & 1;     // row-tile (16 rows)
  const int ch = wv >> 1;    // col-half / component selector

  // ---- layer 1: H = tanh(T @ Wp1 + b1)   [32 x 128]
  {
    short8 aT[2][2];
#pragma unroll
    for (int s = 0; s < 2; ++s) {
      aT[s][0] = *(const short8*)&Th[rt * 16 + l16][s * 32 + quad * 8];
      aT[s][1] = *(const short8*)&Tl[rt * 16 + l16][s * 32 + quad * 8];
    }
#pragma unroll
    for (int ct = 0; ct < 4; ++ct) {
      const int colg = ch * 64 + ct * 16 + l16;
      f32x4 c = {0.f, 0.f, 0.f, 0.f};
#pragma unroll
      for (int s = 0; s < 2; ++s) {
        short8 bh8 = *(const short8*)&W1s[(size_t)colg * 64 + s * 32 + quad * 8];
        short8 bl8 = *(const short8*)&W1s[8192 + (size_t)colg * 64 + s * 32 + quad * 8];
        c = __builtin_amdgcn_mfma_f32_16x16x32_bf16(aT[s][0], bh8, c, 0, 0, 0);
        c = __builtin_amdgcn_mfma_f32_16x16x32_bf16(aT[s][0], bl8, c, 0, 0, 0);
        c = __builtin_amdgcn_mfma_f32_16x16x32_bf16(aT[s][1], bh8, c, 0, 0, 0);
      }
      const float bb = bp1[colg];
#pragma unroll
      for (int r = 0; r < 4; ++r) {
        const int row = rt * 16 + quad * 4 + r;
        const float hv = fast_tanh(c[r] + bb);
        const ushort_t hh_ = f2bf(hv);
        Hh[row][colg] = hh_;
        Hl[row][colg] = f2bf(hv - bf2f(hh_));
      }
    }
  }
  __syncthreads();

  // ---- layer 2 + z: phase = tanh(H@Wp2 + b2)*pi; z = amp * e^{i*phase}
  {
    short8 aH[4][2];
#pragma unroll
    for (int s = 0; s < 4; ++s) {
      aH[s][0] = *(const short8*)&Hh[rt * 16 + l16][s * 32 + quad * 8];
      aH[s][1] = *(const short8*)&Hl[rt * 16 + l16][s * 32 + quad * 8];
    }
#pragma unroll
    for (int t2 = 0; t2 < 2; ++t2) {
      const int d = (ch * 2 + t2) * 16 + l16;
      f32x4 c = {0.f, 0.f, 0.f, 0.f};
#pragma unroll
      for (int s = 0; s < 4; ++s) {
        short8 bh8 = *(const short8*)&W2s[(size_t)d * 128 + s * 32 + quad * 8];
        short8 bl8 = *(const short8*)&W2s[8192 + (size_t)d * 128 + s * 32 + quad * 8];
        c = __builtin_amdgcn_mfma_f32_16x16x32_bf16(aH[s][0], bh8, c, 0, 0, 0);
        c = __builtin_amdgcn_mfma_f32_16x16x32_bf16(aH[s][0], bl8, c, 0, 0, 0);
        c = __builtin_amdgcn_mfma_f32_16x16x32_bf16(aH[s][1], bh8, c, 0, 0, 0);
      }
      const float b2v = bp2[d];
#pragma unroll
      for (int r = 0; r < 4; ++r) {
        const int row = rt * 16 + quad * 4 + r;
        const float ph = fast_tanh(c[r] + b2v) * PI_F;
        const float tv = bf2f(Th[row][d]) + bf2f(Tl[row][d]);
        const float amp = tv * invt[row];
        const float zr = amp * __cosf(ph);
        const float zi = amp * __sinf(ph);
        const ushort_t zrh = f2bf(zr);
        const ushort_t zih = f2bf(zi);
        Zrh[row][d] = zrh; Zrl[row][d] = f2bf(zr - bf2f(zrh));
        Zih[row][d] = zih; Zil[row][d] = f2bf(zi - bf2f(zih));
      }
    }
  }
  __syncthreads();

  // ---- flow: F = Z @ M (complex = 2 real GEMMs). F overwrites dead T/H.
  {
    const ushort_t (*Zh)[72] = ch ? Zih : Zrh;
    const ushort_t (*Zl)[72] = ch ? Zil : Zrl;
    float (*Fo)[68] = ch ? Fi : Fr;
    short8 aZ[2][2];
#pragma unroll
    for (int s = 0; s < 2; ++s) {
      aZ[s][0] = *(const short8*)&Zh[rt * 16 + l16][s * 32 + quad * 8];
      aZ[s][1] = *(const short8*)&Zl[rt * 16 + l16][s * 32 + quad * 8];
    }
#pragma unroll
    for (int ct = 0; ct < 4; ++ct) {
      const int colg = ct * 16 + l16;
      f32x4 c = {0.f, 0.f, 0.f, 0.f};
#pragma unroll
      for (int s = 0; s < 2; ++s) {
        short8 bh8 = *(const short8*)&Ms[(size_t)colg * 64 + s * 32 + quad * 8];
        short8 bl8 = *(const short8*)&Ms[4096 + (size_t)colg * 64 + s * 32 + quad * 8];
        c = __builtin_amdgcn_mfma_f32_16x16x32_bf16(aZ[s][0], bh8, c, 0, 0, 0);
        c = __builtin_amdgcn_mfma_f32_16x16x32_bf16(aZ[s][0], bl8, c, 0, 0, 0);
        c = __builtin_amdgcn_mfma_f32_16x16x32_bf16(aZ[s][1], bh8, c, 0, 0, 0);
      }
#pragma unroll
      for (int r = 0; r < 4; ++r)
        Fo[rt * 16 + quad * 4 + r][colg] = c[r];
    }
  }
  __syncthreads();

  // ---- normalize + parallel transport + outputs (wave = 4 pairs, lane = d)
#pragma unroll
  for (int jj = 0; jj < 4; ++jj) {
    const int j = wv * 4 + jj;
    const int n = n0 + j;
    float qr = Fr[j][ln], qi = Fi[j][ln];
    float kr = Fr[16 + j][ln], ki = Fi[16 + j][ln];
    {
      const float s = wave_sum(fmaf(qr, qr, qi * qi));
      const float inv = 1.0f / fmaxf(sqrtf(s), 1e-12f);
      qr *= inv; qi *= inv;
    }
    {
      const float s = wave_sum(fmaf(kr, kr, ki * ki));
      const float inv = 1.0f / fmaxf(sqrtf(s), 1e-12f);
      kr *= inv; ki *= inv;
    }
    const size_t o = ((size_t)bh * N_ + n) * 128;
    Qc[o + ln]      = f2bf(qr);
    Qc[o + 64 + ln] = f2bf(qi);
    // transport: dist = csqrt(sum(diff^2)), tf = 1/(1+cexp(10*dist))
    const float dr = kr - qr, di = ki - qi;
    const float sr = wave_sum(fmaf(dr, dr, -di * di));
    const float si = wave_sum(2.0f * dr * di);
    const float rad = sqrtf(fmaf(sr, sr, si * si));
    const float ur = sqrtf(fmaxf((rad + sr) * 0.5f, 0.0f));
    const float ui = copysignf(sqrtf(fmaxf((rad - sr) * 0.5f, 0.0f)), si);
    const float er = __expf(10.0f * ur);
    const float exr = er * cosf(10.0f * ui);
    const float exi = er * sinf(10.0f * ui);
    const float dnr = 1.0f + exr, dni = exi;
    const float d2 = fmaf(dnr, dnr, dni * dni);
    const float tfr = dnr / d2, tfi = -dni / d2;
    const float omr = 1.0f - tfr, omi = -tfi;
    const float ktr = kr * tfr - ki * tfi + qr * omr - qi * omi;
    const float kti = kr * tfi + ki * tfr + qr * omi + qi * omr;
    const float s2 = wave_sum(fmaf(ktr, ktr, kti * kti));
    const float inv2 = 1.0f / fmaxf(sqrtf(s2), 1e-12f);
    Kc[o + ln]      = f2bf(ktr * inv2);
    Kc[o + 64 + ln] = f2bf(-kti * inv2);   // negated: S = qr.kr + qi.(-ki)
  }
}

// ---------------------------------------------------------------------------
// attention: bf16 MFMA flash (no running max; |logit| <= 0.125)
// ---------------------------------------------------------------------------
__global__ __launch_bounds__(256) void attn2(
    const unsigned short* __restrict__ Qc,
    const unsigned short* __restrict__ Kc,
    const unsigned short* __restrict__ Vt,
    float* __restrict__ out) {
  __shared__ unsigned short Qs[64][136];
  __shared__ unsigned short Ks[64][136];
  __shared__ unsigned short Vs[64][72];
  __shared__ unsigned short Ps[64][72];
  const int tid = threadIdx.x;
  const int wv = tid >> 6, ln = tid & 63;
  const int l16 = ln & 15, quad = ln >> 4;
  const int bh = blockIdx.y;
  const int q0 = blockIdx.x * 64;
  const size_t qbase = ((size_t)bh * N_ + q0) * 128;
  for (int l = tid; l < 1024; l += 256) {
    const int r = l >> 4, c = l & 15;
    *(uint4*)&Qs[r][c * 8] = *(const uint4*)&Qc[qbase + (size_t)r * 128 + c * 8];
  }
  __syncthreads();
  short8 aq[4];
#pragma unroll
  for (int s = 0; s < 4; ++s)
    aq[s] = *(const short8*)&Qs[wv * 16 + l16][s * 32 + quad * 8];
  f32x4 acc_o[4];
#pragma unroll
  for (int d = 0; d < 4; ++d) acc_o[d] = {0.f, 0.f, 0.f, 0.f};
  float den[4] = {0.f, 0.f, 0.f, 0.f};

  for (int kt = 0; kt < N_ / 64; ++kt) {
    const int k0 = kt * 64;
    const size_t kbase = ((size_t)bh * N_ + k0) * 128;
    __syncthreads();
    for (int l = tid; l < 1024; l += 256) {
      const int r = l >> 4, c = l & 15;
      *(uint4*)&Ks[r][c * 8] = *(const uint4*)&Kc[kbase + (size_t)r * 128 + c * 8];
    }
    for (int l = tid; l < 512; l += 256) {
      const int d = l >> 3, c = l & 7;
      *(uint4*)&Vs[d][c * 8] =
          *(const uint4*)&Vt[((size_t)bh * 64 + d) * N_ + k0 + c * 8];
    }
    __syncthreads();
#pragma unroll
    for (int t = 0; t < 4; ++t) {
      f32x4 acc = {0.f, 0.f, 0.f, 0.f};
#pragma unroll
      for (int s = 0; s < 4; ++s) {
        short8 bk = *(const short8*)&Ks[t * 16 + l16][s * 32 + quad * 8];
        acc = __builtin_amdgcn_mfma_f32_16x16x32_bf16(aq[s], bk, acc, 0, 0, 0);
      }
#pragma unroll
      for (int r = 0; r < 4; ++r) {
        const float p = __expf(acc[r] * SCALE_F);
        den[r] += p;
        Ps[wv * 16 + quad * 4 + r][t * 16 + l16] = f2bf(p);
      }
    }
#pragma unroll
    for (int s2 = 0; s2 < 2; ++s2) {
      short8 ap = *(const short8*)&Ps[wv * 16 + l16][s2 * 32 + quad * 8];
#pragma unroll
      for (int dt = 0; dt < 4; ++dt) {
        short8 bv = *(const short8*)&Vs[dt * 16 + l16][s2 * 32 + quad * 8];
        acc_o[dt] = __builtin_amdgcn_mfma_f32_16x16x32_bf16(ap, bv, acc_o[dt], 0, 0, 0);
      }
    }
  }
#pragma unroll
  for (int r = 0; r < 4; ++r) {
    float d = den[r];
    d += __shfl_xor(d, 1, 64);
    d += __shfl_xor(d, 2, 64);
    d += __shfl_xor(d, 4, 64);
    d += __shfl_xor(d, 8, 64);
    den[r] = 1.0f / d;
  }
  const int b = bh >> 4, h = bh & 15;
#pragma unroll
  for (int dt = 0; dt < 4; ++dt) {
#pragma unroll
    for (int r = 0; r < 4; ++r) {
      const int qg = q0 + wv * 16 + quad * 4 + r;
      out[(((size_t)b * N_ + qg) * H_ + h) * HD_ + dt * 16 + l16] = acc_o[dt][r] * den[r];
    }
  }
}

// ---------------------------------------------------------------------------
extern "C" void kernel_launch(void* const* d_in, const int* in_sizes, int n_in,
                              void* d_out, int out_size, void* d_ws, size_t ws_size,
                              hipStream_t stream) {
  const float* x    = (const float*)d_in[0];
  const float* Wqkv = (const float*)d_in[1];
  const float* bqkv = (const float*)d_in[2];
  const float* Wp1  = (const float*)d_in[3];
  const float* bp1  = (const float*)d_in[4];
  const float* Wp2  = (const float*)d_in[5];
  const float* bp2  = (const float*)d_in[6];
  const float* Wf   = (const float*)d_in[7];
  float* out = (float*)d_out;

  char* w = (char*)d_ws;
  float* qkv = (float*)w;               w += (size_t)ROWS * TDIM * 4;
  float* invn = (float*)w;              w += (size_t)ROWS * 4;
  ushort_t* Ms  = (ushort_t*)w;         w += 2 * 4096 * 2;
  ushort_t* W1s = (ushort_t*)w;         w += 2 * 8192 * 2;
  ushort_t* W2s = (ushort_t*)w;         w += 2 * 8192 * 2;
  unsigned short* Xs = (unsigned short*)w; w += (size_t)ROWS * 2048 * 2;
  unsigned short* Wt = (unsigned short*)w; w += (size_t)TDIM * 2048 * 2;
  unsigned short* Qc = (unsigned short*)w; w += (size_t)32 * N_ * 128 * 2;
  unsigned short* Kc = (unsigned short*)w; w += (size_t)32 * N_ * 128 * 2;
  unsigned short* Vt = (unsigned short*)w; w += (size_t)32 * 64 * N_ * 2;

  hipLaunchKernelGGL(split_X, dim3(ROWS * 1024 / 4 / 256), dim3(256), 0, stream, x, Xs);
  hipLaunchKernelGGL(split_W, dim3(48, 16), dim3(256), 0, stream, Wqkv, Wt);
  hipLaunchKernelGGL(compute_M, dim3(1), dim3(256), 0, stream, Wf, Ms);
  hipLaunchKernelGGL(prep_w, dim3(1), dim3(256), 0, stream, Wp1, Wp2, W1s, W2s);
  hipLaunchKernelGGL(gemm2, dim3(24, 32), dim3(256), 0, stream, Xs, Wt, bqkv, qkv);
  hipLaunchKernelGGL(rownorm, dim3(ROWS), dim3(256), 0, stream, qkv, invn);
  hipLaunchKernelGGL(prep_mfma, dim3(4096), dim3(256), 0, stream,
                     qkv, invn, W1s, bp1, W2s, bp2, Ms, Qc, Kc, Vt);
  hipLaunchKernelGGL(attn2, dim3(N_ / 64, B_ * H_), dim3(256), 0, stream,
                     Qc, Kc, Vt, out);
}

// Round 4
// 522.189 us; speedup vs baseline: 3.4114x; 1.1867x over previous
//
#include <hip/hip_runtime.h>
#include <math.h>

#define B_    2
#define N_    2048
#define DIM_  1024
#define H_    16
#define HD_   64
#define TDIM  3072      // 3*DIM
#define ROWS  4096      // B*N
#define PI_F  3.14159265358979323846f
#define SCALE_F 0.125f

typedef short short8 __attribute__((ext_vector_type(8)));
typedef float f32x4 __attribute__((ext_vector_type(4)));
typedef float f32x16 __attribute__((ext_vector_type(16)));
typedef unsigned u32x4 __attribute__((ext_vector_type(4)));
typedef unsigned short ushort_t;

__device__ __forceinline__ float wave_sum(float v) {
#pragma unroll
  for (int off = 32; off > 0; off >>= 1) v += __shfl_xor(v, off, 64);
  return v;
}

__device__ __forceinline__ unsigned short f2bf(float x) {
  unsigned u = __float_as_uint(x);
  u += 0x7fffu + ((u >> 16) & 1u);   // RNE
  return (unsigned short)(u >> 16);
}
__device__ __forceinline__ float bf2f(unsigned short h) {
  return __uint_as_float(((unsigned)h) << 16);
}
// abs err ~1e-7 -- below bf16-split representation err
__device__ __forceinline__ float fast_tanh(float x) {
  return 1.0f - 2.0f / (__expf(2.0f * x) + 1.0f);
}

// ---------------------------------------------------------------------------
// M = (I + 0.1*Wf)^10 (64x64); emit transposed split-bf16 Ms[2][64][64],
// Ms[h][n][k] = split(M[k][n]) for MFMA B-operand use.
// ---------------------------------------------------------------------------
__global__ __launch_bounds__(256) void compute_M(const float* __restrict__ Wf,
                                                 ushort_t* __restrict__ Ms) {
  __shared__ float A[4096], Mc[4096], Mn[4096];
  const int tid = threadIdx.x;
  for (int i = tid; i < 4096; i += 256) {
    float a = 0.1f * Wf[i] + (((i >> 6) == (i & 63)) ? 1.0f : 0.0f);
    A[i] = a; Mc[i] = a;
  }
  __syncthreads();
  for (int it = 0; it < 9; ++it) {
    for (int i = tid; i < 4096; i += 256) {
      const int r = i >> 6, c = i & 63;
      float s = 0.0f;
      for (int e = 0; e < 64; ++e) s = fmaf(Mc[r * 64 + e], A[e * 64 + c], s);
      Mn[i] = s;
    }
    __syncthreads();
    for (int i = tid; i < 4096; i += 256) Mc[i] = Mn[i];
    __syncthreads();
  }
  for (int i = tid; i < 4096; i += 256) {
    const int n = i >> 6, k = i & 63;
    const float v = Mc[k * 64 + n];
    const ushort_t hi = f2bf(v);
    Ms[i] = hi; Ms[4096 + i] = f2bf(v - bf2f(hi));
  }
}

// ---------------------------------------------------------------------------
// split/transpose the phase-MLP weights
// ---------------------------------------------------------------------------
__global__ __launch_bounds__(256) void prep_w(const float* __restrict__ Wp1,
                                              const float* __restrict__ Wp2,
                                              ushort_t* __restrict__ W1s,
                                              ushort_t* __restrict__ W2s) {
  const int tid = threadIdx.x;
  for (int i = tid; i < 8192; i += 256) {
    const int n = i >> 6, k = i & 63;
    const float v = Wp1[k * 128 + n];
    const ushort_t hi = f2bf(v);
    W1s[i] = hi; W1s[8192 + i] = f2bf(v - bf2f(hi));
  }
  for (int i = tid; i < 8192; i += 256) {
    const int n = i >> 7, k = i & 127;
    const float v = Wp2[k * 64 + n];
    const ushort_t hi = f2bf(v);
    W2s[i] = hi; W2s[8192 + i] = f2bf(v - bf2f(hi));
  }
}

// ---------------------------------------------------------------------------
// split fp32 -> bf16 hi/lo.  Xs[m][0..1023]=hi, [1024..2047]=lo
// ---------------------------------------------------------------------------
__global__ __launch_bounds__(256) void split_X(const float* __restrict__ X,
                                               unsigned short* __restrict__ Xs) {
  const int gid = blockIdx.x * 256 + threadIdx.x;
  const int m = gid >> 8, c = (gid & 255) * 4;
  float4 v = *(const float4*)&X[(size_t)m * 1024 + c];
  ushort4 hi, lo;
  hi.x = f2bf(v.x); lo.x = f2bf(v.x - bf2f(hi.x));
  hi.y = f2bf(v.y); lo.y = f2bf(v.y - bf2f(hi.y));
  hi.z = f2bf(v.z); lo.z = f2bf(v.z - bf2f(hi.z));
  hi.w = f2bf(v.w); lo.w = f2bf(v.w - bf2f(hi.w));
  *(ushort4*)&Xs[(size_t)m * 2048 + c] = hi;
  *(ushort4*)&Xs[(size_t)m * 2048 + 1024 + c] = lo;
}

// W[1024][3072] -> Wt[3072][2048] (n-major; cols 0..1023 hi, 1024..2047 lo)
__global__ __launch_bounds__(256) void split_W(const float* __restrict__ W,
                                               unsigned short* __restrict__ Wt) {
  __shared__ float T[64][68];
  const int n0 = blockIdx.x * 64, k0 = blockIdx.y * 64;
  const int tid = threadIdx.x;
  for (int l = tid; l < 1024; l += 256) {
    const int r = l >> 4, c = (l & 15) * 4;
    *(float4*)&T[r][c] = *(const float4*)&W[(size_t)(k0 + r) * TDIM + n0 + c];
  }
  __syncthreads();
  const int n = tid >> 2, q = (tid & 3) * 16;
  alignas(16) unsigned short hi16[16];
  alignas(16) unsigned short lo16[16];
#pragma unroll
  for (int j = 0; j < 16; ++j) {
    const float v = T[q + j][n];
    const unsigned short h = f2bf(v);
    hi16[j] = h; lo16[j] = f2bf(v - bf2f(h));
  }
  unsigned short* dst = &Wt[(size_t)(n0 + n) * 2048];
  *(uint4*)&dst[k0 + q]          = *(uint4*)&hi16[0];
  *(uint4*)&dst[k0 + q + 8]      = *(uint4*)&hi16[8];
  *(uint4*)&dst[1024 + k0 + q]     = *(uint4*)&lo16[0];
  *(uint4*)&dst[1024 + k0 + q + 8] = *(uint4*)&lo16[8];
}

// ---------------------------------------------------------------------------
// qkv = x @ Wqkv + bqkv via split-bf16 MFMA, K'=3072 (hh + hl + lh)
// ---------------------------------------------------------------------------
__global__ __launch_bounds__(256) void gemm2(const unsigned short* __restrict__ Xs,
                                             const unsigned short* __restrict__ Wt,
                                             const float* __restrict__ bias,
                                             float* __restrict__ C) {
  __shared__ unsigned short As[128][40];
  __shared__ unsigned short Bs[128][40];
  const int tid = threadIdx.x;
  const int wv = tid >> 6, ln = tid & 63;
  const int l16 = ln & 15, quad = ln >> 4;
  const int wrow = wv >> 1, wcol = wv & 1;
  const int row0 = blockIdx.y * 128, col0 = blockIdx.x * 128;
  const int sr = tid >> 1;
  const int sc = (tid & 1) * 2;
  f32x4 acc[4][4];
#pragma unroll
  for (int i = 0; i < 4; ++i)
#pragma unroll
    for (int j = 0; j < 4; ++j) acc[i][j] = {0.f, 0.f, 0.f, 0.f};
  for (int k0 = 0; k0 < 3072; k0 += 32) {
    const int acol = (k0 < 1024) ? k0 : k0 - 1024;   // hi, hi, lo
    const int bcol = (k0 < 2048) ? k0 : k0 - 2048;   // hi, lo, hi
    uint4 a0 = *(const uint4*)&Xs[(size_t)(row0 + sr) * 2048 + acol + (sc + 0) * 8];
    uint4 a1 = *(const uint4*)&Xs[(size_t)(row0 + sr) * 2048 + acol + (sc + 1) * 8];
    uint4 b0 = *(const uint4*)&Wt[(size_t)(col0 + sr) * 2048 + bcol + (sc + 0) * 8];
    uint4 b1 = *(const uint4*)&Wt[(size_t)(col0 + sr) * 2048 + bcol + (sc + 1) * 8];
    __syncthreads();
    *(uint4*)&As[sr][(sc + 0) * 8] = a0;
    *(uint4*)&As[sr][(sc + 1) * 8] = a1;
    *(uint4*)&Bs[sr][(sc + 0) * 8] = b0;
    *(uint4*)&Bs[sr][(sc + 1) * 8] = b1;
    __syncthreads();
    short8 af[4], bfr[4];
#pragma unroll
    for (int mi = 0; mi < 4; ++mi)
      af[mi] = *(const short8*)&As[wrow * 64 + mi * 16 + l16][quad * 8];
#pragma unroll
    for (int ni = 0; ni < 4; ++ni)
      bfr[ni] = *(const short8*)&Bs[wcol * 64 + ni * 16 + l16][quad * 8];
#pragma unroll
    for (int mi = 0; mi < 4; ++mi)
#pragma unroll
      for (int ni = 0; ni < 4; ++ni)
        acc[mi][ni] = __builtin_amdgcn_mfma_f32_16x16x32_bf16(af[mi], bfr[ni], acc[mi][ni], 0, 0, 0);
  }
#pragma unroll
  for (int ni = 0; ni < 4; ++ni) {
    const int col = col0 + wcol * 64 + ni * 16 + l16;
    const float bb = bias[col];
#pragma unroll
    for (int mi = 0; mi < 4; ++mi) {
#pragma unroll
      for (int r = 0; r < 4; ++r) {
        const int row = row0 + wrow * 64 + mi * 16 + quad * 4 + r;
        C[(size_t)row * TDIM + col] = acc[mi][ni][r] + bb;
      }
    }
  }
}

// ---------------------------------------------------------------------------
// inv row norm over 3072
// ---------------------------------------------------------------------------
__global__ __launch_bounds__(256) void rownorm(const float* __restrict__ qkv,
                                               float* __restrict__ invn) {
  const int row = blockIdx.x;
  const float4* rp = (const float4*)(qkv + (size_t)row * TDIM);
  float s = 0.f;
  for (int c = threadIdx.x; c < TDIM / 4; c += 256) {
    float4 v = rp[c];
    s += v.x * v.x + v.y * v.y + v.z * v.z + v.w * v.w;
  }
  s = wave_sum(s);
  __shared__ float red[4];
  if ((threadIdx.x & 63) == 0) red[threadIdx.x >> 6] = s;
  __syncthreads();
  if (threadIdx.x == 0) {
    float t = red[0] + red[1] + red[2] + red[3];
    invn[row] = 1.0f / fmaxf(sqrtf(t), 1e-12f);
  }
}

// ---------------------------------------------------------------------------
// prep (MFMA version) -- unchanged from round 3
// ---------------------------------------------------------------------------
__global__ __launch_bounds__(256) void prep_mfma(
    const float* __restrict__ qkv, const float* __restrict__ invn,
    const ushort_t* __restrict__ W1s, const float* __restrict__ bp1,
    const ushort_t* __restrict__ W2s, const float* __restrict__ bp2,
    const ushort_t* __restrict__ Ms,
    ushort_t* __restrict__ Qc, ushort_t* __restrict__ Kc,
    ushort_t* __restrict__ Vt) {
  __shared__ __align__(16) char smem[45184];
  ushort_t (*Th)[72]  = (ushort_t(*)[72])(smem + 0);
  ushort_t (*Tl)[72]  = (ushort_t(*)[72])(smem + 4608);
  ushort_t (*Hh)[136] = (ushort_t(*)[136])(smem + 9216);
  ushort_t (*Hl)[136] = (ushort_t(*)[136])(smem + 17920);
  ushort_t (*Zrh)[72] = (ushort_t(*)[72])(smem + 26624);
  ushort_t (*Zrl)[72] = (ushort_t(*)[72])(smem + 31232);
  ushort_t (*Zih)[72] = (ushort_t(*)[72])(smem + 35840);
  ushort_t (*Zil)[72] = (ushort_t(*)[72])(smem + 40448);
  float (*Fr)[68] = (float(*)[68])(smem + 0);
  float (*Fi)[68] = (float(*)[68])(smem + 8704);
  float* invt = (float*)(smem + 45056);

  const int tid = threadIdx.x;
  const int wv = tid >> 6, ln = tid & 63;
  const int l16 = ln & 15, quad = ln >> 4;
  const int g0 = blockIdx.x * 16;
  const int bh = g0 >> 11, n0 = g0 & 2047;
  const int b = bh >> 4, h = bh & 15;

  {
    const int row = tid >> 4;
    const int c4 = (tid & 15) * 4;
    const int n = n0 + row;
    const size_t base = ((size_t)(b * N_ + n)) * TDIM + h * HD_;
    const float inv = invn[b * N_ + n];
    float4 q4 = *(const float4*)&qkv[base + c4];
    float4 k4 = *(const float4*)&qkv[base + 1024 + c4];
    float4 v4 = *(const float4*)&qkv[base + 2048 + c4];
    q4.x *= inv; q4.y *= inv; q4.z *= inv; q4.w *= inv;
    k4.x *= inv; k4.y *= inv; k4.z *= inv; k4.w *= inv;
    v4.x *= inv; v4.y *= inv; v4.z *= inv; v4.w *= inv;
    float sq = q4.x * q4.x + q4.y * q4.y + q4.z * q4.z + q4.w * q4.w;
    float sk = k4.x * k4.x + k4.y * k4.y + k4.z * k4.z + k4.w * k4.w;
    float sv = v4.x * v4.x + v4.y * v4.y + v4.z * v4.z + v4.w * v4.w;
#pragma unroll
    for (int off = 1; off < 16; off <<= 1) {
      sq += __shfl_xor(sq, off, 64);
      sk += __shfl_xor(sk, off, 64);
      sv += __shfl_xor(sv, off, 64);
    }
    if ((tid & 15) == 0) {
      invt[row]      = 1.0f / fmaxf(sqrtf(sq), 1e-12f);
      invt[16 + row] = 1.0f / fmaxf(sqrtf(sk), 1e-12f);
    }
    const float vinv = 1.0f / fmaxf(sqrtf(sv), 1e-12f);
    const float va[4] = {v4.x, v4.y, v4.z, v4.w};
#pragma unroll
    for (int j = 0; j < 4; ++j)
      Vt[((size_t)(bh * 64 + c4 + j)) * N_ + n] = f2bf(fabsf(va[j]) * vinv);
    ushort4 qh, ql, kh, kl;
    qh.x = f2bf(q4.x); ql.x = f2bf(q4.x - bf2f(qh.x));
    qh.y = f2bf(q4.y); ql.y = f2bf(q4.y - bf2f(qh.y));
    qh.z = f2bf(q4.z); ql.z = f2bf(q4.z - bf2f(qh.z));
    qh.w = f2bf(q4.w); ql.w = f2bf(q4.w - bf2f(qh.w));
    kh.x = f2bf(k4.x); kl.x = f2bf(k4.x - bf2f(kh.x));
    kh.y = f2bf(k4.y); kl.y = f2bf(k4.y - bf2f(kh.y));
    kh.z = f2bf(k4.z); kl.z = f2bf(k4.z - bf2f(kh.z));
    kh.w = f2bf(k4.w); kl.w = f2bf(k4.w - bf2f(kh.w));
    *(ushort4*)&Th[row][c4] = qh;      *(ushort4*)&Tl[row][c4] = ql;
    *(ushort4*)&Th[16 + row][c4] = kh; *(ushort4*)&Tl[16 + row][c4] = kl;
  }
  __syncthreads();

  const int rt = wv & 1;
  const int ch = wv >> 1;

  {
    short8 aT[2][2];
#pragma unroll
    for (int s = 0; s < 2; ++s) {
      aT[s][0] = *(const short8*)&Th[rt * 16 + l16][s * 32 + quad * 8];
      aT[s][1] = *(const short8*)&Tl[rt * 16 + l16][s * 32 + quad * 8];
    }
#pragma unroll
    for (int ct = 0; ct < 4; ++ct) {
      const int colg = ch * 64 + ct * 16 + l16;
      f32x4 c = {0.f, 0.f, 0.f, 0.f};
#pragma unroll
      for (int s = 0; s < 2; ++s) {
        short8 bh8 = *(const short8*)&W1s[(size_t)colg * 64 + s * 32 + quad * 8];
        short8 bl8 = *(const short8*)&W1s[8192 + (size_t)colg * 64 + s * 32 + quad * 8];
        c = __builtin_amdgcn_mfma_f32_16x16x32_bf16(aT[s][0], bh8, c, 0, 0, 0);
        c = __builtin_amdgcn_mfma_f32_16x16x32_bf16(aT[s][0], bl8, c, 0, 0, 0);
        c = __builtin_amdgcn_mfma_f32_16x16x32_bf16(aT[s][1], bh8, c, 0, 0, 0);
      }
      const float bb = bp1[colg];
#pragma unroll
      for (int r = 0; r < 4; ++r) {
        const int row = rt * 16 + quad * 4 + r;
        const float hv = fast_tanh(c[r] + bb);
        const ushort_t hh_ = f2bf(hv);
        Hh[row][colg] = hh_;
        Hl[row][colg] = f2bf(hv - bf2f(hh_));
      }
    }
  }
  __syncthreads();

  {
    short8 aH[4][2];
#pragma unroll
    for (int s = 0; s < 4; ++s) {
      aH[s][0] = *(const short8*)&Hh[rt * 16 + l16][s * 32 + quad * 8];
      aH[s][1] = *(const short8*)&Hl[rt * 16 + l16][s * 32 + quad * 8];
    }
#pragma unroll
    for (int t2 = 0; t2 < 2; ++t2) {
      const int d = (ch * 2 + t2) * 16 + l16;
      f32x4 c = {0.f, 0.f, 0.f, 0.f};
#pragma unroll
      for (int s = 0; s < 4; ++s) {
        short8 bh8 = *(const short8*)&W2s[(size_t)d * 128 + s * 32 + quad * 8];
        short8 bl8 = *(const short8*)&W2s[8192 + (size_t)d * 128 + s * 32 + quad * 8];
        c = __builtin_amdgcn_mfma_f32_16x16x32_bf16(aH[s][0], bh8, c, 0, 0, 0);
        c = __builtin_amdgcn_mfma_f32_16x16x32_bf16(aH[s][0], bl8, c, 0, 0, 0);
        c = __builtin_amdgcn_mfma_f32_16x16x32_bf16(aH[s][1], bh8, c, 0, 0, 0);
      }
      const float b2v = bp2[d];
#pragma unroll
      for (int r = 0; r < 4; ++r) {
        const int row = rt * 16 + quad * 4 + r;
        const float ph = fast_tanh(c[r] + b2v) * PI_F;
        const float tv = bf2f(Th[row][d]) + bf2f(Tl[row][d]);
        const float amp = tv * invt[row];
        const float zr = amp * __cosf(ph);
        const float zi = amp * __sinf(ph);
        const ushort_t zrh = f2bf(zr);
        const ushort_t zih = f2bf(zi);
        Zrh[row][d] = zrh; Zrl[row][d] = f2bf(zr - bf2f(zrh));
        Zih[row][d] = zih; Zil[row][d] = f2bf(zi - bf2f(zih));
      }
    }
  }
  __syncthreads();

  {
    const ushort_t (*Zh)[72] = ch ? Zih : Zrh;
    const ushort_t (*Zl)[72] = ch ? Zil : Zrl;
    float (*Fo)[68] = ch ? Fi : Fr;
    short8 aZ[2][2];
#pragma unroll
    for (int s = 0; s < 2; ++s) {
      aZ[s][0] = *(const short8*)&Zh[rt * 16 + l16][s * 32 + quad * 8];
      aZ[s][1] = *(const short8*)&Zl[rt * 16 + l16][s * 32 + quad * 8];
    }
#pragma unroll
    for (int ct = 0; ct < 4; ++ct) {
      const int colg = ct * 16 + l16;
      f32x4 c = {0.f, 0.f, 0.f, 0.f};
#pragma unroll
      for (int s = 0; s < 2; ++s) {
        short8 bh8 = *(const short8*)&Ms[(size_t)colg * 64 + s * 32 + quad * 8];
        short8 bl8 = *(const short8*)&Ms[4096 + (size_t)colg * 64 + s * 32 + quad * 8];
        c = __builtin_amdgcn_mfma_f32_16x16x32_bf16(aZ[s][0], bh8, c, 0, 0, 0);
        c = __builtin_amdgcn_mfma_f32_16x16x32_bf16(aZ[s][0], bl8, c, 0, 0, 0);
        c = __builtin_amdgcn_mfma_f32_16x16x32_bf16(aZ[s][1], bh8, c, 0, 0, 0);
      }
#pragma unroll
      for (int r = 0; r < 4; ++r)
        Fo[rt * 16 + quad * 4 + r][colg] = c[r];
    }
  }
  __syncthreads();

#pragma unroll
  for (int jj = 0; jj < 4; ++jj) {
    const int j = wv * 4 + jj;
    const int n = n0 + j;
    float qr = Fr[j][ln], qi = Fi[j][ln];
    float kr = Fr[16 + j][ln], ki = Fi[16 + j][ln];
    {
      const float s = wave_sum(fmaf(qr, qr, qi * qi));
      const float inv = 1.0f / fmaxf(sqrtf(s), 1e-12f);
      qr *= inv; qi *= inv;
    }
    {
      const float s = wave_sum(fmaf(kr, kr, ki * ki));
      const float inv = 1.0f / fmaxf(sqrtf(s), 1e-12f);
      kr *= inv; ki *= inv;
    }
    const size_t o = ((size_t)bh * N_ + n) * 128;
    Qc[o + ln]      = f2bf(qr);
    Qc[o + 64 + ln] = f2bf(qi);
    const float dr = kr - qr, di = ki - qi;
    const float sr = wave_sum(fmaf(dr, dr, -di * di));
    const float si = wave_sum(2.0f * dr * di);
    const float rad = sqrtf(fmaf(sr, sr, si * si));
    const float ur = sqrtf(fmaxf((rad + sr) * 0.5f, 0.0f));
    const float ui = copysignf(sqrtf(fmaxf((rad - sr) * 0.5f, 0.0f)), si);
    const float er = __expf(10.0f * ur);
    const float exr = er * cosf(10.0f * ui);
    const float exi = er * sinf(10.0f * ui);
    const float dnr = 1.0f + exr, dni = exi;
    const float d2 = fmaf(dnr, dnr, dni * dni);
    const float tfr = dnr / d2, tfi = -dni / d2;
    const float omr = 1.0f - tfr, omi = -tfi;
    const float ktr = kr * tfr - ki * tfi + qr * omr - qi * omi;
    const float kti = kr * tfi + ki * tfr + qr * omi + qi * omr;
    const float s2 = wave_sum(fmaf(ktr, ktr, kti * kti));
    const float inv2 = 1.0f / fmaxf(sqrtf(s2), 1e-12f);
    Kc[o + ln]      = f2bf(ktr * inv2);
    Kc[o + 64 + ln] = f2bf(-kti * inv2);   // negated: S = qr.kr + qi.(-ki)
  }
}

// ---------------------------------------------------------------------------
// attn3: 32x32x16 MFMA flash. Block = 128 q; wave (qh,kh) = 64 q x key-half.
// A=K / B=Q(regs) for S  ->  P lands with col=q = PV A-operand lane mapping;
// P->PV frag assembly via one shfl_xor(32), zero LDS for P.
// Ks/Vs: unpadded 256B pitch + chunk XOR swizzle (c ^= r&15) -> conflict-free.
// Partial O/den per key-half merged through LDS at the end.
// ---------------------------------------------------------------------------
__global__ __launch_bounds__(256, 2) void attn3(
    const ushort_t* __restrict__ Qc, const ushort_t* __restrict__ Kc,
    const ushort_t* __restrict__ Vt, float* __restrict__ out) {
  __shared__ __align__(16) char smem[35328];
  ushort_t* Ks = (ushort_t*)smem;              // [64][128] swizzled (16 KB)
  ushort_t* Vs = (ushort_t*)(smem + 16384);    // [64][128-slot] swizzled (16 KB)
  float (*Of)[68] = (float(*)[68])smem;        // merge: [128][68] f32 (34816 B)
  float* Dd = (float*)(smem + 34816);          // den[128]

  const int tid = threadIdx.x;
  const int wv = tid >> 6, ln = tid & 63;
  const int l31 = ln & 31, hi = ln >> 5;
  const int qh = wv & 1, kh = wv >> 1;
  const int bh = blockIdx.y;
  const int q0 = blockIdx.x * 128;
  const size_t hb = (size_t)bh * N_;

  // hoist Q B-frags: qf[nt][s], q = q0 + qh*64 + nt*32 + l31, d = s*16 + hi*8
  short8 qf[2][8];
#pragma unroll
  for (int nt = 0; nt < 2; ++nt) {
    const size_t qrow = (hb + q0 + qh * 64 + nt * 32 + l31) * 128;
#pragma unroll
    for (int s = 0; s < 8; ++s)
      qf[nt][s] = *(const short8*)&Qc[qrow + s * 16 + hi * 8];
  }

  f32x16 oacc[2][2];
#pragma unroll
  for (int i = 0; i < 2; ++i)
#pragma unroll
    for (int j = 0; j < 2; ++j)
#pragma unroll
      for (int r = 0; r < 16; ++r) oacc[i][j][r] = 0.f;
  float den[2] = {0.f, 0.f};

  const int rK = kh * 32 + l31;                 // this wave's K row in Ks
  for (int kt = 0; kt < N_ / 64; ++kt) {
    const size_t kbase = (hb + kt * 64) * 128;
    __syncthreads();
#pragma unroll
    for (int i = 0; i < 4; ++i) {               // stage K tile (64 x 128)
      const int l = tid + i * 256;
      const int r = l >> 4, c = l & 15;
      uint4 v = *(const uint4*)&Kc[kbase + (size_t)r * 128 + c * 8];
      *(uint4*)&Ks[r * 128 + ((c ^ (r & 15)) * 8)] = v;
    }
#pragma unroll
    for (int i = 0; i < 2; ++i) {               // stage V tile [d=64][key=64]
      const int l = tid + i * 256;
      const int r = l >> 3, c = l & 7;
      uint4 v = *(const uint4*)&Vt[((size_t)bh * 64 + r) * N_ + kt * 64 + c * 8];
      *(uint4*)&Vs[r * 128 + ((c ^ (r & 15)) * 8)] = v;
    }
    __syncthreads();

    // S: D[m=key(32)][n=q(32)] x2 n-tiles, K=128 over 8 steps
    f32x16 sacc[2];
#pragma unroll
    for (int nt = 0; nt < 2; ++nt)
#pragma unroll
      for (int r = 0; r < 16; ++r) sacc[nt][r] = 0.f;
#pragma unroll
    for (int s = 0; s < 8; ++s) {
      const int c = s * 2 + hi;
      short8 ak = *(const short8*)&Ks[rK * 128 + ((c ^ (rK & 15)) * 8)];
      sacc[0] = __builtin_amdgcn_mfma_f32_32x32x16_bf16(ak, qf[0][s], sacc[0], 0, 0, 0);
      sacc[1] = __builtin_amdgcn_mfma_f32_32x32x16_bf16(ak, qf[1][s], sacc[1], 0, 0, 0);
    }

    // P = exp(S/8); assemble PV A-frags in-register (shfl_xor lane^32)
    short8 pfrag[2][2];
#pragma unroll
    for (int nt = 0; nt < 2; ++nt) {
      float pv[16];
      float dl = 0.f;
#pragma unroll
      for (int r = 0; r < 16; ++r) {
        pv[r] = __expf(sacc[nt][r] * SCALE_F);
        dl += pv[r];
      }
      den[nt] += dl;
      unsigned u8a[8], pu[8];
#pragma unroll
      for (int t = 0; t < 8; ++t)
        u8a[t] = (unsigned)f2bf(pv[2 * t]) | ((unsigned)f2bf(pv[2 * t + 1]) << 16);
#pragma unroll
      for (int t = 0; t < 8; ++t)
        pu[t] = (unsigned)__shfl_xor((int)u8a[t], 32, 64);
#pragma unroll
      for (int s2 = 0; s2 < 2; ++s2) {
        u32x4 fu;
        if (hi == 0) {
          fu[0] = u8a[4 * s2]; fu[1] = u8a[4 * s2 + 1];
          fu[2] = pu[4 * s2];  fu[3] = pu[4 * s2 + 1];
        } else {
          fu[0] = pu[4 * s2 + 2];  fu[1] = pu[4 * s2 + 3];
          fu[2] = u8a[4 * s2 + 2]; fu[3] = u8a[4 * s2 + 3];
        }
        pfrag[nt][s2] = __builtin_bit_cast(short8, fu);
      }
    }

    // PV: D[m=q][n=d], keys of this wave's half-tile
#pragma unroll
    for (int s2 = 0; s2 < 2; ++s2) {
#pragma unroll
      for (int dt = 0; dt < 2; ++dt) {
        const int rV = dt * 32 + l31;
        const int c = kh * 4 + s2 * 2 + hi;
        short8 bv = *(const short8*)&Vs[rV * 128 + ((c ^ (rV & 15)) * 8)];
        oacc[0][dt] = __builtin_amdgcn_mfma_f32_32x32x16_bf16(pfrag[0][s2], bv, oacc[0][dt], 0, 0, 0);
        oacc[1][dt] = __builtin_amdgcn_mfma_f32_32x32x16_bf16(pfrag[1][s2], bv, oacc[1][dt], 0, 0, 0);
      }
    }
  }

  // fold hi halves of den (same q, disjoint keys)
#pragma unroll
  for (int nt = 0; nt < 2; ++nt)
    den[nt] += __shfl_xor(den[nt], 32, 64);

  // merge the two key-halves through LDS
  __syncthreads();
  if (kh == 0) {
#pragma unroll
    for (int nt = 0; nt < 2; ++nt) {
#pragma unroll
      for (int dt = 0; dt < 2; ++dt)
#pragma unroll
        for (int r = 0; r < 16; ++r) {
          const int row = qh * 64 + nt * 32 + (r & 3) + 8 * (r >> 2) + 4 * hi;
          Of[row][dt * 32 + l31] = oacc[nt][dt][r];
        }
      if (hi == 0) Dd[qh * 64 + nt * 32 + l31] = den[nt];
    }
  }
  __syncthreads();
  if (kh == 1) {
#pragma unroll
    for (int nt = 0; nt < 2; ++nt) {
#pragma unroll
      for (int dt = 0; dt < 2; ++dt)
#pragma unroll
        for (int r = 0; r < 16; ++r) {
          const int row = qh * 64 + nt * 32 + (r & 3) + 8 * (r >> 2) + 4 * hi;
          Of[row][dt * 32 + l31] += oacc[nt][dt][r];
        }
      if (hi == 0) Dd[qh * 64 + nt * 32 + l31] += den[nt];
    }
  }
  __syncthreads();

  // coalesced store: thread -> (q = tid>>1, d-half = tid&1)
  {
    const int ql = tid >> 1, half = tid & 1;
    const int b = bh >> 4, h = bh & 15;
    const float invd = 1.0f / Dd[ql];
    float* op = &out[(((size_t)b * N_ + q0 + ql) * H_ + h) * HD_ + half * 32];
#pragma unroll
    for (int j = 0; j < 8; ++j) {
      float4 o = *(const float4*)&Of[ql][half * 32 + j * 4];
      o.x *= invd; o.y *= invd; o.z *= invd; o.w *= invd;
      *(float4*)&op[j * 4] = o;
    }
  }
}

// ---------------------------------------------------------------------------
extern "C" void kernel_launch(void* const* d_in, const int* in_sizes, int n_in,
                              void* d_out, int out_size, void* d_ws, size_t ws_size,
                              hipStream_t stream) {
  const float* x    = (const float*)d_in[0];
  const float* Wqkv = (const float*)d_in[1];
  const float* bqkv = (const float*)d_in[2];
  const float* Wp1  = (const float*)d_in[3];
  const float* bp1  = (const float*)d_in[4];
  const float* Wp2  = (const float*)d_in[5];
  const float* bp2  = (const float*)d_in[6];
  const float* Wf   = (const float*)d_in[7];
  float* out = (float*)d_out;

  char* w = (char*)d_ws;
  float* qkv = (float*)w;               w += (size_t)ROWS * TDIM * 4;
  float* invn = (float*)w;              w += (size_t)ROWS * 4;
  ushort_t* Ms  = (ushort_t*)w;         w += 2 * 4096 * 2;
  ushort_t* W1s = (ushort_t*)w;         w += 2 * 8192 * 2;
  ushort_t* W2s = (ushort_t*)w;         w += 2 * 8192 * 2;
  unsigned short* Xs = (unsigned short*)w; w += (size_t)ROWS * 2048 * 2;
  unsigned short* Wt = (unsigned short*)w; w += (size_t)TDIM * 2048 * 2;
  unsigned short* Qc = (unsigned short*)w; w += (size_t)32 * N_ * 128 * 2;
  unsigned short* Kc = (unsigned short*)w; w += (size_t)32 * N_ * 128 * 2;
  unsigned short* Vt = (unsigned short*)w; w += (size_t)32 * 64 * N_ * 2;

  hipLaunchKernelGGL(split_X, dim3(ROWS * 1024 / 4 / 256), dim3(256), 0, stream, x, Xs);
  hipLaunchKernelGGL(split_W, dim3(48, 16), dim3(256), 0, stream, Wqkv, Wt);
  hipLaunchKernelGGL(compute_M, dim3(1), dim3(256), 0, stream, Wf, Ms);
  hipLaunchKernelGGL(prep_w, dim3(1), dim3(256), 0, stream, Wp1, Wp2, W1s, W2s);
  hipLaunchKernelGGL(gemm2, dim3(24, 32), dim3(256), 0, stream, Xs, Wt, bqkv, qkv);
  hipLaunchKernelGGL(rownorm, dim3(ROWS), dim3(256), 0, stream, qkv, invn);
  hipLaunchKernelGGL(prep_mfma, dim3(4096), dim3(256), 0, stream,
                     qkv, invn, W1s, bp1, W2s, bp2, Ms, Qc, Kc, Vt);
  hipLaunchKernelGGL(attn3, dim3(N_ / 128, B_ * H_), dim3(256), 0, stream,
                     Qc, Kc, Vt, out);
}

// Round 5
// 503.470 us; speedup vs baseline: 3.5382x; 1.0372x over previous
//
#include <hip/hip_runtime.h>
#include <math.h>

#define B_    2
#define N_    2048
#define DIM_  1024
#define H_    16
#define HD_   64
#define TDIM  3072      // 3*DIM
#define ROWS  4096      // B*N
#define PI_F  3.14159265358979323846f
#define SCALE_F 0.125f

typedef short short8 __attribute__((ext_vector_type(8)));
typedef float f32x4 __attribute__((ext_vector_type(4)));
typedef float f32x16 __attribute__((ext_vector_type(16)));
typedef unsigned u32x4 __attribute__((ext_vector_type(4)));
typedef unsigned short ushort_t;

__device__ __forceinline__ float wave_sum(float v) {
#pragma unroll
  for (int off = 32; off > 0; off >>= 1) v += __shfl_xor(v, off, 64);
  return v;
}

__device__ __forceinline__ unsigned short f2bf(float x) {
  unsigned u = __float_as_uint(x);
  u += 0x7fffu + ((u >> 16) & 1u);   // RNE
  return (unsigned short)(u >> 16);
}
__device__ __forceinline__ float bf2f(unsigned short h) {
  return __uint_as_float(((unsigned)h) << 16);
}
// abs err ~1e-7 -- below bf16-split representation err
__device__ __forceinline__ float fast_tanh(float x) {
  return 1.0f - 2.0f / (__expf(2.0f * x) + 1.0f);
}

// async global->LDS, 16B per lane; LDS dest = wave-uniform base + lane*16
__device__ __forceinline__ void gl_lds16(const void* g, void* l) {
  __builtin_amdgcn_global_load_lds(
      (const __attribute__((address_space(1))) unsigned int*)g,
      (__attribute__((address_space(3))) unsigned int*)l, 16, 0, 0);
}

// ---------------------------------------------------------------------------
// M = (I + 0.1*Wf)^10 (64x64); emit transposed split-bf16 Ms[2][64][64],
// Ms[h][n][k] = split(M[k][n]) for MFMA B-operand use.
// ---------------------------------------------------------------------------
__global__ __launch_bounds__(256) void compute_M(const float* __restrict__ Wf,
                                                 ushort_t* __restrict__ Ms) {
  __shared__ float A[4096], Mc[4096], Mn[4096];
  const int tid = threadIdx.x;
  for (int i = tid; i < 4096; i += 256) {
    float a = 0.1f * Wf[i] + (((i >> 6) == (i & 63)) ? 1.0f : 0.0f);
    A[i] = a; Mc[i] = a;
  }
  __syncthreads();
  for (int it = 0; it < 9; ++it) {
    for (int i = tid; i < 4096; i += 256) {
      const int r = i >> 6, c = i & 63;
      float s = 0.0f;
      for (int e = 0; e < 64; ++e) s = fmaf(Mc[r * 64 + e], A[e * 64 + c], s);
      Mn[i] = s;
    }
    __syncthreads();
    for (int i = tid; i < 4096; i += 256) Mc[i] = Mn[i];
    __syncthreads();
  }
  for (int i = tid; i < 4096; i += 256) {
    const int n = i >> 6, k = i & 63;
    const float v = Mc[k * 64 + n];
    const ushort_t hi = f2bf(v);
    Ms[i] = hi; Ms[4096 + i] = f2bf(v - bf2f(hi));
  }
}

// ---------------------------------------------------------------------------
// split/transpose the phase-MLP weights
// ---------------------------------------------------------------------------
__global__ __launch_bounds__(256) void prep_w(const float* __restrict__ Wp1,
                                              const float* __restrict__ Wp2,
                                              ushort_t* __restrict__ W1s,
                                              ushort_t* __restrict__ W2s) {
  const int tid = threadIdx.x;
  for (int i = tid; i < 8192; i += 256) {
    const int n = i >> 6, k = i & 63;
    const float v = Wp1[k * 128 + n];
    const ushort_t hi = f2bf(v);
    W1s[i] = hi; W1s[8192 + i] = f2bf(v - bf2f(hi));
  }
  for (int i = tid; i < 8192; i += 256) {
    const int n = i >> 7, k = i & 127;
    const float v = Wp2[k * 64 + n];
    const ushort_t hi = f2bf(v);
    W2s[i] = hi; W2s[8192 + i] = f2bf(v - bf2f(hi));
  }
}

// ---------------------------------------------------------------------------
// split fp32 -> bf16 hi/lo.  Xs[m][0..1023]=hi, [1024..2047]=lo
// ---------------------------------------------------------------------------
__global__ __launch_bounds__(256) void split_X(const float* __restrict__ X,
                                               unsigned short* __restrict__ Xs) {
  const int gid = blockIdx.x * 256 + threadIdx.x;
  const int m = gid >> 8, c = (gid & 255) * 4;
  float4 v = *(const float4*)&X[(size_t)m * 1024 + c];
  ushort4 hi, lo;
  hi.x = f2bf(v.x); lo.x = f2bf(v.x - bf2f(hi.x));
  hi.y = f2bf(v.y); lo.y = f2bf(v.y - bf2f(hi.y));
  hi.z = f2bf(v.z); lo.z = f2bf(v.z - bf2f(hi.z));
  hi.w = f2bf(v.w); lo.w = f2bf(v.w - bf2f(hi.w));
  *(ushort4*)&Xs[(size_t)m * 2048 + c] = hi;
  *(ushort4*)&Xs[(size_t)m * 2048 + 1024 + c] = lo;
}

// W[1024][3072] -> Wt[3072][2048] (n-major; cols 0..1023 hi, 1024..2047 lo)
__global__ __launch_bounds__(256) void split_W(const float* __restrict__ W,
                                               unsigned short* __restrict__ Wt) {
  __shared__ float T[64][68];
  const int n0 = blockIdx.x * 64, k0 = blockIdx.y * 64;
  const int tid = threadIdx.x;
  for (int l = tid; l < 1024; l += 256) {
    const int r = l >> 4, c = (l & 15) * 4;
    *(float4*)&T[r][c] = *(const float4*)&W[(size_t)(k0 + r) * TDIM + n0 + c];
  }
  __syncthreads();
  const int n = tid >> 2, q = (tid & 3) * 16;
  alignas(16) unsigned short hi16[16];
  alignas(16) unsigned short lo16[16];
#pragma unroll
  for (int j = 0; j < 16; ++j) {
    const float v = T[q + j][n];
    const unsigned short h = f2bf(v);
    hi16[j] = h; lo16[j] = f2bf(v - bf2f(h));
  }
  unsigned short* dst = &Wt[(size_t)(n0 + n) * 2048];
  *(uint4*)&dst[k0 + q]          = *(uint4*)&hi16[0];
  *(uint4*)&dst[k0 + q + 8]      = *(uint4*)&hi16[8];
  *(uint4*)&dst[1024 + k0 + q]     = *(uint4*)&lo16[0];
  *(uint4*)&dst[1024 + k0 + q + 8] = *(uint4*)&lo16[8];
}

// ---------------------------------------------------------------------------
// gemm3 (m97-style): qkv = x @ Wqkv + bqkv, split-bf16 MFMA, virtual K=3072.
// 128x128 tile, BK=64, global_load_lds width=16 staging into unpadded
// row-major As/Bs[128][64] (layout forced by wave-uniform-base semantics).
// Per K-step per wave: 8 global_load_lds + 16 ds_read_b128 + 32 MFMA.
// A cols: [Xh | Xh | Xl] -> acol = k<1024 ? k : k-1024
// B cols: [Wh | Wl | Wh] -> bcol = k<2048 ? k : k-2048   (both BK-uniform)
// ---------------------------------------------------------------------------
__global__ __launch_bounds__(256) void gemm3(const unsigned short* __restrict__ Xs,
                                             const unsigned short* __restrict__ Wt,
                                             const float* __restrict__ bias,
                                             float* __restrict__ C) {
  __shared__ ushort_t As[128 * 64];   // 16 KB, row-major [row][64]
  __shared__ ushort_t Bs[128 * 64];   // 16 KB
  const int tid = threadIdx.x;
  const int wv = tid >> 6, ln = tid & 63;
  const int l16 = ln & 15, quad = ln >> 4;
  const int wrow = wv >> 1, wcol = wv & 1;
  const int row0 = blockIdx.y * 128, col0 = blockIdx.x * 128;
  // staging geometry: chunk ci = wv*4+i covers rows ci*8..ci*8+7 (1024 B)
  const int srow = ln >> 3;           // row within chunk (0..7)
  const int scol = (ln & 7) * 8;      // element col (0,8,..56)
  f32x4 acc[4][4];
#pragma unroll
  for (int i = 0; i < 4; ++i)
#pragma unroll
    for (int j = 0; j < 4; ++j) acc[i][j] = {0.f, 0.f, 0.f, 0.f};

  for (int k0 = 0; k0 < 3072; k0 += 64) {
    const int acol = (k0 < 1024) ? k0 : k0 - 1024;
    const int bcol = (k0 < 2048) ? k0 : k0 - 2048;
    __syncthreads();   // all waves done reading As/Bs of prev step
#pragma unroll
    for (int i = 0; i < 4; ++i) {
      const int ci = wv * 4 + i;
      const int r = ci * 8 + srow;
      gl_lds16(&Xs[(size_t)(row0 + r) * 2048 + acol + scol],
               (char*)As + ci * 1024);
      gl_lds16(&Wt[(size_t)(col0 + r) * 2048 + bcol + scol],
               (char*)Bs + ci * 1024);
    }
    __syncthreads();   // drains vmcnt -> staged data visible
    short8 af[4][2], bf[4][2];
#pragma unroll
    for (int kk = 0; kk < 2; ++kk) {
#pragma unroll
      for (int mi = 0; mi < 4; ++mi)
        af[mi][kk] = *(const short8*)&As[(wrow * 64 + mi * 16 + l16) * 64 + kk * 32 + quad * 8];
#pragma unroll
      for (int ni = 0; ni < 4; ++ni)
        bf[ni][kk] = *(const short8*)&Bs[(wcol * 64 + ni * 16 + l16) * 64 + kk * 32 + quad * 8];
    }
#pragma unroll
    for (int kk = 0; kk < 2; ++kk)
#pragma unroll
      for (int mi = 0; mi < 4; ++mi)
#pragma unroll
        for (int ni = 0; ni < 4; ++ni)
          acc[mi][ni] = __builtin_amdgcn_mfma_f32_16x16x32_bf16(af[mi][kk], bf[ni][kk], acc[mi][ni], 0, 0, 0);
  }
#pragma unroll
  for (int ni = 0; ni < 4; ++ni) {
    const int col = col0 + wcol * 64 + ni * 16 + l16;
    const float bb = bias[col];
#pragma unroll
    for (int mi = 0; mi < 4; ++mi) {
#pragma unroll
      for (int r = 0; r < 4; ++r) {
        const int row = row0 + wrow * 64 + mi * 16 + quad * 4 + r;
        C[(size_t)row * TDIM + col] = acc[mi][ni][r] + bb;
      }
    }
  }
}

// ---------------------------------------------------------------------------
// inv row norm over 3072
// ---------------------------------------------------------------------------
__global__ __launch_bounds__(256) void rownorm(const float* __restrict__ qkv,
                                               float* __restrict__ invn) {
  const int row = blockIdx.x;
  const float4* rp = (const float4*)(qkv + (size_t)row * TDIM);
  float s = 0.f;
  for (int c = threadIdx.x; c < TDIM / 4; c += 256) {
    float4 v = rp[c];
    s += v.x * v.x + v.y * v.y + v.z * v.z + v.w * v.w;
  }
  s = wave_sum(s);
  __shared__ float red[4];
  if ((threadIdx.x & 63) == 0) red[threadIdx.x >> 6] = s;
  __syncthreads();
  if (threadIdx.x == 0) {
    float t = red[0] + red[1] + red[2] + red[3];
    invn[row] = 1.0f / fmaxf(sqrtf(t), 1e-12f);
  }
}

// ---------------------------------------------------------------------------
// prep (MFMA version) -- unchanged
// ---------------------------------------------------------------------------
__global__ __launch_bounds__(256) void prep_mfma(
    const float* __restrict__ qkv, const float* __restrict__ invn,
    const ushort_t* __restrict__ W1s, const float* __restrict__ bp1,
    const ushort_t* __restrict__ W2s, const float* __restrict__ bp2,
    const ushort_t* __restrict__ Ms,
    ushort_t* __restrict__ Qc, ushort_t* __restrict__ Kc,
    ushort_t* __restrict__ Vt) {
  __shared__ __align__(16) char smem[45184];
  ushort_t (*Th)[72]  = (ushort_t(*)[72])(smem + 0);
  ushort_t (*Tl)[72]  = (ushort_t(*)[72])(smem + 4608);
  ushort_t (*Hh)[136] = (ushort_t(*)[136])(smem + 9216);
  ushort_t (*Hl)[136] = (ushort_t(*)[136])(smem + 17920);
  ushort_t (*Zrh)[72] = (ushort_t(*)[72])(smem + 26624);
  ushort_t (*Zrl)[72] = (ushort_t(*)[72])(smem + 31232);
  ushort_t (*Zih)[72] = (ushort_t(*)[72])(smem + 35840);
  ushort_t (*Zil)[72] = (ushort_t(*)[72])(smem + 40448);
  float (*Fr)[68] = (float(*)[68])(smem + 0);
  float (*Fi)[68] = (float(*)[68])(smem + 8704);
  float* invt = (float*)(smem + 45056);

  const int tid = threadIdx.x;
  const int wv = tid >> 6, ln = tid & 63;
  const int l16 = ln & 15, quad = ln >> 4;
  const int g0 = blockIdx.x * 16;
  const int bh = g0 >> 11, n0 = g0 & 2047;
  const int b = bh >> 4, h = bh & 15;

  {
    const int row = tid >> 4;
    const int c4 = (tid & 15) * 4;
    const int n = n0 + row;
    const size_t base = ((size_t)(b * N_ + n)) * TDIM + h * HD_;
    const float inv = invn[b * N_ + n];
    float4 q4 = *(const float4*)&qkv[base + c4];
    float4 k4 = *(const float4*)&qkv[base + 1024 + c4];
    float4 v4 = *(const float4*)&qkv[base + 2048 + c4];
    q4.x *= inv; q4.y *= inv; q4.z *= inv; q4.w *= inv;
    k4.x *= inv; k4.y *= inv; k4.z *= inv; k4.w *= inv;
    v4.x *= inv; v4.y *= inv; v4.z *= inv; v4.w *= inv;
    float sq = q4.x * q4.x + q4.y * q4.y + q4.z * q4.z + q4.w * q4.w;
    float sk = k4.x * k4.x + k4.y * k4.y + k4.z * k4.z + k4.w * k4.w;
    float sv = v4.x * v4.x + v4.y * v4.y + v4.z * v4.z + v4.w * v4.w;
#pragma unroll
    for (int off = 1; off < 16; off <<= 1) {
      sq += __shfl_xor(sq, off, 64);
      sk += __shfl_xor(sk, off, 64);
      sv += __shfl_xor(sv, off, 64);
    }
    if ((tid & 15) == 0) {
      invt[row]      = 1.0f / fmaxf(sqrtf(sq), 1e-12f);
      invt[16 + row] = 1.0f / fmaxf(sqrtf(sk), 1e-12f);
    }
    const float vinv = 1.0f / fmaxf(sqrtf(sv), 1e-12f);
    const float va[4] = {v4.x, v4.y, v4.z, v4.w};
#pragma unroll
    for (int j = 0; j < 4; ++j)
      Vt[((size_t)(bh * 64 + c4 + j)) * N_ + n] = f2bf(fabsf(va[j]) * vinv);
    ushort4 qh, ql, kh, kl;
    qh.x = f2bf(q4.x); ql.x = f2bf(q4.x - bf2f(qh.x));
    qh.y = f2bf(q4.y); ql.y = f2bf(q4.y - bf2f(qh.y));
    qh.z = f2bf(q4.z); ql.z = f2bf(q4.z - bf2f(qh.z));
    qh.w = f2bf(q4.w); ql.w = f2bf(q4.w - bf2f(qh.w));
    kh.x = f2bf(k4.x); kl.x = f2bf(k4.x - bf2f(kh.x));
    kh.y = f2bf(k4.y); kl.y = f2bf(k4.y - bf2f(kh.y));
    kh.z = f2bf(k4.z); kl.z = f2bf(k4.z - bf2f(kh.z));
    kh.w = f2bf(k4.w); kl.w = f2bf(k4.w - bf2f(kh.w));
    *(ushort4*)&Th[row][c4] = qh;      *(ushort4*)&Tl[row][c4] = ql;
    *(ushort4*)&Th[16 + row][c4] = kh; *(ushort4*)&Tl[16 + row][c4] = kl;
  }
  __syncthreads();

  const int rt = wv & 1;
  const int ch = wv >> 1;

  {
    short8 aT[2][2];
#pragma unroll
    for (int s = 0; s < 2; ++s) {
      aT[s][0] = *(const short8*)&Th[rt * 16 + l16][s * 32 + quad * 8];
      aT[s][1] = *(const short8*)&Tl[rt * 16 + l16][s * 32 + quad * 8];
    }
#pragma unroll
    for (int ct = 0; ct < 4; ++ct) {
      const int colg = ch * 64 + ct * 16 + l16;
      f32x4 c = {0.f, 0.f, 0.f, 0.f};
#pragma unroll
      for (int s = 0; s < 2; ++s) {
        short8 bh8 = *(const short8*)&W1s[(size_t)colg * 64 + s * 32 + quad * 8];
        short8 bl8 = *(const short8*)&W1s[8192 + (size_t)colg * 64 + s * 32 + quad * 8];
        c = __builtin_amdgcn_mfma_f32_16x16x32_bf16(aT[s][0], bh8, c, 0, 0, 0);
        c = __builtin_amdgcn_mfma_f32_16x16x32_bf16(aT[s][0], bl8, c, 0, 0, 0);
        c = __builtin_amdgcn_mfma_f32_16x16x32_bf16(aT[s][1], bh8, c, 0, 0, 0);
      }
      const float bb = bp1[colg];
#pragma unroll
      for (int r = 0; r < 4; ++r) {
        const int row = rt * 16 + quad * 4 + r;
        const float hv = fast_tanh(c[r] + bb);
        const ushort_t hh_ = f2bf(hv);
        Hh[row][colg] = hh_;
        Hl[row][colg] = f2bf(hv - bf2f(hh_));
      }
    }
  }
  __syncthreads();

  {
    short8 aH[4][2];
#pragma unroll
    for (int s = 0; s < 4; ++s) {
      aH[s][0] = *(const short8*)&Hh[rt * 16 + l16][s * 32 + quad * 8];
      aH[s][1] = *(const short8*)&Hl[rt * 16 + l16][s * 32 + quad * 8];
    }
#pragma unroll
    for (int t2 = 0; t2 < 2; ++t2) {
      const int d = (ch * 2 + t2) * 16 + l16;
      f32x4 c = {0.f, 0.f, 0.f, 0.f};
#pragma unroll
      for (int s = 0; s < 4; ++s) {
        short8 bh8 = *(const short8*)&W2s[(size_t)d * 128 + s * 32 + quad * 8];
        short8 bl8 = *(const short8*)&W2s[8192 + (size_t)d * 128 + s * 32 + quad * 8];
        c = __builtin_amdgcn_mfma_f32_16x16x32_bf16(aH[s][0], bh8, c, 0, 0, 0);
        c = __builtin_amdgcn_mfma_f32_16x16x32_bf16(aH[s][0], bl8, c, 0, 0, 0);
        c = __builtin_amdgcn_mfma_f32_16x16x32_bf16(aH[s][1], bh8, c, 0, 0, 0);
      }
      const float b2v = bp2[d];
#pragma unroll
      for (int r = 0; r < 4; ++r) {
        const int row = rt * 16 + quad * 4 + r;
        const float ph = fast_tanh(c[r] + b2v) * PI_F;
        const float tv = bf2f(Th[row][d]) + bf2f(Tl[row][d]);
        const float amp = tv * invt[row];
        const float zr = amp * __cosf(ph);
        const float zi = amp * __sinf(ph);
        const ushort_t zrh = f2bf(zr);
        const ushort_t zih = f2bf(zi);
        Zrh[row][d] = zrh; Zrl[row][d] = f2bf(zr - bf2f(zrh));
        Zih[row][d] = zih; Zil[row][d] = f2bf(zi - bf2f(zih));
      }
    }
  }
  __syncthreads();

  {
    const ushort_t (*Zh)[72] = ch ? Zih : Zrh;
    const ushort_t (*Zl)[72] = ch ? Zil : Zrl;
    float (*Fo)[68] = ch ? Fi : Fr;
    short8 aZ[2][2];
#pragma unroll
    for (int s = 0; s < 2; ++s) {
      aZ[s][0] = *(const short8*)&Zh[rt * 16 + l16][s * 32 + quad * 8];
      aZ[s][1] = *(const short8*)&Zl[rt * 16 + l16][s * 32 + quad * 8];
    }
#pragma unroll
    for (int ct = 0; ct < 4; ++ct) {
      const int colg = ct * 16 + l16;
      f32x4 c = {0.f, 0.f, 0.f, 0.f};
#pragma unroll
      for (int s = 0; s < 2; ++s) {
        short8 bh8 = *(const short8*)&Ms[(size_t)colg * 64 + s * 32 + quad * 8];
        short8 bl8 = *(const short8*)&Ms[4096 + (size_t)colg * 64 + s * 32 + quad * 8];
        c = __builtin_amdgcn_mfma_f32_16x16x32_bf16(aZ[s][0], bh8, c, 0, 0, 0);
        c = __builtin_amdgcn_mfma_f32_16x16x32_bf16(aZ[s][0], bl8, c, 0, 0, 0);
        c = __builtin_amdgcn_mfma_f32_16x16x32_bf16(aZ[s][1], bh8, c, 0, 0, 0);
      }
#pragma unroll
      for (int r = 0; r < 4; ++r)
        Fo[rt * 16 + quad * 4 + r][colg] = c[r];
    }
  }
  __syncthreads();

#pragma unroll
  for (int jj = 0; jj < 4; ++jj) {
    const int j = wv * 4 + jj;
    const int n = n0 + j;
    float qr = Fr[j][ln], qi = Fi[j][ln];
    float kr = Fr[16 + j][ln], ki = Fi[16 + j][ln];
    {
      const float s = wave_sum(fmaf(qr, qr, qi * qi));
      const float inv = 1.0f / fmaxf(sqrtf(s), 1e-12f);
      qr *= inv; qi *= inv;
    }
    {
      const float s = wave_sum(fmaf(kr, kr, ki * ki));
      const float inv = 1.0f / fmaxf(sqrtf(s), 1e-12f);
      kr *= inv; ki *= inv;
    }
    const size_t o = ((size_t)bh * N_ + n) * 128;
    Qc[o + ln]      = f2bf(qr);
    Qc[o + 64 + ln] = f2bf(qi);
    const float dr = kr - qr, di = ki - qi;
    const float sr = wave_sum(fmaf(dr, dr, -di * di));
    const float si = wave_sum(2.0f * dr * di);
    const float rad = sqrtf(fmaf(sr, sr, si * si));
    const float ur = sqrtf(fmaxf((rad + sr) * 0.5f, 0.0f));
    const float ui = copysignf(sqrtf(fmaxf((rad - sr) * 0.5f, 0.0f)), si);
    const float er = __expf(10.0f * ur);
    const float exr = er * cosf(10.0f * ui);
    const float exi = er * sinf(10.0f * ui);
    const float dnr = 1.0f + exr, dni = exi;
    const float d2 = fmaf(dnr, dnr, dni * dni);
    const float tfr = dnr / d2, tfi = -dni / d2;
    const float omr = 1.0f - tfr, omi = -tfi;
    const float ktr = kr * tfr - ki * tfi + qr * omr - qi * omi;
    const float kti = kr * tfi + ki * tfr + qr * omi + qi * omr;
    const float s2 = wave_sum(fmaf(ktr, ktr, kti * kti));
    const float inv2 = 1.0f / fmaxf(sqrtf(s2), 1e-12f);
    Kc[o + ln]      = f2bf(ktr * inv2);
    Kc[o + 64 + ln] = f2bf(-kti * inv2);   // negated: S = qr.kr + qi.(-ki)
  }
}

// ---------------------------------------------------------------------------
// attn3: 32x32x16 MFMA flash -- unchanged from round 4
// ---------------------------------------------------------------------------
__global__ __launch_bounds__(256, 2) void attn3(
    const ushort_t* __restrict__ Qc, const ushort_t* __restrict__ Kc,
    const ushort_t* __restrict__ Vt, float* __restrict__ out) {
  __shared__ __align__(16) char smem[35328];
  ushort_t* Ks = (ushort_t*)smem;              // [64][128] swizzled (16 KB)
  ushort_t* Vs = (ushort_t*)(smem + 16384);    // [64][128-slot] swizzled (16 KB)
  float (*Of)[68] = (float(*)[68])smem;        // merge: [128][68] f32
  float* Dd = (float*)(smem + 34816);          // den[128]

  const int tid = threadIdx.x;
  const int wv = tid >> 6, ln = tid & 63;
  const int l31 = ln & 31, hi = ln >> 5;
  const int qh = wv & 1, kh = wv >> 1;
  const int bh = blockIdx.y;
  const int q0 = blockIdx.x * 128;
  const size_t hb = (size_t)bh * N_;

  short8 qf[2][8];
#pragma unroll
  for (int nt = 0; nt < 2; ++nt) {
    const size_t qrow = (hb + q0 + qh * 64 + nt * 32 + l31) * 128;
#pragma unroll
    for (int s = 0; s < 8; ++s)
      qf[nt][s] = *(const short8*)&Qc[qrow + s * 16 + hi * 8];
  }

  f32x16 oacc[2][2];
#pragma unroll
  for (int i = 0; i < 2; ++i)
#pragma unroll
    for (int j = 0; j < 2; ++j)
#pragma unroll
      for (int r = 0; r < 16; ++r) oacc[i][j][r] = 0.f;
  float den[2] = {0.f, 0.f};

  const int rK = kh * 32 + l31;
  for (int kt = 0; kt < N_ / 64; ++kt) {
    const size_t kbase = (hb + kt * 64) * 128;
    __syncthreads();
#pragma unroll
    for (int i = 0; i < 4; ++i) {
      const int l = tid + i * 256;
      const int r = l >> 4, c = l & 15;
      uint4 v = *(const uint4*)&Kc[kbase + (size_t)r * 128 + c * 8];
      *(uint4*)&Ks[r * 128 + ((c ^ (r & 15)) * 8)] = v;
    }
#pragma unroll
    for (int i = 0; i < 2; ++i) {
      const int l = tid + i * 256;
      const int r = l >> 3, c = l & 7;
      uint4 v = *(const uint4*)&Vt[((size_t)bh * 64 + r) * N_ + kt * 64 + c * 8];
      *(uint4*)&Vs[r * 128 + ((c ^ (r & 15)) * 8)] = v;
    }
    __syncthreads();

    f32x16 sacc[2];
#pragma unroll
    for (int nt = 0; nt < 2; ++nt)
#pragma unroll
      for (int r = 0; r < 16; ++r) sacc[nt][r] = 0.f;
#pragma unroll
    for (int s = 0; s < 8; ++s) {
      const int c = s * 2 + hi;
      short8 ak = *(const short8*)&Ks[rK * 128 + ((c ^ (rK & 15)) * 8)];
      sacc[0] = __builtin_amdgcn_mfma_f32_32x32x16_bf16(ak, qf[0][s], sacc[0], 0, 0, 0);
      sacc[1] = __builtin_amdgcn_mfma_f32_32x32x16_bf16(ak, qf[1][s], sacc[1], 0, 0, 0);
    }

    short8 pfrag[2][2];
#pragma unroll
    for (int nt = 0; nt < 2; ++nt) {
      float pv[16];
      float dl = 0.f;
#pragma unroll
      for (int r = 0; r < 16; ++r) {
        pv[r] = __expf(sacc[nt][r] * SCALE_F);
        dl += pv[r];
      }
      den[nt] += dl;
      unsigned u8a[8], pu[8];
#pragma unroll
      for (int t = 0; t < 8; ++t)
        u8a[t] = (unsigned)f2bf(pv[2 * t]) | ((unsigned)f2bf(pv[2 * t + 1]) << 16);
#pragma unroll
      for (int t = 0; t < 8; ++t)
        pu[t] = (unsigned)__shfl_xor((int)u8a[t], 32, 64);
#pragma unroll
      for (int s2 = 0; s2 < 2; ++s2) {
        u32x4 fu;
        if (hi == 0) {
          fu[0] = u8a[4 * s2]; fu[1] = u8a[4 * s2 + 1];
          fu[2] = pu[4 * s2];  fu[3] = pu[4 * s2 + 1];
        } else {
          fu[0] = pu[4 * s2 + 2];  fu[1] = pu[4 * s2 + 3];
          fu[2] = u8a[4 * s2 + 2]; fu[3] = u8a[4 * s2 + 3];
        }
        pfrag[nt][s2] = __builtin_bit_cast(short8, fu);
      }
    }

#pragma unroll
    for (int s2 = 0; s2 < 2; ++s2) {
#pragma unroll
      for (int dt = 0; dt < 2; ++dt) {
        const int rV = dt * 32 + l31;
        const int c = kh * 4 + s2 * 2 + hi;
        short8 bv = *(const short8*)&Vs[rV * 128 + ((c ^ (rV & 15)) * 8)];
        oacc[0][dt] = __builtin_amdgcn_mfma_f32_32x32x16_bf16(pfrag[0][s2], bv, oacc[0][dt], 0, 0, 0);
        oacc[1][dt] = __builtin_amdgcn_mfma_f32_32x32x16_bf16(pfrag[1][s2], bv, oacc[1][dt], 0, 0, 0);
      }
    }
  }

#pragma unroll
  for (int nt = 0; nt < 2; ++nt)
    den[nt] += __shfl_xor(den[nt], 32, 64);

  __syncthreads();
  if (kh == 0) {
#pragma unroll
    for (int nt = 0; nt < 2; ++nt) {
#pragma unroll
      for (int dt = 0; dt < 2; ++dt)
#pragma unroll
        for (int r = 0; r < 16; ++r) {
          const int row = qh * 64 + nt * 32 + (r & 3) + 8 * (r >> 2) + 4 * hi;
          Of[row][dt * 32 + l31] = oacc[nt][dt][r];
        }
      if (hi == 0) Dd[qh * 64 + nt * 32 + l31] = den[nt];
    }
  }
  __syncthreads();
  if (kh == 1) {
#pragma unroll
    for (int nt = 0; nt < 2; ++nt) {
#pragma unroll
      for (int dt = 0; dt < 2; ++dt)
#pragma unroll
        for (int r = 0; r < 16; ++r) {
          const int row = qh * 64 + nt * 32 + (r & 3) + 8 * (r >> 2) + 4 * hi;
          Of[row][dt * 32 + l31] += oacc[nt][dt][r];
        }
      if (hi == 0) Dd[qh * 64 + nt * 32 + l31] += den[nt];
    }
  }
  __syncthreads();

  {
    const int ql = tid >> 1, half = tid & 1;
    const int b = bh >> 4, h = bh & 15;
    const float invd = 1.0f / Dd[ql];
    float* op = &out[(((size_t)b * N_ + q0 + ql) * H_ + h) * HD_ + half * 32];
#pragma unroll
    for (int j = 0; j < 8; ++j) {
      float4 o = *(const float4*)&Of[ql][half * 32 + j * 4];
      o.x *= invd; o.y *= invd; o.z *= invd; o.w *= invd;
      *(float4*)&op[j * 4] = o;
    }
  }
}

// ---------------------------------------------------------------------------
extern "C" void kernel_launch(void* const* d_in, const int* in_sizes, int n_in,
                              void* d_out, int out_size, void* d_ws, size_t ws_size,
                              hipStream_t stream) {
  const float* x    = (const float*)d_in[0];
  const float* Wqkv = (const float*)d_in[1];
  const float* bqkv = (const float*)d_in[2];
  const float* Wp1  = (const float*)d_in[3];
  const float* bp1  = (const float*)d_in[4];
  const float* Wp2  = (const float*)d_in[5];
  const float* bp2  = (const float*)d_in[6];
  const float* Wf   = (const float*)d_in[7];
  float* out = (float*)d_out;

  char* w = (char*)d_ws;
  float* qkv = (float*)w;               w += (size_t)ROWS * TDIM * 4;
  float* invn = (float*)w;              w += (size_t)ROWS * 4;
  ushort_t* Ms  = (ushort_t*)w;         w += 2 * 4096 * 2;
  ushort_t* W1s = (ushort_t*)w;         w += 2 * 8192 * 2;
  ushort_t* W2s = (ushort_t*)w;         w += 2 * 8192 * 2;
  unsigned short* Xs = (unsigned short*)w; w += (size_t)ROWS * 2048 * 2;
  unsigned short* Wt = (unsigned short*)w; w += (size_t)TDIM * 2048 * 2;
  unsigned short* Qc = (unsigned short*)w; w += (size_t)32 * N_ * 128 * 2;
  unsigned short* Kc = (unsigned short*)w; w += (size_t)32 * N_ * 128 * 2;
  unsigned short* Vt = (unsigned short*)w; w += (size_t)32 * 64 * N_ * 2;

  hipLaunchKernelGGL(split_X, dim3(ROWS * 1024 / 4 / 256), dim3(256), 0, stream, x, Xs);
  hipLaunchKernelGGL(split_W, dim3(48, 16), dim3(256), 0, stream, Wqkv, Wt);
  hipLaunchKernelGGL(compute_M, dim3(1), dim3(256), 0, stream, Wf, Ms);
  hipLaunchKernelGGL(prep_w, dim3(1), dim3(256), 0, stream, Wp1, Wp2, W1s, W2s);
  hipLaunchKernelGGL(gemm3, dim3(24, 32), dim3(256), 0, stream, Xs, Wt, bqkv, qkv);
  hipLaunchKernelGGL(rownorm, dim3(ROWS), dim3(256), 0, stream, qkv, invn);
  hipLaunchKernelGGL(prep_mfma, dim3(4096), dim3(256), 0, stream,
                     qkv, invn, W1s, bp1, W2s, bp2, Ms, Qc, Kc, Vt);
  hipLaunchKernelGGL(attn3, dim3(N_ / 128, B_ * H_), dim3(256), 0, stream,
                     Qc, Kc, Vt, out);
}

// Round 6
// 482.037 us; speedup vs baseline: 3.6955x; 1.0445x over previous
//
#include <hip/hip_runtime.h>
#include <math.h>

#define B_    2
#define N_    2048
#define DIM_  1024
#define H_    16
#define HD_   64
#define TDIM  3072      // 3*DIM
#define ROWS  4096      // B*N
#define PI_F  3.14159265358979323846f
#define SCALE_F 0.125f

typedef short short8 __attribute__((ext_vector_type(8)));
typedef float f32x4 __attribute__((ext_vector_type(4)));
typedef float f32x16 __attribute__((ext_vector_type(16)));
typedef unsigned u32x4 __attribute__((ext_vector_type(4)));
typedef unsigned short ushort_t;

__device__ __forceinline__ float wave_sum(float v) {
#pragma unroll
  for (int off = 32; off > 0; off >>= 1) v += __shfl_xor(v, off, 64);
  return v;
}

__device__ __forceinline__ unsigned short f2bf(float x) {
  unsigned u = __float_as_uint(x);
  u += 0x7fffu + ((u >> 16) & 1u);   // RNE
  return (unsigned short)(u >> 16);
}
__device__ __forceinline__ float bf2f(unsigned short h) {
  return __uint_as_float(((unsigned)h) << 16);
}
// abs err ~1e-7 -- below bf16-split representation err
__device__ __forceinline__ float fast_tanh(float x) {
  return 1.0f - 2.0f / (__expf(2.0f * x) + 1.0f);
}

// async global->LDS, 16B per lane; LDS dest = wave-uniform base + lane*16
__device__ __forceinline__ void gl_lds16(const void* g, void* l) {
  __builtin_amdgcn_global_load_lds(
      (const __attribute__((address_space(1))) unsigned int*)g,
      (__attribute__((address_space(3))) unsigned int*)l, 16, 0, 0);
}

// ---------------------------------------------------------------------------
// zero the per-row sumsq accumulator (gemm4 epilogue atomics land here)
// ---------------------------------------------------------------------------
__global__ __launch_bounds__(256) void zero_sumsq(float* __restrict__ s) {
  const int i = threadIdx.x;
#pragma unroll
  for (int j = 0; j < 16; ++j) s[j * 256 + i] = 0.0f;
}

// ---------------------------------------------------------------------------
// M = (I + 0.1*Wf)^10 (64x64); emit transposed split-bf16 Ms[2][64][64],
// Ms[h][n][k] = split(M[k][n]) for MFMA B-operand use.
// ---------------------------------------------------------------------------
__global__ __launch_bounds__(256) void compute_M(const float* __restrict__ Wf,
                                                 ushort_t* __restrict__ Ms) {
  __shared__ float A[4096], Mc[4096], Mn[4096];
  const int tid = threadIdx.x;
  for (int i = tid; i < 4096; i += 256) {
    float a = 0.1f * Wf[i] + (((i >> 6) == (i & 63)) ? 1.0f : 0.0f);
    A[i] = a; Mc[i] = a;
  }
  __syncthreads();
  for (int it = 0; it < 9; ++it) {
    for (int i = tid; i < 4096; i += 256) {
      const int r = i >> 6, c = i & 63;
      float s = 0.0f;
      for (int e = 0; e < 64; ++e) s = fmaf(Mc[r * 64 + e], A[e * 64 + c], s);
      Mn[i] = s;
    }
    __syncthreads();
    for (int i = tid; i < 4096; i += 256) Mc[i] = Mn[i];
    __syncthreads();
  }
  for (int i = tid; i < 4096; i += 256) {
    const int n = i >> 6, k = i & 63;
    const float v = Mc[k * 64 + n];
    const ushort_t hi = f2bf(v);
    Ms[i] = hi; Ms[4096 + i] = f2bf(v - bf2f(hi));
  }
}

// ---------------------------------------------------------------------------
// split/transpose the phase-MLP weights
// ---------------------------------------------------------------------------
__global__ __launch_bounds__(256) void prep_w(const float* __restrict__ Wp1,
                                              const float* __restrict__ Wp2,
                                              ushort_t* __restrict__ W1s,
                                              ushort_t* __restrict__ W2s) {
  const int tid = threadIdx.x;
  for (int i = tid; i < 8192; i += 256) {
    const int n = i >> 6, k = i & 63;
    const float v = Wp1[k * 128 + n];
    const ushort_t hi = f2bf(v);
    W1s[i] = hi; W1s[8192 + i] = f2bf(v - bf2f(hi));
  }
  for (int i = tid; i < 8192; i += 256) {
    const int n = i >> 7, k = i & 127;
    const float v = Wp2[k * 64 + n];
    const ushort_t hi = f2bf(v);
    W2s[i] = hi; W2s[8192 + i] = f2bf(v - bf2f(hi));
  }
}

// ---------------------------------------------------------------------------
// split fp32 -> bf16 hi/lo.  Xs[m][0..1023]=hi, [1024..2047]=lo
// ---------------------------------------------------------------------------
__global__ __launch_bounds__(256) void split_X(const float* __restrict__ X,
                                               unsigned short* __restrict__ Xs) {
  const int gid = blockIdx.x * 256 + threadIdx.x;
  const int m = gid >> 8, c = (gid & 255) * 4;
  float4 v = *(const float4*)&X[(size_t)m * 1024 + c];
  ushort4 hi, lo;
  hi.x = f2bf(v.x); lo.x = f2bf(v.x - bf2f(hi.x));
  hi.y = f2bf(v.y); lo.y = f2bf(v.y - bf2f(hi.y));
  hi.z = f2bf(v.z); lo.z = f2bf(v.z - bf2f(hi.z));
  hi.w = f2bf(v.w); lo.w = f2bf(v.w - bf2f(hi.w));
  *(ushort4*)&Xs[(size_t)m * 2048 + c] = hi;
  *(ushort4*)&Xs[(size_t)m * 2048 + 1024 + c] = lo;
}

// W[1024][3072] -> Wt[3072][2048] (n-major; cols 0..1023 hi, 1024..2047 lo)
__global__ __launch_bounds__(256) void split_W(const float* __restrict__ W,
                                               unsigned short* __restrict__ Wt) {
  __shared__ float T[64][68];
  const int n0 = blockIdx.x * 64, k0 = blockIdx.y * 64;
  const int tid = threadIdx.x;
  for (int l = tid; l < 1024; l += 256) {
    const int r = l >> 4, c = (l & 15) * 4;
    *(float4*)&T[r][c] = *(const float4*)&W[(size_t)(k0 + r) * TDIM + n0 + c];
  }
  __syncthreads();
  const int n = tid >> 2, q = (tid & 3) * 16;
  alignas(16) unsigned short hi16[16];
  alignas(16) unsigned short lo16[16];
#pragma unroll
  for (int j = 0; j < 16; ++j) {
    const float v = T[q + j][n];
    const unsigned short h = f2bf(v);
    hi16[j] = h; lo16[j] = f2bf(v - bf2f(h));
  }
  unsigned short* dst = &Wt[(size_t)(n0 + n) * 2048];
  *(uint4*)&dst[k0 + q]          = *(uint4*)&hi16[0];
  *(uint4*)&dst[k0 + q + 8]      = *(uint4*)&hi16[8];
  *(uint4*)&dst[1024 + k0 + q]     = *(uint4*)&lo16[0];
  *(uint4*)&dst[1024 + k0 + q + 8] = *(uint4*)&lo16[8];
}

// ---------------------------------------------------------------------------
// gemm4: m97-style + XOR bank swizzle + fused row-sumsq epilogue.
// LDS row r holds global 16B-group g at slot (g ^ (r&7)) -- achieved by
// having staging lane ln fetch global group (ln&7)^(ln>>3). Frag ds_read
// then hits all 8 4-bank groups (8 lanes each) = conflict-free optimum.
// Epilogue: C store + per-row sum(o^2) shfl-reduced over l16, one
// atomicAdd per (row, col-half) into sumsq[4096].
// ---------------------------------------------------------------------------
__global__ __launch_bounds__(256) void gemm4(const unsigned short* __restrict__ Xs,
                                             const unsigned short* __restrict__ Wt,
                                             const float* __restrict__ bias,
                                             float* __restrict__ C,
                                             float* __restrict__ sumsq) {
  __shared__ ushort_t As[128 * 64];   // 16 KB, row r / slot s: holds g = s^(r&7)
  __shared__ ushort_t Bs[128 * 64];   // 16 KB
  const int tid = threadIdx.x;
  const int wv = tid >> 6, ln = tid & 63;
  const int l16 = ln & 15, quad = ln >> 4;
  const int wrow = wv >> 1, wcol = wv & 1;
  const int row0 = blockIdx.y * 128, col0 = blockIdx.x * 128;
  const int srow = ln >> 3;           // row within chunk (0..7)
  const int sgrp = (ln & 7) ^ srow;   // swizzled global 16B-group index
  f32x4 acc[4][4];
#pragma unroll
  for (int i = 0; i < 4; ++i)
#pragma unroll
    for (int j = 0; j < 4; ++j) acc[i][j] = {0.f, 0.f, 0.f, 0.f};

  for (int k0 = 0; k0 < 3072; k0 += 64) {
    const int acol = (k0 < 1024) ? k0 : k0 - 1024;   // [Xh | Xh | Xl]
    const int bcol = (k0 < 2048) ? k0 : k0 - 2048;   // [Wh | Wl | Wh]
    __syncthreads();   // all waves done reading As/Bs of prev step
#pragma unroll
    for (int i = 0; i < 4; ++i) {
      const int ci = wv * 4 + i;
      const int r = ci * 8 + srow;
      gl_lds16(&Xs[(size_t)(row0 + r) * 2048 + acol + sgrp * 8],
               (char*)As + ci * 1024);
      gl_lds16(&Wt[(size_t)(col0 + r) * 2048 + bcol + sgrp * 8],
               (char*)Bs + ci * 1024);
    }
    __syncthreads();   // drains vmcnt -> staged data visible
    short8 af[4][2], bf[4][2];
#pragma unroll
    for (int kk = 0; kk < 2; ++kk) {
      const int g = kk * 4 + quad;
      const int slot = g ^ (l16 & 7);
#pragma unroll
      for (int mi = 0; mi < 4; ++mi)
        af[mi][kk] = *(const short8*)&As[(wrow * 64 + mi * 16 + l16) * 64 + slot * 8];
#pragma unroll
      for (int ni = 0; ni < 4; ++ni)
        bf[ni][kk] = *(const short8*)&Bs[(wcol * 64 + ni * 16 + l16) * 64 + slot * 8];
    }
#pragma unroll
    for (int kk = 0; kk < 2; ++kk)
#pragma unroll
      for (int mi = 0; mi < 4; ++mi)
#pragma unroll
        for (int ni = 0; ni < 4; ++ni)
          acc[mi][ni] = __builtin_amdgcn_mfma_f32_16x16x32_bf16(af[mi][kk], bf[ni][kk], acc[mi][ni], 0, 0, 0);
  }
  float ps[4][4];   // [mi][r] partial sum of squares over this thread's 4 cols
#pragma unroll
  for (int mi = 0; mi < 4; ++mi)
#pragma unroll
    for (int r = 0; r < 4; ++r) ps[mi][r] = 0.f;
#pragma unroll
  for (int ni = 0; ni < 4; ++ni) {
    const int col = col0 + wcol * 64 + ni * 16 + l16;
    const float bb = bias[col];
#pragma unroll
    for (int mi = 0; mi < 4; ++mi) {
#pragma unroll
      for (int r = 0; r < 4; ++r) {
        const int row = row0 + wrow * 64 + mi * 16 + quad * 4 + r;
        const float o = acc[mi][ni][r] + bb;
        C[(size_t)row * TDIM + col] = o;
        ps[mi][r] = fmaf(o, o, ps[mi][r]);
      }
    }
  }
#pragma unroll
  for (int mi = 0; mi < 4; ++mi) {
#pragma unroll
    for (int r = 0; r < 4; ++r) {
      float v = ps[mi][r];
      v += __shfl_xor(v, 1, 64);
      v += __shfl_xor(v, 2, 64);
      v += __shfl_xor(v, 4, 64);
      v += __shfl_xor(v, 8, 64);
      if (l16 == 0)
        atomicAdd(&sumsq[row0 + wrow * 64 + mi * 16 + quad * 4 + r], v);
    }
  }
}

// ---------------------------------------------------------------------------
// prep (MFMA version); row norm now computed inline from fused sumsq
// ---------------------------------------------------------------------------
__global__ __launch_bounds__(256) void prep_mfma(
    const float* __restrict__ qkv, const float* __restrict__ sumsq,
    const ushort_t* __restrict__ W1s, const float* __restrict__ bp1,
    const ushort_t* __restrict__ W2s, const float* __restrict__ bp2,
    const ushort_t* __restrict__ Ms,
    ushort_t* __restrict__ Qc, ushort_t* __restrict__ Kc,
    ushort_t* __restrict__ Vt) {
  __shared__ __align__(16) char smem[45184];
  ushort_t (*Th)[72]  = (ushort_t(*)[72])(smem + 0);
  ushort_t (*Tl)[72]  = (ushort_t(*)[72])(smem + 4608);
  ushort_t (*Hh)[136] = (ushort_t(*)[136])(smem + 9216);
  ushort_t (*Hl)[136] = (ushort_t(*)[136])(smem + 17920);
  ushort_t (*Zrh)[72] = (ushort_t(*)[72])(smem + 26624);
  ushort_t (*Zrl)[72] = (ushort_t(*)[72])(smem + 31232);
  ushort_t (*Zih)[72] = (ushort_t(*)[72])(smem + 35840);
  ushort_t (*Zil)[72] = (ushort_t(*)[72])(smem + 40448);
  float (*Fr)[68] = (float(*)[68])(smem + 0);
  float (*Fi)[68] = (float(*)[68])(smem + 8704);
  float* invt = (float*)(smem + 45056);

  const int tid = threadIdx.x;
  const int wv = tid >> 6, ln = tid & 63;
  const int l16 = ln & 15, quad = ln >> 4;
  const int g0 = blockIdx.x * 16;
  const int bh = g0 >> 11, n0 = g0 & 2047;
  const int b = bh >> 4, h = bh & 15;

  {
    const int row = tid >> 4;
    const int c4 = (tid & 15) * 4;
    const int n = n0 + row;
    const size_t base = ((size_t)(b * N_ + n)) * TDIM + h * HD_;
    const float ssq = sumsq[b * N_ + n];
    const float inv = 1.0f / fmaxf(sqrtf(ssq), 1e-12f);
    float4 q4 = *(const float4*)&qkv[base + c4];
    float4 k4 = *(const float4*)&qkv[base + 1024 + c4];
    float4 v4 = *(const float4*)&qkv[base + 2048 + c4];
    q4.x *= inv; q4.y *= inv; q4.z *= inv; q4.w *= inv;
    k4.x *= inv; k4.y *= inv; k4.z *= inv; k4.w *= inv;
    v4.x *= inv; v4.y *= inv; v4.z *= inv; v4.w *= inv;
    float sq = q4.x * q4.x + q4.y * q4.y + q4.z * q4.z + q4.w * q4.w;
    float sk = k4.x * k4.x + k4.y * k4.y + k4.z * k4.z + k4.w * k4.w;
    float sv = v4.x * v4.x + v4.y * v4.y + v4.z * v4.z + v4.w * v4.w;
#pragma unroll
    for (int off = 1; off < 16; off <<= 1) {
      sq += __shfl_xor(sq, off, 64);
      sk += __shfl_xor(sk, off, 64);
      sv += __shfl_xor(sv, off, 64);
    }
    if ((tid & 15) == 0) {
      invt[row]      = 1.0f / fmaxf(sqrtf(sq), 1e-12f);
      invt[16 + row] = 1.0f / fmaxf(sqrtf(sk), 1e-12f);
    }
    const float vinv = 1.0f / fmaxf(sqrtf(sv), 1e-12f);
    const float va[4] = {v4.x, v4.y, v4.z, v4.w};
#pragma unroll
    for (int j = 0; j < 4; ++j)
      Vt[((size_t)(bh * 64 + c4 + j)) * N_ + n] = f2bf(fabsf(va[j]) * vinv);
    ushort4 qh, ql, kh, kl;
    qh.x = f2bf(q4.x); ql.x = f2bf(q4.x - bf2f(qh.x));
    qh.y = f2bf(q4.y); ql.y = f2bf(q4.y - bf2f(qh.y));
    qh.z = f2bf(q4.z); ql.z = f2bf(q4.z - bf2f(qh.z));
    qh.w = f2bf(q4.w); ql.w = f2bf(q4.w - bf2f(qh.w));
    kh.x = f2bf(k4.x); kl.x = f2bf(k4.x - bf2f(kh.x));
    kh.y = f2bf(k4.y); kl.y = f2bf(k4.y - bf2f(kh.y));
    kh.z = f2bf(k4.z); kl.z = f2bf(k4.z - bf2f(kh.z));
    kh.w = f2bf(k4.w); kl.w = f2bf(k4.w - bf2f(kh.w));
    *(ushort4*)&Th[row][c4] = qh;      *(ushort4*)&Tl[row][c4] = ql;
    *(ushort4*)&Th[16 + row][c4] = kh; *(ushort4*)&Tl[16 + row][c4] = kl;
  }
  __syncthreads();

  const int rt = wv & 1;
  const int ch = wv >> 1;

  {
    short8 aT[2][2];
#pragma unroll
    for (int s = 0; s < 2; ++s) {
      aT[s][0] = *(const short8*)&Th[rt * 16 + l16][s * 32 + quad * 8];
      aT[s][1] = *(const short8*)&Tl[rt * 16 + l16][s * 32 + quad * 8];
    }
#pragma unroll
    for (int ct = 0; ct < 4; ++ct) {
      const int colg = ch * 64 + ct * 16 + l16;
      f32x4 c = {0.f, 0.f, 0.f, 0.f};
#pragma unroll
      for (int s = 0; s < 2; ++s) {
        short8 bh8 = *(const short8*)&W1s[(size_t)colg * 64 + s * 32 + quad * 8];
        short8 bl8 = *(const short8*)&W1s[8192 + (size_t)colg * 64 + s * 32 + quad * 8];
        c = __builtin_amdgcn_mfma_f32_16x16x32_bf16(aT[s][0], bh8, c, 0, 0, 0);
        c = __builtin_amdgcn_mfma_f32_16x16x32_bf16(aT[s][0], bl8, c, 0, 0, 0);
        c = __builtin_amdgcn_mfma_f32_16x16x32_bf16(aT[s][1], bh8, c, 0, 0, 0);
      }
      const float bb = bp1[colg];
#pragma unroll
      for (int r = 0; r < 4; ++r) {
        const int row = rt * 16 + quad * 4 + r;
        const float hv = fast_tanh(c[r] + bb);
        const ushort_t hh_ = f2bf(hv);
        Hh[row][colg] = hh_;
        Hl[row][colg] = f2bf(hv - bf2f(hh_));
      }
    }
  }
  __syncthreads();

  {
    short8 aH[4][2];
#pragma unroll
    for (int s = 0; s < 4; ++s) {
      aH[s][0] = *(const short8*)&Hh[rt * 16 + l16][s * 32 + quad * 8];
      aH[s][1] = *(const short8*)&Hl[rt * 16 + l16][s * 32 + quad * 8];
    }
#pragma unroll
    for (int t2 = 0; t2 < 2; ++t2) {
      const int d = (ch * 2 + t2) * 16 + l16;
      f32x4 c = {0.f, 0.f, 0.f, 0.f};
#pragma unroll
      for (int s = 0; s < 4; ++s) {
        short8 bh8 = *(const short8*)&W2s[(size_t)d * 128 + s * 32 + quad * 8];
        short8 bl8 = *(const short8*)&W2s[8192 + (size_t)d * 128 + s * 32 + quad * 8];
        c = __builtin_amdgcn_mfma_f32_16x16x32_bf16(aH[s][0], bh8, c, 0, 0, 0);
        c = __builtin_amdgcn_mfma_f32_16x16x32_bf16(aH[s][0], bl8, c, 0, 0, 0);
        c = __builtin_amdgcn_mfma_f32_16x16x32_bf16(aH[s][1], bh8, c, 0, 0, 0);
      }
      const float b2v = bp2[d];
#pragma unroll
      for (int r = 0; r < 4; ++r) {
        const int row = rt * 16 + quad * 4 + r;
        const float ph = fast_tanh(c[r] + b2v) * PI_F;
        const float tv = bf2f(Th[row][d]) + bf2f(Tl[row][d]);
        const float amp = tv * invt[row];
        const float zr = amp * __cosf(ph);
        const float zi = amp * __sinf(ph);
        const ushort_t zrh = f2bf(zr);
        const ushort_t zih = f2bf(zi);
        Zrh[row][d] = zrh; Zrl[row][d] = f2bf(zr - bf2f(zrh));
        Zih[row][d] = zih; Zil[row][d] = f2bf(zi - bf2f(zih));
      }
    }
  }
  __syncthreads();

  {
    const ushort_t (*Zh)[72] = ch ? Zih : Zrh;
    const ushort_t (*Zl)[72] = ch ? Zil : Zrl;
    float (*Fo)[68] = ch ? Fi : Fr;
    short8 aZ[2][2];
#pragma unroll
    for (int s = 0; s < 2; ++s) {
      aZ[s][0] = *(const short8*)&Zh[rt * 16 + l16][s * 32 + quad * 8];
      aZ[s][1] = *(const short8*)&Zl[rt * 16 + l16][s * 32 + quad * 8];
    }
#pragma unroll
    for (int ct = 0; ct < 4; ++ct) {
      const int colg = ct * 16 + l16;
      f32x4 c = {0.f, 0.f, 0.f, 0.f};
#pragma unroll
      for (int s = 0; s < 2; ++s) {
        short8 bh8 = *(const short8*)&Ms[(size_t)colg * 64 + s * 32 + quad * 8];
        short8 bl8 = *(const short8*)&Ms[4096 + (size_t)colg * 64 + s * 32 + quad * 8];
        c = __builtin_amdgcn_mfma_f32_16x16x32_bf16(aZ[s][0], bh8, c, 0, 0, 0);
        c = __builtin_amdgcn_mfma_f32_16x16x32_bf16(aZ[s][0], bl8, c, 0, 0, 0);
        c = __builtin_amdgcn_mfma_f32_16x16x32_bf16(aZ[s][1], bh8, c, 0, 0, 0);
      }
#pragma unroll
      for (int r = 0; r < 4; ++r)
        Fo[rt * 16 + quad * 4 + r][colg] = c[r];
    }
  }
  __syncthreads();

#pragma unroll
  for (int jj = 0; jj < 4; ++jj) {
    const int j = wv * 4 + jj;
    const int n = n0 + j;
    float qr = Fr[j][ln], qi = Fi[j][ln];
    float kr = Fr[16 + j][ln], ki = Fi[16 + j][ln];
    {
      const float s = wave_sum(fmaf(qr, qr, qi * qi));
      const float inv = 1.0f / fmaxf(sqrtf(s), 1e-12f);
      qr *= inv; qi *= inv;
    }
    {
      const float s = wave_sum(fmaf(kr, kr, ki * ki));
      const float inv = 1.0f / fmaxf(sqrtf(s), 1e-12f);
      kr *= inv; ki *= inv;
    }
    const size_t o = ((size_t)bh * N_ + n) * 128;
    Qc[o + ln]      = f2bf(qr);
    Qc[o + 64 + ln] = f2bf(qi);
    const float dr = kr - qr, di = ki - qi;
    const float sr = wave_sum(fmaf(dr, dr, -di * di));
    const float si = wave_sum(2.0f * dr * di);
    const float rad = sqrtf(fmaf(sr, sr, si * si));
    const float ur = sqrtf(fmaxf((rad + sr) * 0.5f, 0.0f));
    const float ui = copysignf(sqrtf(fmaxf((rad - sr) * 0.5f, 0.0f)), si);
    const float er = __expf(10.0f * ur);
    const float exr = er * cosf(10.0f * ui);
    const float exi = er * sinf(10.0f * ui);
    const float dnr = 1.0f + exr, dni = exi;
    const float d2 = fmaf(dnr, dnr, dni * dni);
    const float tfr = dnr / d2, tfi = -dni / d2;
    const float omr = 1.0f - tfr, omi = -tfi;
    const float ktr = kr * tfr - ki * tfi + qr * omr - qi * omi;
    const float kti = kr * tfi + ki * tfr + qr * omi + qi * omr;
    const float s2 = wave_sum(fmaf(ktr, ktr, kti * kti));
    const float inv2 = 1.0f / fmaxf(sqrtf(s2), 1e-12f);
    Kc[o + ln]      = f2bf(ktr * inv2);
    Kc[o + 64 + ln] = f2bf(-kti * inv2);   // negated: S = qr.kr + qi.(-ki)
  }
}

// ---------------------------------------------------------------------------
// attn3: 32x32x16 MFMA flash -- unchanged
// ---------------------------------------------------------------------------
__global__ __launch_bounds__(256, 2) void attn3(
    const ushort_t* __restrict__ Qc, const ushort_t* __restrict__ Kc,
    const ushort_t* __restrict__ Vt, float* __restrict__ out) {
  __shared__ __align__(16) char smem[35328];
  ushort_t* Ks = (ushort_t*)smem;              // [64][128] swizzled (16 KB)
  ushort_t* Vs = (ushort_t*)(smem + 16384);    // [64][128-slot] swizzled (16 KB)
  float (*Of)[68] = (float(*)[68])smem;        // merge: [128][68] f32
  float* Dd = (float*)(smem + 34816);          // den[128]

  const int tid = threadIdx.x;
  const int wv = tid >> 6, ln = tid & 63;
  const int l31 = ln & 31, hi = ln >> 5;
  const int qh = wv & 1, kh = wv >> 1;
  const int bh = blockIdx.y;
  const int q0 = blockIdx.x * 128;
  const size_t hb = (size_t)bh * N_;

  short8 qf[2][8];
#pragma unroll
  for (int nt = 0; nt < 2; ++nt) {
    const size_t qrow = (hb + q0 + qh * 64 + nt * 32 + l31) * 128;
#pragma unroll
    for (int s = 0; s < 8; ++s)
      qf[nt][s] = *(const short8*)&Qc[qrow + s * 16 + hi * 8];
  }

  f32x16 oacc[2][2];
#pragma unroll
  for (int i = 0; i < 2; ++i)
#pragma unroll
    for (int j = 0; j < 2; ++j)
#pragma unroll
      for (int r = 0; r < 16; ++r) oacc[i][j][r] = 0.f;
  float den[2] = {0.f, 0.f};

  const int rK = kh * 32 + l31;
  for (int kt = 0; kt < N_ / 64; ++kt) {
    const size_t kbase = (hb + kt * 64) * 128;
    __syncthreads();
#pragma unroll
    for (int i = 0; i < 4; ++i) {
      const int l = tid + i * 256;
      const int r = l >> 4, c = l & 15;
      uint4 v = *(const uint4*)&Kc[kbase + (size_t)r * 128 + c * 8];
      *(uint4*)&Ks[r * 128 + ((c ^ (r & 15)) * 8)] = v;
    }
#pragma unroll
    for (int i = 0; i < 2; ++i) {
      const int l = tid + i * 256;
      const int r = l >> 3, c = l & 7;
      uint4 v = *(const uint4*)&Vt[((size_t)bh * 64 + r) * N_ + kt * 64 + c * 8];
      *(uint4*)&Vs[r * 128 + ((c ^ (r & 15)) * 8)] = v;
    }
    __syncthreads();

    f32x16 sacc[2];
#pragma unroll
    for (int nt = 0; nt < 2; ++nt)
#pragma unroll
      for (int r = 0; r < 16; ++r) sacc[nt][r] = 0.f;
#pragma unroll
    for (int s = 0; s < 8; ++s) {
      const int c = s * 2 + hi;
      short8 ak = *(const short8*)&Ks[rK * 128 + ((c ^ (rK & 15)) * 8)];
      sacc[0] = __builtin_amdgcn_mfma_f32_32x32x16_bf16(ak, qf[0][s], sacc[0], 0, 0, 0);
      sacc[1] = __builtin_amdgcn_mfma_f32_32x32x16_bf16(ak, qf[1][s], sacc[1], 0, 0, 0);
    }

    short8 pfrag[2][2];
#pragma unroll
    for (int nt = 0; nt < 2; ++nt) {
      float pv[16];
      float dl = 0.f;
#pragma unroll
      for (int r = 0; r < 16; ++r) {
        pv[r] = __expf(sacc[nt][r] * SCALE_F);
        dl += pv[r];
      }
      den[nt] += dl;
      unsigned u8a[8], pu[8];
#pragma unroll
      for (int t = 0; t < 8; ++t)
        u8a[t] = (unsigned)f2bf(pv[2 * t]) | ((unsigned)f2bf(pv[2 * t + 1]) << 16);
#pragma unroll
      for (int t = 0; t < 8; ++t)
        pu[t] = (unsigned)__shfl_xor((int)u8a[t], 32, 64);
#pragma unroll
      for (int s2 = 0; s2 < 2; ++s2) {
        u32x4 fu;
        if (hi == 0) {
          fu[0] = u8a[4 * s2]; fu[1] = u8a[4 * s2 + 1];
          fu[2] = pu[4 * s2];  fu[3] = pu[4 * s2 + 1];
        } else {
          fu[0] = pu[4 * s2 + 2];  fu[1] = pu[4 * s2 + 3];
          fu[2] = u8a[4 * s2 + 2]; fu[3] = u8a[4 * s2 + 3];
        }
        pfrag[nt][s2] = __builtin_bit_cast(short8, fu);
      }
    }

#pragma unroll
    for (int s2 = 0; s2 < 2; ++s2) {
#pragma unroll
      for (int dt = 0; dt < 2; ++dt) {
        const int rV = dt * 32 + l31;
        const int c = kh * 4 + s2 * 2 + hi;
        short8 bv = *(const short8*)&Vs[rV * 128 + ((c ^ (rV & 15)) * 8)];
        oacc[0][dt] = __builtin_amdgcn_mfma_f32_32x32x16_bf16(pfrag[0][s2], bv, oacc[0][dt], 0, 0, 0);
        oacc[1][dt] = __builtin_amdgcn_mfma_f32_32x32x16_bf16(pfrag[1][s2], bv, oacc[1][dt], 0, 0, 0);
      }
    }
  }

#pragma unroll
  for (int nt = 0; nt < 2; ++nt)
    den[nt] += __shfl_xor(den[nt], 32, 64);

  __syncthreads();
  if (kh == 0) {
#pragma unroll
    for (int nt = 0; nt < 2; ++nt) {
#pragma unroll
      for (int dt = 0; dt < 2; ++dt)
#pragma unroll
        for (int r = 0; r < 16; ++r) {
          const int row = qh * 64 + nt * 32 + (r & 3) + 8 * (r >> 2) + 4 * hi;
          Of[row][dt * 32 + l31] = oacc[nt][dt][r];
        }
      if (hi == 0) Dd[qh * 64 + nt * 32 + l31] = den[nt];
    }
  }
  __syncthreads();
  if (kh == 1) {
#pragma unroll
    for (int nt = 0; nt < 2; ++nt) {
#pragma unroll
      for (int dt = 0; dt < 2; ++dt)
#pragma unroll
        for (int r = 0; r < 16; ++r) {
          const int row = qh * 64 + nt * 32 + (r & 3) + 8 * (r >> 2) + 4 * hi;
          Of[row][dt * 32 + l31] += oacc[nt][dt][r];
        }
      if (hi == 0) Dd[qh * 64 + nt * 32 + l31] += den[nt];
    }
  }
  __syncthreads();

  {
    const int ql = tid >> 1, half = tid & 1;
    const int b = bh >> 4, h = bh & 15;
    const float invd = 1.0f / Dd[ql];
    float* op = &out[(((size_t)b * N_ + q0 + ql) * H_ + h) * HD_ + half * 32];
#pragma unroll
    for (int j = 0; j < 8; ++j) {
      float4 o = *(const float4*)&Of[ql][half * 32 + j * 4];
      o.x *= invd; o.y *= invd; o.z *= invd; o.w *= invd;
      *(float4*)&op[j * 4] = o;
    }
  }
}

// ---------------------------------------------------------------------------
extern "C" void kernel_launch(void* const* d_in, const int* in_sizes, int n_in,
                              void* d_out, int out_size, void* d_ws, size_t ws_size,
                              hipStream_t stream) {
  const float* x    = (const float*)d_in[0];
  const float* Wqkv = (const float*)d_in[1];
  const float* bqkv = (const float*)d_in[2];
  const float* Wp1  = (const float*)d_in[3];
  const float* bp1  = (const float*)d_in[4];
  const float* Wp2  = (const float*)d_in[5];
  const float* bp2  = (const float*)d_in[6];
  const float* Wf   = (const float*)d_in[7];
  float* out = (float*)d_out;

  char* w = (char*)d_ws;
  float* qkv = (float*)w;               w += (size_t)ROWS * TDIM * 4;
  float* sumsq = (float*)w;             w += (size_t)ROWS * 4;
  ushort_t* Ms  = (ushort_t*)w;         w += 2 * 4096 * 2;
  ushort_t* W1s = (ushort_t*)w;         w += 2 * 8192 * 2;
  ushort_t* W2s = (ushort_t*)w;         w += 2 * 8192 * 2;
  unsigned short* Xs = (unsigned short*)w; w += (size_t)ROWS * 2048 * 2;
  unsigned short* Wt = (unsigned short*)w; w += (size_t)TDIM * 2048 * 2;
  unsigned short* Qc = (unsigned short*)w; w += (size_t)32 * N_ * 128 * 2;
  unsigned short* Kc = (unsigned short*)w; w += (size_t)32 * N_ * 128 * 2;
  unsigned short* Vt = (unsigned short*)w; w += (size_t)32 * 64 * N_ * 2;

  hipLaunchKernelGGL(split_X, dim3(ROWS * 1024 / 4 / 256), dim3(256), 0, stream, x, Xs);
  hipLaunchKernelGGL(split_W, dim3(48, 16), dim3(256), 0, stream, Wqkv, Wt);
  hipLaunchKernelGGL(compute_M, dim3(1), dim3(256), 0, stream, Wf, Ms);
  hipLaunchKernelGGL(prep_w, dim3(1), dim3(256), 0, stream, Wp1, Wp2, W1s, W2s);
  hipLaunchKernelGGL(zero_sumsq, dim3(1), dim3(256), 0, stream, sumsq);
  hipLaunchKernelGGL(gemm4, dim3(24, 32), dim3(256), 0, stream, Xs, Wt, bqkv, qkv, sumsq);
  hipLaunchKernelGGL(prep_mfma, dim3(4096), dim3(256), 0, stream,
                     qkv, sumsq, W1s, bp1, W2s, bp2, Ms, Qc, Kc, Vt);
  hipLaunchKernelGGL(attn3, dim3(N_ / 128, B_ * H_), dim3(256), 0, stream,
                     Qc, Kc, Vt, out);
}

// Round 7
// 442.978 us; speedup vs baseline: 4.0214x; 1.0882x over previous
//
#include <hip/hip_runtime.h>
#include <math.h>

#define B_    2
#define N_    2048
#define DIM_  1024
#define H_    16
#define HD_   64
#define TDIM  3072      // 3*DIM
#define ROWS  4096      // B*N
#define PI_F  3.14159265358979323846f
#define SCALE_F 0.125f

typedef short short8 __attribute__((ext_vector_type(8)));
typedef float f32x4 __attribute__((ext_vector_type(4)));
typedef float f32x16 __attribute__((ext_vector_type(16)));
typedef unsigned u32x4 __attribute__((ext_vector_type(4)));
typedef unsigned short ushort_t;

__device__ __forceinline__ float wave_sum(float v) {
#pragma unroll
  for (int off = 32; off > 0; off >>= 1) v += __shfl_xor(v, off, 64);
  return v;
}

// 2-op bf16 round (round-half-up; differs from RNE only on exact ties --
// irrelevant: split-lo absorbs the residual, and ties are measure-zero)
__device__ __forceinline__ unsigned short f2bf(float x) {
  return (unsigned short)((__float_as_uint(x) + 0x8000u) >> 16);
}
__device__ __forceinline__ float bf2f(unsigned short h) {
  return __uint_as_float(((unsigned)h) << 16);
}
// 1/max(sqrt(s),1e-12) via v_rsq (rel err ~1e-7, far below bf16 noise)
__device__ __forceinline__ float inv_norm(float s) {
  return __builtin_amdgcn_rsqf(fmaxf(s, 1e-24f));
}
// abs err ~1e-7 -- below bf16-split representation err
__device__ __forceinline__ float fast_tanh(float x) {
  return 1.0f - 2.0f / (__expf(2.0f * x) + 1.0f);
}

// async global->LDS, 16B per lane; LDS dest = wave-uniform base + lane*16
__device__ __forceinline__ void gl_lds16(const void* g, void* l) {
  __builtin_amdgcn_global_load_lds(
      (const __attribute__((address_space(1))) unsigned int*)g,
      (__attribute__((address_space(3))) unsigned int*)l, 16, 0, 0);
}

// ---------------------------------------------------------------------------
// zero the per-row sumsq accumulator (gemm epilogue atomics land here)
// ---------------------------------------------------------------------------
__global__ __launch_bounds__(256) void zero_sumsq(float* __restrict__ s) {
  const int i = threadIdx.x;
#pragma unroll
  for (int j = 0; j < 16; ++j) s[j * 256 + i] = 0.0f;
}

// ---------------------------------------------------------------------------
// M = (I + 0.1*Wf)^10 (64x64); emit transposed split-bf16 Ms[2][64][64]
// ---------------------------------------------------------------------------
__global__ __launch_bounds__(256) void compute_M(const float* __restrict__ Wf,
                                                 ushort_t* __restrict__ Ms) {
  __shared__ float A[4096], Mc[4096], Mn[4096];
  const int tid = threadIdx.x;
  for (int i = tid; i < 4096; i += 256) {
    float a = 0.1f * Wf[i] + (((i >> 6) == (i & 63)) ? 1.0f : 0.0f);
    A[i] = a; Mc[i] = a;
  }
  __syncthreads();
  for (int it = 0; it < 9; ++it) {
    for (int i = tid; i < 4096; i += 256) {
      const int r = i >> 6, c = i & 63;
      float s = 0.0f;
      for (int e = 0; e < 64; ++e) s = fmaf(Mc[r * 64 + e], A[e * 64 + c], s);
      Mn[i] = s;
    }
    __syncthreads();
    for (int i = tid; i < 4096; i += 256) Mc[i] = Mn[i];
    __syncthreads();
  }
  for (int i = tid; i < 4096; i += 256) {
    const int n = i >> 6, k = i & 63;
    const float v = Mc[k * 64 + n];
    const ushort_t hi = f2bf(v);
    Ms[i] = hi; Ms[4096 + i] = f2bf(v - bf2f(hi));
  }
}

// ---------------------------------------------------------------------------
// split/transpose the phase-MLP weights
// ---------------------------------------------------------------------------
__global__ __launch_bounds__(256) void prep_w(const float* __restrict__ Wp1,
                                              const float* __restrict__ Wp2,
                                              ushort_t* __restrict__ W1s,
                                              ushort_t* __restrict__ W2s) {
  const int tid = threadIdx.x;
  for (int i = tid; i < 8192; i += 256) {
    const int n = i >> 6, k = i & 63;
    const float v = Wp1[k * 128 + n];
    const ushort_t hi = f2bf(v);
    W1s[i] = hi; W1s[8192 + i] = f2bf(v - bf2f(hi));
  }
  for (int i = tid; i < 8192; i += 256) {
    const int n = i >> 7, k = i & 127;
    const float v = Wp2[k * 64 + n];
    const ushort_t hi = f2bf(v);
    W2s[i] = hi; W2s[8192 + i] = f2bf(v - bf2f(hi));
  }
}

// ---------------------------------------------------------------------------
// split fp32 -> bf16 hi/lo.  Xs[m][0..1023]=hi, [1024..2047]=lo
// ---------------------------------------------------------------------------
__global__ __launch_bounds__(256) void split_X(const float* __restrict__ X,
                                               unsigned short* __restrict__ Xs) {
  const int gid = blockIdx.x * 256 + threadIdx.x;
  const int m = gid >> 8, c = (gid & 255) * 4;
  float4 v = *(const float4*)&X[(size_t)m * 1024 + c];
  ushort4 hi, lo;
  hi.x = f2bf(v.x); lo.x = f2bf(v.x - bf2f(hi.x));
  hi.y = f2bf(v.y); lo.y = f2bf(v.y - bf2f(hi.y));
  hi.z = f2bf(v.z); lo.z = f2bf(v.z - bf2f(hi.z));
  hi.w = f2bf(v.w); lo.w = f2bf(v.w - bf2f(hi.w));
  *(ushort4*)&Xs[(size_t)m * 2048 + c] = hi;
  *(ushort4*)&Xs[(size_t)m * 2048 + 1024 + c] = lo;
}

// W[1024][3072] -> Wt[3072][2048] (n-major; cols 0..1023 hi, 1024..2047 lo)
__global__ __launch_bounds__(256) void split_W(const float* __restrict__ W,
                                               unsigned short* __restrict__ Wt) {
  __shared__ float T[64][68];
  const int n0 = blockIdx.x * 64, k0 = blockIdx.y * 64;
  const int tid = threadIdx.x;
  for (int l = tid; l < 1024; l += 256) {
    const int r = l >> 4, c = (l & 15) * 4;
    *(float4*)&T[r][c] = *(const float4*)&W[(size_t)(k0 + r) * TDIM + n0 + c];
  }
  __syncthreads();
  const int n = tid >> 2, q = (tid & 3) * 16;
  alignas(16) unsigned short hi16[16];
  alignas(16) unsigned short lo16[16];
#pragma unroll
  for (int j = 0; j < 16; ++j) {
    const float v = T[q + j][n];
    const unsigned short h = f2bf(v);
    hi16[j] = h; lo16[j] = f2bf(v - bf2f(h));
  }
  unsigned short* dst = &Wt[(size_t)(n0 + n) * 2048];
  *(uint4*)&dst[k0 + q]          = *(uint4*)&hi16[0];
  *(uint4*)&dst[k0 + q + 8]      = *(uint4*)&hi16[8];
  *(uint4*)&dst[1024 + k0 + q]     = *(uint4*)&lo16[0];
  *(uint4*)&dst[1024 + k0 + q + 8] = *(uint4*)&lo16[8];
}

// ---------------------------------------------------------------------------
// gemm5: two-phase split-bf16 MFMA.
// Phase 1 (16 iters): stage {Xh, Wh, Wl}; compute hh + hl (64 MFMA/drain,
//   A-frags shared). Phase 2 (16 iters): stage {Xl, Wh}; compute lh.
// vs gemm4: barriers 96->64, staged tiles 96->80, same 1536 MFMAs.
// XOR bank swizzle on staging/reads (R6: conflicts -> 0). LDS 48 KB -> 3/CU.
// Fused epilogue: C + per-row sumsq atomics.
// ---------------------------------------------------------------------------
__global__ __launch_bounds__(256) void gemm5(const unsigned short* __restrict__ Xs,
                                             const unsigned short* __restrict__ Wt,
                                             const float* __restrict__ bias,
                                             float* __restrict__ C,
                                             float* __restrict__ sumsq) {
  __shared__ ushort_t As[128 * 64];   // 16 KB each
  __shared__ ushort_t B0[128 * 64];
  __shared__ ushort_t B1[128 * 64];
  const int tid = threadIdx.x;
  const int wv = tid >> 6, ln = tid & 63;
  const int l16 = ln & 15, quad = ln >> 4;
  const int wrow = wv >> 1, wcol = wv & 1;
  const int row0 = blockIdx.y * 128, col0 = blockIdx.x * 128;
  const int srow = ln >> 3;           // row within chunk (0..7)
  const int sgrp = (ln & 7) ^ srow;   // swizzled global 16B-group index
  f32x4 acc[4][4];
#pragma unroll
  for (int i = 0; i < 4; ++i)
#pragma unroll
    for (int j = 0; j < 4; ++j) acc[i][j] = {0.f, 0.f, 0.f, 0.f};

  // ---- phase 1: C += Xh·Wh + Xh·Wl
  for (int k0 = 0; k0 < 1024; k0 += 64) {
    __syncthreads();
#pragma unroll
    for (int i = 0; i < 4; ++i) {
      const int ci = wv * 4 + i;
      const int r = ci * 8 + srow;
      gl_lds16(&Xs[(size_t)(row0 + r) * 2048 + k0 + sgrp * 8],
               (char*)As + ci * 1024);
      gl_lds16(&Wt[(size_t)(col0 + r) * 2048 + k0 + sgrp * 8],
               (char*)B0 + ci * 1024);
      gl_lds16(&Wt[(size_t)(col0 + r) * 2048 + 1024 + k0 + sgrp * 8],
               (char*)B1 + ci * 1024);
    }
    __syncthreads();
#pragma unroll
    for (int kk = 0; kk < 2; ++kk) {
      const int slot = (kk * 4 + quad) ^ (l16 & 7);
      short8 af[4], b[4];
#pragma unroll
      for (int mi = 0; mi < 4; ++mi)
        af[mi] = *(const short8*)&As[(wrow * 64 + mi * 16 + l16) * 64 + slot * 8];
#pragma unroll
      for (int ni = 0; ni < 4; ++ni)
        b[ni] = *(const short8*)&B0[(wcol * 64 + ni * 16 + l16) * 64 + slot * 8];
#pragma unroll
      for (int mi = 0; mi < 4; ++mi)
#pragma unroll
        for (int ni = 0; ni < 4; ++ni)
          acc[mi][ni] = __builtin_amdgcn_mfma_f32_16x16x32_bf16(af[mi], b[ni], acc[mi][ni], 0, 0, 0);
#pragma unroll
      for (int ni = 0; ni < 4; ++ni)
        b[ni] = *(const short8*)&B1[(wcol * 64 + ni * 16 + l16) * 64 + slot * 8];
#pragma unroll
      for (int mi = 0; mi < 4; ++mi)
#pragma unroll
        for (int ni = 0; ni < 4; ++ni)
          acc[mi][ni] = __builtin_amdgcn_mfma_f32_16x16x32_bf16(af[mi], b[ni], acc[mi][ni], 0, 0, 0);
    }
  }
  // ---- phase 2: C += Xl·Wh
  for (int k0 = 0; k0 < 1024; k0 += 64) {
    __syncthreads();
#pragma unroll
    for (int i = 0; i < 4; ++i) {
      const int ci = wv * 4 + i;
      const int r = ci * 8 + srow;
      gl_lds16(&Xs[(size_t)(row0 + r) * 2048 + 1024 + k0 + sgrp * 8],
               (char*)As + ci * 1024);
      gl_lds16(&Wt[(size_t)(col0 + r) * 2048 + k0 + sgrp * 8],
               (char*)B0 + ci * 1024);
    }
    __syncthreads();
#pragma unroll
    for (int kk = 0; kk < 2; ++kk) {
      const int slot = (kk * 4 + quad) ^ (l16 & 7);
      short8 af[4], b[4];
#pragma unroll
      for (int mi = 0; mi < 4; ++mi)
        af[mi] = *(const short8*)&As[(wrow * 64 + mi * 16 + l16) * 64 + slot * 8];
#pragma unroll
      for (int ni = 0; ni < 4; ++ni)
        b[ni] = *(const short8*)&B0[(wcol * 64 + ni * 16 + l16) * 64 + slot * 8];
#pragma unroll
      for (int mi = 0; mi < 4; ++mi)
#pragma unroll
        for (int ni = 0; ni < 4; ++ni)
          acc[mi][ni] = __builtin_amdgcn_mfma_f32_16x16x32_bf16(af[mi], b[ni], acc[mi][ni], 0, 0, 0);
    }
  }
  // ---- epilogue: C store + row sumsq
  float ps[4][4];
#pragma unroll
  for (int mi = 0; mi < 4; ++mi)
#pragma unroll
    for (int r = 0; r < 4; ++r) ps[mi][r] = 0.f;
#pragma unroll
  for (int ni = 0; ni < 4; ++ni) {
    const int col = col0 + wcol * 64 + ni * 16 + l16;
    const float bb = bias[col];
#pragma unroll
    for (int mi = 0; mi < 4; ++mi) {
#pragma unroll
      for (int r = 0; r < 4; ++r) {
        const int row = row0 + wrow * 64 + mi * 16 + quad * 4 + r;
        const float o = acc[mi][ni][r] + bb;
        C[(size_t)row * TDIM + col] = o;
        ps[mi][r] = fmaf(o, o, ps[mi][r]);
      }
    }
  }
#pragma unroll
  for (int mi = 0; mi < 4; ++mi) {
#pragma unroll
    for (int r = 0; r < 4; ++r) {
      float v = ps[mi][r];
      v += __shfl_xor(v, 1, 64);
      v += __shfl_xor(v, 2, 64);
      v += __shfl_xor(v, 4, 64);
      v += __shfl_xor(v, 8, 64);
      if (l16 == 0)
        atomicAdd(&sumsq[row0 + wrow * 64 + mi * 16 + quad * 4 + r], v);
    }
  }
}

// ---------------------------------------------------------------------------
// prep (MFMA); VALU-trimmed: rsq inverses, cheap f2bf, __sincosf, 1-rcp
// ---------------------------------------------------------------------------
__global__ __launch_bounds__(256) void prep_mfma(
    const float* __restrict__ qkv, const float* __restrict__ sumsq,
    const ushort_t* __restrict__ W1s, const float* __restrict__ bp1,
    const ushort_t* __restrict__ W2s, const float* __restrict__ bp2,
    const ushort_t* __restrict__ Ms,
    ushort_t* __restrict__ Qc, ushort_t* __restrict__ Kc,
    ushort_t* __restrict__ Vt) {
  __shared__ __align__(16) char smem[45184];
  ushort_t (*Th)[72]  = (ushort_t(*)[72])(smem + 0);
  ushort_t (*Tl)[72]  = (ushort_t(*)[72])(smem + 4608);
  ushort_t (*Hh)[136] = (ushort_t(*)[136])(smem + 9216);
  ushort_t (*Hl)[136] = (ushort_t(*)[136])(smem + 17920);
  ushort_t (*Zrh)[72] = (ushort_t(*)[72])(smem + 26624);
  ushort_t (*Zrl)[72] = (ushort_t(*)[72])(smem + 31232);
  ushort_t (*Zih)[72] = (ushort_t(*)[72])(smem + 35840);
  ushort_t (*Zil)[72] = (ushort_t(*)[72])(smem + 40448);
  float (*Fr)[68] = (float(*)[68])(smem + 0);
  float (*Fi)[68] = (float(*)[68])(smem + 8704);
  float* invt = (float*)(smem + 45056);

  const int tid = threadIdx.x;
  const int wv = tid >> 6, ln = tid & 63;
  const int l16 = ln & 15, quad = ln >> 4;
  const int g0 = blockIdx.x * 16;
  const int bh = g0 >> 11, n0 = g0 & 2047;
  const int b = bh >> 4, h = bh & 15;

  {
    const int row = tid >> 4;
    const int c4 = (tid & 15) * 4;
    const int n = n0 + row;
    const size_t base = ((size_t)(b * N_ + n)) * TDIM + h * HD_;
    const float inv = inv_norm(sumsq[b * N_ + n]);
    float4 q4 = *(const float4*)&qkv[base + c4];
    float4 k4 = *(const float4*)&qkv[base + 1024 + c4];
    float4 v4 = *(const float4*)&qkv[base + 2048 + c4];
    q4.x *= inv; q4.y *= inv; q4.z *= inv; q4.w *= inv;
    k4.x *= inv; k4.y *= inv; k4.z *= inv; k4.w *= inv;
    v4.x *= inv; v4.y *= inv; v4.z *= inv; v4.w *= inv;
    float sq = q4.x * q4.x + q4.y * q4.y + q4.z * q4.z + q4.w * q4.w;
    float sk = k4.x * k4.x + k4.y * k4.y + k4.z * k4.z + k4.w * k4.w;
    float sv = v4.x * v4.x + v4.y * v4.y + v4.z * v4.z + v4.w * v4.w;
#pragma unroll
    for (int off = 1; off < 16; off <<= 1) {
      sq += __shfl_xor(sq, off, 64);
      sk += __shfl_xor(sk, off, 64);
      sv += __shfl_xor(sv, off, 64);
    }
    if ((tid & 15) == 0) {
      invt[row]      = inv_norm(sq);
      invt[16 + row] = inv_norm(sk);
    }
    const float vinv = inv_norm(sv);
    const float va[4] = {v4.x, v4.y, v4.z, v4.w};
#pragma unroll
    for (int j = 0; j < 4; ++j)
      Vt[((size_t)(bh * 64 + c4 + j)) * N_ + n] = f2bf(fabsf(va[j]) * vinv);
    ushort4 qh, ql, kh, kl;
    qh.x = f2bf(q4.x); ql.x = f2bf(q4.x - bf2f(qh.x));
    qh.y = f2bf(q4.y); ql.y = f2bf(q4.y - bf2f(qh.y));
    qh.z = f2bf(q4.z); ql.z = f2bf(q4.z - bf2f(qh.z));
    qh.w = f2bf(q4.w); ql.w = f2bf(q4.w - bf2f(qh.w));
    kh.x = f2bf(k4.x); kl.x = f2bf(k4.x - bf2f(kh.x));
    kh.y = f2bf(k4.y); kl.y = f2bf(k4.y - bf2f(kh.y));
    kh.z = f2bf(k4.z); kl.z = f2bf(k4.z - bf2f(kh.z));
    kh.w = f2bf(k4.w); kl.w = f2bf(k4.w - bf2f(kh.w));
    *(ushort4*)&Th[row][c4] = qh;      *(ushort4*)&Tl[row][c4] = ql;
    *(ushort4*)&Th[16 + row][c4] = kh; *(ushort4*)&Tl[16 + row][c4] = kl;
  }
  __syncthreads();

  const int rt = wv & 1;
  const int ch = wv >> 1;

  {
    short8 aT[2][2];
#pragma unroll
    for (int s = 0; s < 2; ++s) {
      aT[s][0] = *(const short8*)&Th[rt * 16 + l16][s * 32 + quad * 8];
      aT[s][1] = *(const short8*)&Tl[rt * 16 + l16][s * 32 + quad * 8];
    }
#pragma unroll
    for (int ct = 0; ct < 4; ++ct) {
      const int colg = ch * 64 + ct * 16 + l16;
      f32x4 c = {0.f, 0.f, 0.f, 0.f};
#pragma unroll
      for (int s = 0; s < 2; ++s) {
        short8 bh8 = *(const short8*)&W1s[(size_t)colg * 64 + s * 32 + quad * 8];
        short8 bl8 = *(const short8*)&W1s[8192 + (size_t)colg * 64 + s * 32 + quad * 8];
        c = __builtin_amdgcn_mfma_f32_16x16x32_bf16(aT[s][0], bh8, c, 0, 0, 0);
        c = __builtin_amdgcn_mfma_f32_16x16x32_bf16(aT[s][0], bl8, c, 0, 0, 0);
        c = __builtin_amdgcn_mfma_f32_16x16x32_bf16(aT[s][1], bh8, c, 0, 0, 0);
      }
      const float bb = bp1[colg];
#pragma unroll
      for (int r = 0; r < 4; ++r) {
        const int row = rt * 16 + quad * 4 + r;
        const float hv = fast_tanh(c[r] + bb);
        const ushort_t hh_ = f2bf(hv);
        Hh[row][colg] = hh_;
        Hl[row][colg] = f2bf(hv - bf2f(hh_));
      }
    }
  }
  __syncthreads();

  {
    short8 aH[4][2];
#pragma unroll
    for (int s = 0; s < 4; ++s) {
      aH[s][0] = *(const short8*)&Hh[rt * 16 + l16][s * 32 + quad * 8];
      aH[s][1] = *(const short8*)&Hl[rt * 16 + l16][s * 32 + quad * 8];
    }
#pragma unroll
    for (int t2 = 0; t2 < 2; ++t2) {
      const int d = (ch * 2 + t2) * 16 + l16;
      f32x4 c = {0.f, 0.f, 0.f, 0.f};
#pragma unroll
      for (int s = 0; s < 4; ++s) {
        short8 bh8 = *(const short8*)&W2s[(size_t)d * 128 + s * 32 + quad * 8];
        short8 bl8 = *(const short8*)&W2s[8192 + (size_t)d * 128 + s * 32 + quad * 8];
        c = __builtin_amdgcn_mfma_f32_16x16x32_bf16(aH[s][0], bh8, c, 0, 0, 0);
        c = __builtin_amdgcn_mfma_f32_16x16x32_bf16(aH[s][0], bl8, c, 0, 0, 0);
        c = __builtin_amdgcn_mfma_f32_16x16x32_bf16(aH[s][1], bh8, c, 0, 0, 0);
      }
      const float b2v = bp2[d];
#pragma unroll
      for (int r = 0; r < 4; ++r) {
        const int row = rt * 16 + quad * 4 + r;
        const float ph = fast_tanh(c[r] + b2v) * PI_F;
        const float tv = bf2f(Th[row][d]) + bf2f(Tl[row][d]);
        const float amp = tv * invt[row];
        float sp, cp;
        __sincosf(ph, &sp, &cp);
        const float zr = amp * cp;
        const float zi = amp * sp;
        const ushort_t zrh = f2bf(zr);
        const ushort_t zih = f2bf(zi);
        Zrh[row][d] = zrh; Zrl[row][d] = f2bf(zr - bf2f(zrh));
        Zih[row][d] = zih; Zil[row][d] = f2bf(zi - bf2f(zih));
      }
    }
  }
  __syncthreads();

  {
    const ushort_t (*Zh)[72] = ch ? Zih : Zrh;
    const ushort_t (*Zl)[72] = ch ? Zil : Zrl;
    float (*Fo)[68] = ch ? Fi : Fr;
    short8 aZ[2][2];
#pragma unroll
    for (int s = 0; s < 2; ++s) {
      aZ[s][0] = *(const short8*)&Zh[rt * 16 + l16][s * 32 + quad * 8];
      aZ[s][1] = *(const short8*)&Zl[rt * 16 + l16][s * 32 + quad * 8];
    }
#pragma unroll
    for (int ct = 0; ct < 4; ++ct) {
      const int colg = ct * 16 + l16;
      f32x4 c = {0.f, 0.f, 0.f, 0.f};
#pragma unroll
      for (int s = 0; s < 2; ++s) {
        short8 bh8 = *(const short8*)&Ms[(size_t)colg * 64 + s * 32 + quad * 8];
        short8 bl8 = *(const short8*)&Ms[4096 + (size_t)colg * 64 + s * 32 + quad * 8];
        c = __builtin_amdgcn_mfma_f32_16x16x32_bf16(aZ[s][0], bh8, c, 0, 0, 0);
        c = __builtin_amdgcn_mfma_f32_16x16x32_bf16(aZ[s][0], bl8, c, 0, 0, 0);
        c = __builtin_amdgcn_mfma_f32_16x16x32_bf16(aZ[s][1], bh8, c, 0, 0, 0);
      }
#pragma unroll
      for (int r = 0; r < 4; ++r)
        Fo[rt * 16 + quad * 4 + r][colg] = c[r];
    }
  }
  __syncthreads();

#pragma unroll
  for (int jj = 0; jj < 4; ++jj) {
    const int j = wv * 4 + jj;
    const int n = n0 + j;
    float qr = Fr[j][ln], qi = Fi[j][ln];
    float kr = Fr[16 + j][ln], ki = Fi[16 + j][ln];
    {
      const float inv = inv_norm(wave_sum(fmaf(qr, qr, qi * qi)));
      qr *= inv; qi *= inv;
    }
    {
      const float inv = inv_norm(wave_sum(fmaf(kr, kr, ki * ki)));
      kr *= inv; ki *= inv;
    }
    const size_t o = ((size_t)bh * N_ + n) * 128;
    Qc[o + ln]      = f2bf(qr);
    Qc[o + 64 + ln] = f2bf(qi);
    const float dr = kr - qr, di = ki - qi;
    const float sr = wave_sum(fmaf(dr, dr, -di * di));
    const float si = wave_sum(2.0f * dr * di);
    const float rad = sqrtf(fmaf(sr, sr, si * si));
    const float ur = sqrtf(fmaxf((rad + sr) * 0.5f, 0.0f));
    const float ui = copysignf(sqrtf(fmaxf((rad - sr) * 0.5f, 0.0f)), si);
    const float er = __expf(10.0f * ur);
    float s10, c10;
    __sincosf(10.0f * ui, &s10, &c10);
    const float exr = er * c10;
    const float exi = er * s10;
    const float dnr = 1.0f + exr, dni = exi;
    const float rd2 = __builtin_amdgcn_rcpf(fmaf(dnr, dnr, dni * dni));
    const float tfr = dnr * rd2, tfi = -dni * rd2;
    const float omr = 1.0f - tfr, omi = -tfi;
    const float ktr = kr * tfr - ki * tfi + qr * omr - qi * omi;
    const float kti = kr * tfi + ki * tfr + qr * omi + qi * omr;
    const float inv2 = inv_norm(wave_sum(fmaf(ktr, ktr, kti * kti)));
    Kc[o + ln]      = f2bf(ktr * inv2);
    Kc[o + 64 + ln] = f2bf(-kti * inv2);   // negated: S = qr.kr + qi.(-ki)
  }
}

// ---------------------------------------------------------------------------
// attn3: 32x32x16 MFMA flash -- unchanged (inherits cheap f2bf)
// ---------------------------------------------------------------------------
__global__ __launch_bounds__(256, 2) void attn3(
    const ushort_t* __restrict__ Qc, const ushort_t* __restrict__ Kc,
    const ushort_t* __restrict__ Vt, float* __restrict__ out) {
  __shared__ __align__(16) char smem[35328];
  ushort_t* Ks = (ushort_t*)smem;              // [64][128] swizzled (16 KB)
  ushort_t* Vs = (ushort_t*)(smem + 16384);    // [64][128-slot] swizzled (16 KB)
  float (*Of)[68] = (float(*)[68])smem;        // merge: [128][68] f32
  float* Dd = (float*)(smem + 34816);          // den[128]

  const int tid = threadIdx.x;
  const int wv = tid >> 6, ln = tid & 63;
  const int l31 = ln & 31, hi = ln >> 5;
  const int qh = wv & 1, kh = wv >> 1;
  const int bh = blockIdx.y;
  const int q0 = blockIdx.x * 128;
  const size_t hb = (size_t)bh * N_;

  short8 qf[2][8];
#pragma unroll
  for (int nt = 0; nt < 2; ++nt) {
    const size_t qrow = (hb + q0 + qh * 64 + nt * 32 + l31) * 128;
#pragma unroll
    for (int s = 0; s < 8; ++s)
      qf[nt][s] = *(const short8*)&Qc[qrow + s * 16 + hi * 8];
  }

  f32x16 oacc[2][2];
#pragma unroll
  for (int i = 0; i < 2; ++i)
#pragma unroll
    for (int j = 0; j < 2; ++j)
#pragma unroll
      for (int r = 0; r < 16; ++r) oacc[i][j][r] = 0.f;
  float den[2] = {0.f, 0.f};

  const int rK = kh * 32 + l31;
  for (int kt = 0; kt < N_ / 64; ++kt) {
    const size_t kbase = (hb + kt * 64) * 128;
    __syncthreads();
#pragma unroll
    for (int i = 0; i < 4; ++i) {
      const int l = tid + i * 256;
      const int r = l >> 4, c = l & 15;
      uint4 v = *(const uint4*)&Kc[kbase + (size_t)r * 128 + c * 8];
      *(uint4*)&Ks[r * 128 + ((c ^ (r & 15)) * 8)] = v;
    }
#pragma unroll
    for (int i = 0; i < 2; ++i) {
      const int l = tid + i * 256;
      const int r = l >> 3, c = l & 7;
      uint4 v = *(const uint4*)&Vt[((size_t)bh * 64 + r) * N_ + kt * 64 + c * 8];
      *(uint4*)&Vs[r * 128 + ((c ^ (r & 15)) * 8)] = v;
    }
    __syncthreads();

    f32x16 sacc[2];
#pragma unroll
    for (int nt = 0; nt < 2; ++nt)
#pragma unroll
      for (int r = 0; r < 16; ++r) sacc[nt][r] = 0.f;
#pragma unroll
    for (int s = 0; s < 8; ++s) {
      const int c = s * 2 + hi;
      short8 ak = *(const short8*)&Ks[rK * 128 + ((c ^ (rK & 15)) * 8)];
      sacc[0] = __builtin_amdgcn_mfma_f32_32x32x16_bf16(ak, qf[0][s], sacc[0], 0, 0, 0);
      sacc[1] = __builtin_amdgcn_mfma_f32_32x32x16_bf16(ak, qf[1][s], sacc[1], 0, 0, 0);
    }

    short8 pfrag[2][2];
#pragma unroll
    for (int nt = 0; nt < 2; ++nt) {
      float pv[16];
      float dl = 0.f;
#pragma unroll
      for (int r = 0; r < 16; ++r) {
        pv[r] = __expf(sacc[nt][r] * SCALE_F);
        dl += pv[r];
      }
      den[nt] += dl;
      unsigned u8a[8], pu[8];
#pragma unroll
      for (int t = 0; t < 8; ++t)
        u8a[t] = (unsigned)f2bf(pv[2 * t]) | ((unsigned)f2bf(pv[2 * t + 1]) << 16);
#pragma unroll
      for (int t = 0; t < 8; ++t)
        pu[t] = (unsigned)__shfl_xor((int)u8a[t], 32, 64);
#pragma unroll
      for (int s2 = 0; s2 < 2; ++s2) {
        u32x4 fu;
        if (hi == 0) {
          fu[0] = u8a[4 * s2]; fu[1] = u8a[4 * s2 + 1];
          fu[2] = pu[4 * s2];  fu[3] = pu[4 * s2 + 1];
        } else {
          fu[0] = pu[4 * s2 + 2];  fu[1] = pu[4 * s2 + 3];
          fu[2] = u8a[4 * s2 + 2]; fu[3] = u8a[4 * s2 + 3];
        }
        pfrag[nt][s2] = __builtin_bit_cast(short8, fu);
      }
    }

#pragma unroll
    for (int s2 = 0; s2 < 2; ++s2) {
#pragma unroll
      for (int dt = 0; dt < 2; ++dt) {
        const int rV = dt * 32 + l31;
        const int c = kh * 4 + s2 * 2 + hi;
        short8 bv = *(const short8*)&Vs[rV * 128 + ((c ^ (rV & 15)) * 8)];
        oacc[0][dt] = __builtin_amdgcn_mfma_f32_32x32x16_bf16(pfrag[0][s2], bv, oacc[0][dt], 0, 0, 0);
        oacc[1][dt] = __builtin_amdgcn_mfma_f32_32x32x16_bf16(pfrag[1][s2], bv, oacc[1][dt], 0, 0, 0);
      }
    }
  }

#pragma unroll
  for (int nt = 0; nt < 2; ++nt)
    den[nt] += __shfl_xor(den[nt], 32, 64);

  __syncthreads();
  if (kh == 0) {
#pragma unroll
    for (int nt = 0; nt < 2; ++nt) {
#pragma unroll
      for (int dt = 0; dt < 2; ++dt)
#pragma unroll
        for (int r = 0; r < 16; ++r) {
          const int row = qh * 64 + nt * 32 + (r & 3) + 8 * (r >> 2) + 4 * hi;
          Of[row][dt * 32 + l31] = oacc[nt][dt][r];
        }
      if (hi == 0) Dd[qh * 64 + nt * 32 + l31] = den[nt];
    }
  }
  __syncthreads();
  if (kh == 1) {
#pragma unroll
    for (int nt = 0; nt < 2; ++nt) {
#pragma unroll
      for (int dt = 0; dt < 2; ++dt)
#pragma unroll
        for (int r = 0; r < 16; ++r) {
          const int row = qh * 64 + nt * 32 + (r & 3) + 8 * (r >> 2) + 4 * hi;
          Of[row][dt * 32 + l31] += oacc[nt][dt][r];
        }
      if (hi == 0) Dd[qh * 64 + nt * 32 + l31] += den[nt];
    }
  }
  __syncthreads();

  {
    const int ql = tid >> 1, half = tid & 1;
    const int b = bh >> 4, h = bh & 15;
    const float invd = __builtin_amdgcn_rcpf(Dd[ql]);
    float* op = &out[(((size_t)b * N_ + q0 + ql) * H_ + h) * HD_ + half * 32];
#pragma unroll
    for (int j = 0; j < 8; ++j) {
      float4 o = *(const float4*)&Of[ql][half * 32 + j * 4];
      o.x *= invd; o.y *= invd; o.z *= invd; o.w *= invd;
      *(float4*)&op[j * 4] = o;
    }
  }
}

// ---------------------------------------------------------------------------
extern "C" void kernel_launch(void* const* d_in, const int* in_sizes, int n_in,
                              void* d_out, int out_size, void* d_ws, size_t ws_size,
                              hipStream_t stream) {
  const float* x    = (const float*)d_in[0];
  const float* Wqkv = (const float*)d_in[1];
  const float* bqkv = (const float*)d_in[2];
  const float* Wp1  = (const float*)d_in[3];
  const float* bp1  = (const float*)d_in[4];
  const float* Wp2  = (const float*)d_in[5];
  const float* bp2  = (const float*)d_in[6];
  const float* Wf   = (const float*)d_in[7];
  float* out = (float*)d_out;

  char* w = (char*)d_ws;
  float* qkv = (float*)w;               w += (size_t)ROWS * TDIM * 4;
  float* sumsq = (float*)w;             w += (size_t)ROWS * 4;
  ushort_t* Ms  = (ushort_t*)w;         w += 2 * 4096 * 2;
  ushort_t* W1s = (ushort_t*)w;         w += 2 * 8192 * 2;
  ushort_t* W2s = (ushort_t*)w;         w += 2 * 8192 * 2;
  unsigned short* Xs = (unsigned short*)w; w += (size_t)ROWS * 2048 * 2;
  unsigned short* Wt = (unsigned short*)w; w += (size_t)TDIM * 2048 * 2;
  unsigned short* Qc = (unsigned short*)w; w += (size_t)32 * N_ * 128 * 2;
  unsigned short* Kc = (unsigned short*)w; w += (size_t)32 * N_ * 128 * 2;
  unsigned short* Vt = (unsigned short*)w; w += (size_t)32 * 64 * N_ * 2;

  hipLaunchKernelGGL(split_X, dim3(ROWS * 1024 / 4 / 256), dim3(256), 0, stream, x, Xs);
  hipLaunchKernelGGL(split_W, dim3(48, 16), dim3(256), 0, stream, Wqkv, Wt);
  hipLaunchKernelGGL(compute_M, dim3(1), dim3(256), 0, stream, Wf, Ms);
  hipLaunchKernelGGL(prep_w, dim3(1), dim3(256), 0, stream, Wp1, Wp2, W1s, W2s);
  hipLaunchKernelGGL(zero_sumsq, dim3(1), dim3(256), 0, stream, sumsq);
  hipLaunchKernelGGL(gemm5, dim3(24, 32), dim3(256), 0, stream, Xs, Wt, bqkv, qkv, sumsq);
  hipLaunchKernelGGL(prep_mfma, dim3(4096), dim3(256), 0, stream,
                     qkv, sumsq, W1s, bp1, W2s, bp2, Ms, Qc, Kc, Vt);
  hipLaunchKernelGGL(attn3, dim3(N_ / 128, B_ * H_), dim3(256), 0, stream,
                     Qc, Kc, Vt, out);
}